// Round 1
// baseline (1194.516 us; speedup 1.0000x reference)
//
#include <hip/hip_runtime.h>

static constexpr int BATCH  = 2;
static constexpr int SEQ    = 2048;
static constexpr int DMODEL = 1024;
static constexpr int NHEADS = 16;
static constexpr int EHEAD  = 64;
static constexpr int DFF    = 4096;
static constexpr int NTOP   = 40;

typedef unsigned short u16;
typedef __bf16 bf16x8_t __attribute__((ext_vector_type(8)));
typedef u16    u16x8_t  __attribute__((ext_vector_type(8)));
typedef u16    u16x4_t  __attribute__((ext_vector_type(4)));
typedef float  f32x4_t  __attribute__((ext_vector_type(4)));

static __device__ __forceinline__ u16 f2b(float f) {
  unsigned u = __builtin_bit_cast(unsigned, f);
  unsigned r = u + 0x7FFFu + ((u >> 16) & 1u);
  return (u16)(r >> 16);
}
static __device__ __forceinline__ float b2f(u16 h) {
  unsigned u = ((unsigned)h) << 16;
  return __builtin_bit_cast(float, u);
}
static __device__ __forceinline__ f32x4_t mfma_bf16(u16x8_t a, u16x8_t b, f32x4_t c) {
  return __builtin_amdgcn_mfma_f32_16x16x32_bf16(
      __builtin_bit_cast(bf16x8_t, a), __builtin_bit_cast(bf16x8_t, b), c, 0, 0, 0);
}

// ---------------------------------------------------------------- threefry
static __device__ __forceinline__ void tf2x32(unsigned k0, unsigned k1,
                                              unsigned x0, unsigned x1,
                                              unsigned& o0, unsigned& o1) {
  unsigned ks2 = 0x1BD11BDAu ^ k0 ^ k1;
  x0 += k0; x1 += k1;
#define TFR(r) { x0 += x1; x1 = (x1 << r) | (x1 >> (32 - r)); x1 ^= x0; }
  TFR(13) TFR(15) TFR(26) TFR(6)  x0 += k1;  x1 += ks2 + 1u;
  TFR(17) TFR(29) TFR(16) TFR(24) x0 += ks2; x1 += k0 + 2u;
  TFR(13) TFR(15) TFR(26) TFR(6)  x0 += k0;  x1 += k1 + 3u;
  TFR(17) TFR(29) TFR(16) TFR(24) x0 += k1;  x1 += ks2 + 4u;
  TFR(13) TFR(15) TFR(26) TFR(6)  x0 += ks2; x1 += k0 + 5u;
#undef TFR
  o0 = x0; o1 = x1;
}

#define JAX_PARTITIONABLE 1

__global__ __launch_bounds__(256) void idx_kernel(int* __restrict__ idx) {
#if JAX_PARTITIONABLE
  // partitionable: split children = tf(key,(0,i)); bits[i] = o0^o1 of tf(k2,(0,i))
  int i = blockIdx.x * 256 + threadIdx.x;           // 0..81919, grid 320
  unsigned c0, c1, o0, o1;
  tf2x32(0u, 42u, 0u, 1u, c0, c1);                  // k2 = second child
  tf2x32(c0, c1, 0u, (unsigned)i, o0, o1);
  idx[i] = (int)((o0 ^ o1) & 2047u);
#else
  // legacy: split via iota(4) halves; bits via iota(81920) halves
  int i = blockIdx.x * 256 + threadIdx.x;           // 0..40959, grid 160
  unsigned a0, b0, a1, b1, o0, o1;
  tf2x32(0u, 42u, 0u, 2u, a0, b0);
  tf2x32(0u, 42u, 1u, 3u, a1, b1);
  tf2x32(b0, b1, (unsigned)i, (unsigned)(i + 40960), o0, o1);
  idx[i]         = (int)(o0 & 2047u);
  idx[i + 40960] = (int)(o1 & 2047u);
#endif
}

// ---------------------------------------------------------------- bf16 GEMM
// C[M,N] = A[M,K]f32 @ W[K,N]f32 + bias, optional relu. 128x128 tile, BK=32,
// 4 waves (2x2), 4x4 16x16x32 frags/wave. XOR-swizzled LDS.
__global__ __launch_bounds__(256)
void gemm_kernel(const float* __restrict__ A, const float* __restrict__ W,
                 const float* __restrict__ bias, float* __restrict__ C,
                 int M, int N, int K, int relu) {
  __shared__ __align__(16) u16 Asm[128 * 32];
  __shared__ __align__(16) u16 Bsm[128 * 32];
  const int tid = threadIdx.x;
  const int wave = tid >> 6, lane = tid & 63;
  const int m0 = blockIdx.x * 128, n0 = blockIdx.y * 128;
  const int wr = (wave >> 1) * 64, wc = (wave & 1) * 64;
  const int lr = lane & 15, kg = lane >> 4;

  f32x4_t acc[4][4];
#pragma unroll
  for (int i = 0; i < 4; ++i)
#pragma unroll
    for (int j = 0; j < 4; ++j) acc[i][j] = f32x4_t{0.f, 0.f, 0.f, 0.f};

  for (int k0 = 0; k0 < K; k0 += 32) {
#pragma unroll
    for (int i = 0; i < 4; ++i) {       // A: 128 rows x 32 k
      int j = tid + 256 * i;
      int row = j >> 3, c4 = j & 7;
      f32x4_t v4 = *(const f32x4_t*)(A + (size_t)(m0 + row) * K + k0 + c4 * 4);
      u16x4_t b4;
      b4[0] = f2b(v4[0]); b4[1] = f2b(v4[1]); b4[2] = f2b(v4[2]); b4[3] = f2b(v4[3]);
      *(u16x4_t*)((char*)Asm + ((row * 64 + c4 * 8) ^ ((row & 7) << 4))) = b4;
    }
#pragma unroll
    for (int i = 0; i < 2; ++i) {       // B: Bt[col][k]
      int u = tid + 256 * i;
      int col = u & 127, kb = u >> 7;
      const float* src = W + (size_t)(k0 + kb * 8) * N + n0 + col;
      u16x8_t b8;
#pragma unroll
      for (int j = 0; j < 8; ++j) b8[j] = f2b(src[(size_t)j * N]);
      *(u16x8_t*)((char*)Bsm + ((col * 64 + kb * 16) ^ ((col & 7) << 4))) = b8;
    }
    __syncthreads();
    u16x8_t a8[4], b8v[4];
#pragma unroll
    for (int mi = 0; mi < 4; ++mi) {
      int row = wr + mi * 16 + lr;
      a8[mi] = *(u16x8_t*)((char*)Asm + ((row * 64 + kg * 16) ^ ((row & 7) << 4)));
    }
#pragma unroll
    for (int ni = 0; ni < 4; ++ni) {
      int col = wc + ni * 16 + lr;
      b8v[ni] = *(u16x8_t*)((char*)Bsm + ((col * 64 + kg * 16) ^ ((col & 7) << 4)));
    }
#pragma unroll
    for (int mi = 0; mi < 4; ++mi)
#pragma unroll
      for (int ni = 0; ni < 4; ++ni)
        acc[mi][ni] = mfma_bf16(a8[mi], b8v[ni], acc[mi][ni]);
    __syncthreads();
  }
#pragma unroll
  for (int ni = 0; ni < 4; ++ni) {
    int col = n0 + wc + ni * 16 + lr;
    float bc = bias[col];
#pragma unroll
    for (int mi = 0; mi < 4; ++mi)
#pragma unroll
      for (int r = 0; r < 4; ++r) {
        int row = m0 + wr + mi * 16 + kg * 4 + r;
        float vv = acc[mi][ni][r] + bc;
        if (relu) vv = fmaxf(vv, 0.f);
        C[(size_t)row * N + col] = vv;
      }
  }
}

// 4-term split-precision GEMM (f32-equivalent): used for q,k projections so
// the ProbSparse top-k selection matches the f32 reference.
__global__ __launch_bounds__(256)
void gemm4_kernel(const float* __restrict__ A, const float* __restrict__ W,
                  const float* __restrict__ bias, float* __restrict__ C,
                  int M, int N, int K) {
  __shared__ __align__(16) u16 Ah[128 * 32];
  __shared__ __align__(16) u16 Alo[128 * 32];
  __shared__ __align__(16) u16 Bh[128 * 32];
  __shared__ __align__(16) u16 Blo[128 * 32];
  const int tid = threadIdx.x;
  const int wave = tid >> 6, lane = tid & 63;
  const int m0 = blockIdx.x * 128, n0 = blockIdx.y * 128;
  const int wr = (wave >> 1) * 64, wc = (wave & 1) * 64;
  const int lr = lane & 15, kg = lane >> 4;

  f32x4_t acc[4][4];
#pragma unroll
  for (int i = 0; i < 4; ++i)
#pragma unroll
    for (int j = 0; j < 4; ++j) acc[i][j] = f32x4_t{0.f, 0.f, 0.f, 0.f};

  for (int k0 = 0; k0 < K; k0 += 32) {
#pragma unroll
    for (int i = 0; i < 4; ++i) {
      int j = tid + 256 * i;
      int row = j >> 3, c4 = j & 7;
      f32x4_t v4 = *(const f32x4_t*)(A + (size_t)(m0 + row) * K + k0 + c4 * 4);
      u16x4_t h4, l4;
#pragma unroll
      for (int d = 0; d < 4; ++d) {
        u16 h = f2b(v4[d]); h4[d] = h; l4[d] = f2b(v4[d] - b2f(h));
      }
      unsigned off = (unsigned)((row * 64 + c4 * 8) ^ ((row & 7) << 4));
      *(u16x4_t*)((char*)Ah + off) = h4;
      *(u16x4_t*)((char*)Alo + off) = l4;
    }
#pragma unroll
    for (int i = 0; i < 2; ++i) {
      int u = tid + 256 * i;
      int col = u & 127, kb = u >> 7;
      const float* src = W + (size_t)(k0 + kb * 8) * N + n0 + col;
      u16x8_t h8, l8;
#pragma unroll
      for (int j = 0; j < 8; ++j) {
        float f = src[(size_t)j * N];
        u16 h = f2b(f); h8[j] = h; l8[j] = f2b(f - b2f(h));
      }
      unsigned off = (unsigned)((col * 64 + kb * 16) ^ ((col & 7) << 4));
      *(u16x8_t*)((char*)Bh + off) = h8;
      *(u16x8_t*)((char*)Blo + off) = l8;
    }
    __syncthreads();
#pragma unroll
    for (int p = 0; p < 4; ++p) {
      const u16* As = (p < 2) ? Ah : Alo;
      const u16* Bs = ((p & 1) == 0) ? Bh : Blo;
      // p0: hi*hi, p1: hi*lo, p2: lo*hi, p3: lo*lo
      const u16* As2 = (p == 0 || p == 1) ? Ah : Alo;
      const u16* Bs2 = (p == 0 || p == 2) ? Bh : Blo;
      (void)As; (void)Bs;
      u16x8_t a8[4], b8v[4];
#pragma unroll
      for (int mi = 0; mi < 4; ++mi) {
        int row = wr + mi * 16 + lr;
        a8[mi] = *(const u16x8_t*)((const char*)As2 + ((row * 64 + kg * 16) ^ ((row & 7) << 4)));
      }
#pragma unroll
      for (int ni = 0; ni < 4; ++ni) {
        int col = wc + ni * 16 + lr;
        b8v[ni] = *(const u16x8_t*)((const char*)Bs2 + ((col * 64 + kg * 16) ^ ((col & 7) << 4)));
      }
#pragma unroll
      for (int mi = 0; mi < 4; ++mi)
#pragma unroll
        for (int ni = 0; ni < 4; ++ni)
          acc[mi][ni] = mfma_bf16(a8[mi], b8v[ni], acc[mi][ni]);
    }
    __syncthreads();
  }
#pragma unroll
  for (int ni = 0; ni < 4; ++ni) {
    int col = n0 + wc + ni * 16 + lr;
    float bc = bias[col];
#pragma unroll
    for (int mi = 0; mi < 4; ++mi)
#pragma unroll
      for (int r = 0; r < 4; ++r) {
        int row = m0 + wr + mi * 16 + kg * 4 + r;
        C[(size_t)row * N + col] = acc[mi][ni][r] + bc;
      }
  }
}

// ---------------------------------------------------------------- ProbSparse
__global__ __launch_bounds__(256)
void probM_kernel(const float* __restrict__ q, const float* __restrict__ k,
                  const int* __restrict__ idx, float* __restrict__ Mv) {
  int gw = blockIdx.x * 4 + (threadIdx.x >> 6);
  int lane = threadIdx.x & 63;
  int l = gw & (SEQ - 1);
  int hh = (gw >> 11) & (NHEADS - 1);
  int b = gw >> 15;
  float qv = q[((size_t)b * SEQ + l) * DMODEL + hh * EHEAD + lane];
  const int* ip = idx + l * NTOP;
  float mmax = -3.0e38f, msum = 0.f;
  for (int u = 0; u < NTOP; ++u) {
    int ki = ip[u];
    float p = qv * k[((size_t)b * SEQ + ki) * DMODEL + hh * EHEAD + lane];
#pragma unroll
    for (int m = 1; m < 64; m <<= 1) p += __shfl_xor(p, m);
    mmax = fmaxf(mmax, p);
    msum += p;
  }
  if (lane == 0) Mv[gw] = mmax - msum * (1.f / 2048.f);
}

__global__ __launch_bounds__(256)
void topk_kernel(const float* __restrict__ Mv, int* __restrict__ Mtop) {
  int bh = blockIdx.x;
  int tid = threadIdx.x;
  __shared__ float vals[2048];
  __shared__ float rv[256];
  __shared__ int ri[256];
  for (int j = tid; j < 2048; j += 256) vals[j] = Mv[bh * 2048 + j];
  __syncthreads();
  for (int it = 0; it < NTOP; ++it) {
    float best = -3.0e38f;
    int bi = 1 << 30;
    for (int j = tid; j < 2048; j += 256) {
      float vv = vals[j];
      if (vv > best) { best = vv; bi = j; }
    }
    rv[tid] = best; ri[tid] = bi;
    __syncthreads();
    for (int st = 128; st > 0; st >>= 1) {
      if (tid < st) {
        if (rv[tid + st] > rv[tid] ||
            (rv[tid + st] == rv[tid] && ri[tid + st] < ri[tid])) {
          rv[tid] = rv[tid + st]; ri[tid] = ri[tid + st];
        }
      }
      __syncthreads();
    }
    if (tid == 0) { Mtop[bh * NTOP + it] = ri[0]; vals[ri[0]] = -3.4e38f; }
    __syncthreads();
  }
}

// transpose [B][L][h*64+e] -> [bh][e][L]
__global__ __launch_bounds__(256)
void transpose_head_f32(const float* __restrict__ in, float* __restrict__ outp) {
  int bh = blockIdx.x;
  int b = bh >> 4, hh = bh & 15;
  int l0 = blockIdx.y * 64;
  __shared__ float t[64][65];
  int c = threadIdx.x & 63, r4 = threadIdx.x >> 6;
  for (int i = 0; i < 16; ++i) {
    int row = r4 * 16 + i;
    t[row][c] = in[((size_t)b * SEQ + l0 + row) * DMODEL + hh * EHEAD + c];
  }
  __syncthreads();
  for (int i = 0; i < 16; ++i) {
    int er = r4 * 16 + i;
    outp[((size_t)bh * EHEAD + er) * SEQ + l0 + c] = t[c][er];
  }
}

__global__ __launch_bounds__(256)
void transpose_head_bf16(const float* __restrict__ in, u16* __restrict__ outp) {
  int bh = blockIdx.x;
  int b = bh >> 4, hh = bh & 15;
  int l0 = blockIdx.y * 64;
  __shared__ float t[64][65];
  int c = threadIdx.x & 63, r4 = threadIdx.x >> 6;
  for (int i = 0; i < 16; ++i) {
    int row = r4 * 16 + i;
    t[row][c] = in[((size_t)b * SEQ + l0 + row) * DMODEL + hh * EHEAD + c];
  }
  __syncthreads();
  for (int i = 0; i < 16; ++i) {
    int er = r4 * 16 + i;
    outp[((size_t)bh * EHEAD + er) * SEQ + l0 + c] = f2b(t[c][er]);
  }
}

// [B][L][h*64+e] -> [bh][l][e] bf16
__global__ __launch_bounds__(256)
void split_head_bf16(const float* __restrict__ in, u16* __restrict__ outp) {
  int i = blockIdx.x * 256 + threadIdx.x;  // < 4,194,304
  int e = i & 63;
  int l = (i >> 6) & 2047;
  int hh = (i >> 17) & 15;
  int b = i >> 21;
  outp[i] = f2b(in[((size_t)b * 2048 + l) * 1024 + hh * 64 + e]);
}

// attention for the selected 40 queries/head. grid (BH, 5), wave = 2 queries.
__global__ __launch_bounds__(256)
void probAttn_kernel(const float* __restrict__ q, const float* __restrict__ kT,
                     const float* __restrict__ vT, const int* __restrict__ Mtop,
                     float* __restrict__ upd) {
  int bh = blockIdx.x, b = bh >> 4, hh = bh & 15;
  int wave = threadIdx.x >> 6, lane = threadIdx.x & 63;
  int qg = blockIdx.y * 8 + wave * 2;
  int i0 = Mtop[bh * NTOP + qg], i1 = Mtop[bh * NTOP + qg + 1];
  float qv0 = q[((size_t)b * SEQ + i0) * DMODEL + hh * EHEAD + lane];
  float qv1 = q[((size_t)b * SEQ + i1) * DMODEL + hh * EHEAD + lane];
  const float* kb = kT + (size_t)bh * EHEAD * SEQ;
  const float* vb = vT + (size_t)bh * EHEAD * SEQ;
  float s0[32], s1[32];
#pragma unroll
  for (int kk = 0; kk < 32; ++kk) { s0[kk] = 0.f; s1[kk] = 0.f; }
  for (int e = 0; e < 64; ++e) {
    float qe0 = __shfl(qv0, e), qe1 = __shfl(qv1, e);
    const float* kr = kb + (size_t)e * SEQ;
#pragma unroll
    for (int kk = 0; kk < 32; ++kk) {
      float kv = kr[kk * 64 + lane];
      s0[kk] += qe0 * kv; s1[kk] += qe1 * kv;
    }
  }
  float m0 = -3e38f, m1 = -3e38f;
#pragma unroll
  for (int kk = 0; kk < 32; ++kk) {
    int key = kk * 64 + lane;
    s0[kk] = (key > i0) ? -1e9f : s0[kk] * 0.125f;
    s1[kk] = (key > i1) ? -1e9f : s1[kk] * 0.125f;
    m0 = fmaxf(m0, s0[kk]); m1 = fmaxf(m1, s1[kk]);
  }
#pragma unroll
  for (int m = 1; m < 64; m <<= 1) {
    m0 = fmaxf(m0, __shfl_xor(m0, m));
    m1 = fmaxf(m1, __shfl_xor(m1, m));
  }
  float sum0 = 0.f, sum1 = 0.f;
#pragma unroll
  for (int kk = 0; kk < 32; ++kk) {
    s0[kk] = __expf(s0[kk] - m0); sum0 += s0[kk];
    s1[kk] = __expf(s1[kk] - m1); sum1 += s1[kk];
  }
#pragma unroll
  for (int m = 1; m < 64; m <<= 1) {
    sum0 += __shfl_xor(sum0, m);
    sum1 += __shfl_xor(sum1, m);
  }
  float o0 = 0.f, o1 = 0.f;
  for (int e = 0; e < 64; ++e) {
    const float* vr = vb + (size_t)e * SEQ;
    float a0 = 0.f, a1 = 0.f;
#pragma unroll
    for (int kk = 0; kk < 32; ++kk) {
      float vv = vr[kk * 64 + lane];
      a0 += s0[kk] * vv; a1 += s1[kk] * vv;
    }
#pragma unroll
    for (int m = 1; m < 64; m <<= 1) {
      a0 += __shfl_xor(a0, m);
      a1 += __shfl_xor(a1, m);
    }
    if (lane == e) { o0 = a0; o1 = a1; }
  }
  upd[((size_t)bh * NTOP + qg) * EHEAD + lane] = o0 / sum0;
  upd[((size_t)bh * NTOP + qg + 1) * EHEAD + lane] = o1 / sum1;
}

// cumsum over l, per (b,h,e). chunked 2-pass scan, merged-layout output.
__global__ __launch_bounds__(64)
void scan1_kernel(const float* __restrict__ v, float* __restrict__ ctx,
                  float* __restrict__ csum) {
  int bh = blockIdx.x, c = blockIdx.y;
  int b = bh >> 4, hh = bh & 15, e = threadIdx.x;
  size_t base = ((size_t)b * SEQ + c * 128) * DMODEL + hh * EHEAD + e;
  float run = 0.f;
  for (int i = 0; i < 128; ++i) {
    run += v[base + (size_t)i * DMODEL];
    ctx[base + (size_t)i * DMODEL] = run;
  }
  csum[(bh * 16 + c) * 64 + e] = run;
}
__global__ __launch_bounds__(64)
void scan2_kernel(const float* __restrict__ csum, float* __restrict__ ctx) {
  int bh = blockIdx.x, c = blockIdx.y + 1;
  int b = bh >> 4, hh = bh & 15, e = threadIdx.x;
  float off = 0.f;
  for (int cc = 0; cc < c; ++cc) off += csum[(bh * 16 + cc) * 64 + e];
  size_t base = ((size_t)b * SEQ + c * 128) * DMODEL + hh * EHEAD + e;
  for (int i = 0; i < 128; ++i) ctx[base + (size_t)i * DMODEL] += off;
}

__global__ __launch_bounds__(256)
void scatter_kernel(const float* __restrict__ upd, const int* __restrict__ Mtop,
                    float* __restrict__ ctx) {
  int i = blockIdx.x * 256 + threadIdx.x;  // < 81920
  int e = i & 63;
  int t = i >> 6;          // bh*40+u
  int bh = t / NTOP;
  int b = bh >> 4, hh = bh & 15;
  int row = Mtop[t];
  ctx[((size_t)b * SEQ + row) * DMODEL + hh * EHEAD + e] = upd[i];
}

// ---------------------------------------------------------------- cross attn
// flash attention, 64-q tile per block, 4 waves x 16 q, 64-key chunks, MFMA.
__global__ __launch_bounds__(256)
void cross_attn_kernel(const float* __restrict__ q2, const u16* __restrict__ kb16,
                       const u16* __restrict__ vTb, float* __restrict__ ca) {
  int bh = blockIdx.x, b = bh >> 4, hh = bh & 15;
  int qt0 = blockIdx.y * 64;
  int tid = threadIdx.x, wave = tid >> 6, lane = tid & 63;
  int lr = lane & 15, kg = lane >> 4;
  __shared__ __align__(16) u16 Qs[64 * 64];
  __shared__ __align__(16) u16 Ps[4][16 * 64];
#pragma unroll
  for (int i = 0; i < 4; ++i) {   // stage Q (scaled by 1/8) bf16 swizzled
    int j = tid + 256 * i;
    int row = j >> 4, c4 = j & 15;
    f32x4_t v4 = *(const f32x4_t*)(q2 + ((size_t)b * SEQ + qt0 + row) * DMODEL + hh * EHEAD + c4 * 4);
    u16x4_t b4;
    b4[0] = f2b(v4[0] * 0.125f); b4[1] = f2b(v4[1] * 0.125f);
    b4[2] = f2b(v4[2] * 0.125f); b4[3] = f2b(v4[3] * 0.125f);
    *(u16x4_t*)((char*)Qs + ((row * 128 + c4 * 8) ^ ((row & 7) << 4))) = b4;
  }
  __syncthreads();
  u16x8_t aq[2];
  {
    int qrow = wave * 16 + lr;
#pragma unroll
    for (int ks = 0; ks < 2; ++ks)
      aq[ks] = *(u16x8_t*)((char*)Qs + ((qrow * 128 + ks * 64 + kg * 16) ^ ((qrow & 7) << 4)));
  }
  const u16* kbase = kb16 + (size_t)bh * SEQ * EHEAD;  // [key][e]
  const u16* vbase = vTb + (size_t)bh * EHEAD * SEQ;   // [e][key]
  f32x4_t oacc[4];
#pragma unroll
  for (int i = 0; i < 4; ++i) oacc[i] = f32x4_t{0.f, 0.f, 0.f, 0.f};
  float mrun[4] = {-3e38f, -3e38f, -3e38f, -3e38f};
  float lrun[4] = {0.f, 0.f, 0.f, 0.f};
  u16* pw = &Ps[wave][0];

  for (int kt = 0; kt < SEQ; kt += 64) {
    f32x4_t s[4];
#pragma unroll
    for (int i = 0; i < 4; ++i) s[i] = f32x4_t{0.f, 0.f, 0.f, 0.f};
#pragma unroll
    for (int ks = 0; ks < 2; ++ks) {
#pragma unroll
      for (int nt = 0; nt < 4; ++nt) {
        int key = kt + nt * 16 + lr;
        u16x8_t bk = *(const u16x8_t*)(kbase + (size_t)key * EHEAD + ks * 32 + kg * 8);
        s[nt] = mfma_bf16(aq[ks], bk, s[nt]);
      }
    }
    float al[4];
#pragma unroll
    for (int r = 0; r < 4; ++r) {
      float mx = fmaxf(fmaxf(s[0][r], s[1][r]), fmaxf(s[2][r], s[3][r]));
#pragma unroll
      for (int m = 1; m < 16; m <<= 1) mx = fmaxf(mx, __shfl_xor(mx, m));
      float mnew = fmaxf(mrun[r], mx);
      float a = __expf(mrun[r] - mnew);
      float sum = 0.f;
#pragma unroll
      for (int nt = 0; nt < 4; ++nt) {
        float p = __expf(s[nt][r] - mnew);
        s[nt][r] = p; sum += p;
      }
#pragma unroll
      for (int m = 1; m < 16; m <<= 1) sum += __shfl_xor(sum, m);
      lrun[r] = lrun[r] * a + sum;
      mrun[r] = mnew;
      al[r] = a;
    }
#pragma unroll
    for (int nt = 0; nt < 4; ++nt)
#pragma unroll
      for (int r = 0; r < 4; ++r) oacc[nt][r] *= al[r];
    // P (C-layout) -> LDS bf16 [16 q][64 key] swizzled (per-wave private)
#pragma unroll
    for (int nt = 0; nt < 4; ++nt)
#pragma unroll
      for (int r = 0; r < 4; ++r) {
        int qq = kg * 4 + r;
        *(u16*)((char*)pw + ((qq * 128 + (nt * 16 + lr) * 2) ^ ((qq & 7) << 4))) = f2b(s[nt][r]);
      }
#pragma unroll
    for (int ks2 = 0; ks2 < 2; ++ks2) {
      u16x8_t ap = *(u16x8_t*)((char*)pw + ((lr * 128 + ks2 * 64 + kg * 16) ^ ((lr & 7) << 4)));
#pragma unroll
      for (int ne = 0; ne < 4; ++ne) {
        int e = ne * 16 + lr;
        u16x8_t bv = *(const u16x8_t*)(vbase + (size_t)e * SEQ + kt + ks2 * 32 + kg * 8);
        oacc[ne] = mfma_bf16(ap, bv, oacc[ne]);
      }
    }
  }
#pragma unroll
  for (int ne = 0; ne < 4; ++ne)
#pragma unroll
    for (int r = 0; r < 4; ++r) {
      int row = qt0 + wave * 16 + kg * 4 + r;
      int col = hh * EHEAD + ne * 16 + lr;
      ca[((size_t)b * SEQ + row) * DMODEL + col] = oacc[ne][r] / lrun[r];
    }
}

// ---------------------------------------------------------------- layernorm
__global__ __launch_bounds__(256)
void ln_kernel(const float* __restrict__ x, const float* __restrict__ r,
               const float* __restrict__ g, const float* __restrict__ be,
               float* __restrict__ outp) {
  int row = blockIdx.x, tid = threadIdx.x;
  size_t base = (size_t)row * DMODEL;
  float v[4];
  float s = 0.f, sq = 0.f;
#pragma unroll
  for (int i = 0; i < 4; ++i) {
    int c = tid + i * 256;
    float t = x[base + c] + r[base + c];
    v[i] = t; s += t; sq += t * t;
  }
  __shared__ float rs[256], rq[256];
  rs[tid] = s; rq[tid] = sq;
  __syncthreads();
  for (int st = 128; st > 0; st >>= 1) {
    if (tid < st) { rs[tid] += rs[tid + st]; rq[tid] += rq[tid + st]; }
    __syncthreads();
  }
  float mean = rs[0] * (1.f / DMODEL);
  float var = rq[0] * (1.f / DMODEL) - mean * mean;
  float rstd = rsqrtf(var + 1e-5f);
#pragma unroll
  for (int i = 0; i < 4; ++i) {
    int c = tid + i * 256;
    outp[base + c] = (v[i] - mean) * rstd * g[c] + be[c];
  }
}

// ---------------------------------------------------------------- host side
static inline void gemm(const float* A, const float* W, const float* bias, float* C,
                        int M, int N, int K, int relu, hipStream_t s) {
  gemm_kernel<<<dim3(M / 128, N / 128), 256, 0, s>>>(A, W, bias, C, M, N, K, relu);
}
static inline void gemm_hi(const float* A, const float* W, const float* bias, float* C,
                           int M, int N, int K, hipStream_t s) {
  gemm4_kernel<<<dim3(M / 128, N / 128), 256, 0, s>>>(A, W, bias, C, M, N, K);
}

extern "C" void kernel_launch(void* const* d_in, const int* in_sizes, int n_in,
                              void* d_out, int out_size, void* d_ws, size_t ws_size,
                              hipStream_t stream) {
  const float* x   = (const float*)d_in[0];
  const float* mem = (const float*)d_in[1];
  const float* sWq = (const float*)d_in[2];  const float* sbq = (const float*)d_in[3];
  const float* sWk = (const float*)d_in[4];  const float* sbk = (const float*)d_in[5];
  const float* sWv = (const float*)d_in[6];  const float* sbv = (const float*)d_in[7];
  const float* sWo = (const float*)d_in[8];  const float* sbo = (const float*)d_in[9];
  const float* cWq = (const float*)d_in[10]; const float* cbq = (const float*)d_in[11];
  const float* cWk = (const float*)d_in[12]; const float* cbk = (const float*)d_in[13];
  const float* cWv = (const float*)d_in[14]; const float* cbv = (const float*)d_in[15];
  const float* cWo = (const float*)d_in[16]; const float* cbo = (const float*)d_in[17];
  const float* W1  = (const float*)d_in[18]; const float* b1  = (const float*)d_in[19];
  const float* W2  = (const float*)d_in[20]; const float* b2  = (const float*)d_in[21];
  const float* g1  = (const float*)d_in[22]; const float* be1 = (const float*)d_in[23];
  const float* g2  = (const float*)d_in[24]; const float* be2 = (const float*)d_in[25];
  const float* g3  = (const float*)d_in[26]; const float* be3 = (const float*)d_in[27];
  float* outp = (float*)d_out;
  char* ws = (char*)d_ws;
  const size_t MB = 1u << 20;

  int*   idx  = (int*)(ws);                 // 320 KB
  float* Mv   = (float*)(ws + 0x60000);     // 256 KB
  int*   Mtop = (int*)(ws + 0xA0000);       // 5 KB
  float* upd  = (float*)(ws + 0xA2000);     // 320 KB
  float* csum = (float*)(ws + 0x100000);    // 128 KB
  float* buf[7];
  for (int i = 0; i < 7; ++i) buf[i] = (float*)(ws + 2 * MB + (size_t)i * 16 * MB);
  // peak ws usage: 2MB + 7*16MB = 114MB
  float* q = buf[0];  float* k = buf[1];  float* v = buf[2];
  float* kT = buf[3]; float* vT = buf[4];
  float* ctx = buf[3];                       // after probAttn, kT is dead
  float* sa = buf[4];
  float* x1 = buf[5];
  float* q2 = buf[0]; float* k2 = buf[1]; float* v2 = buf[2];
  u16* kb16 = (u16*)buf[3];
  u16* vTb  = (u16*)((char*)buf[3] + 8 * MB);
  float* ca = buf[4];
  float* ca2 = buf[1];
  float* x2 = buf[6];
  float* hb = buf[0];                        // 64MB spanning buf0..buf3
  float* yb = buf[4];

  const int MROWS = BATCH * SEQ;  // 4096

  // ---- self attention (ProbSparse) ----
  idx_kernel<<<JAX_PARTITIONABLE ? 320 : 160, 256, 0, stream>>>(idx);
  gemm_hi(x, sWq, sbq, q, MROWS, DMODEL, DMODEL, stream);   // f32-accurate
  gemm_hi(x, sWk, sbk, k, MROWS, DMODEL, DMODEL, stream);   // f32-accurate
  gemm(x, sWv, sbv, v, MROWS, DMODEL, DMODEL, 0, stream);
  probM_kernel<<<BATCH * NHEADS * SEQ / 4, 256, 0, stream>>>(q, k, idx, Mv);
  topk_kernel<<<BATCH * NHEADS, 256, 0, stream>>>(Mv, Mtop);
  transpose_head_f32<<<dim3(BATCH * NHEADS, SEQ / 64), 256, 0, stream>>>(k, kT);
  transpose_head_f32<<<dim3(BATCH * NHEADS, SEQ / 64), 256, 0, stream>>>(v, vT);
  probAttn_kernel<<<dim3(BATCH * NHEADS, 5), 256, 0, stream>>>(q, kT, vT, Mtop, upd);
  scan1_kernel<<<dim3(BATCH * NHEADS, 16), 64, 0, stream>>>(v, ctx, csum);
  scan2_kernel<<<dim3(BATCH * NHEADS, 15), 64, 0, stream>>>(csum, ctx);
  scatter_kernel<<<BATCH * NHEADS * NTOP * EHEAD / 256, 256, 0, stream>>>(upd, Mtop, ctx);
  gemm(ctx, sWo, sbo, sa, MROWS, DMODEL, DMODEL, 0, stream);
  ln_kernel<<<MROWS, 256, 0, stream>>>(x, sa, g1, be1, x1);

  // ---- cross attention ----
  gemm(x1, cWq, cbq, q2, MROWS, DMODEL, DMODEL, 0, stream);
  gemm(mem, cWk, cbk, k2, MROWS, DMODEL, DMODEL, 0, stream);
  gemm(mem, cWv, cbv, v2, MROWS, DMODEL, DMODEL, 0, stream);
  split_head_bf16<<<BATCH * SEQ * DMODEL / 256, 256, 0, stream>>>(k2, kb16);
  transpose_head_bf16<<<dim3(BATCH * NHEADS, SEQ / 64), 256, 0, stream>>>(v2, vTb);
  cross_attn_kernel<<<dim3(BATCH * NHEADS, SEQ / 64), 256, 0, stream>>>(q2, kb16, vTb, ca);
  gemm(ca, cWo, cbo, ca2, MROWS, DMODEL, DMODEL, 0, stream);
  ln_kernel<<<MROWS, 256, 0, stream>>>(x1, ca2, g2, be2, x2);

  // ---- FFN ----
  gemm(x2, W1, b1, hb, MROWS, DFF, DMODEL, 1, stream);
  gemm(hb, W2, b2, yb, MROWS, DMODEL, DFF, 0, stream);
  ln_kernel<<<MROWS, 256, 0, stream>>>(x2, yb, g3, be3, outp);
}

// Round 2
// 979.962 us; speedup vs baseline: 1.2189x; 1.2189x over previous
//
#include <hip/hip_runtime.h>

static constexpr int BATCH  = 2;
static constexpr int SEQ    = 2048;
static constexpr int DMODEL = 1024;
static constexpr int NHEADS = 16;
static constexpr int EHEAD  = 64;
static constexpr int DFF    = 4096;
static constexpr int NTOP   = 40;

typedef unsigned short u16;
typedef __bf16 bf16x8_t __attribute__((ext_vector_type(8)));
typedef u16    u16x8_t  __attribute__((ext_vector_type(8)));
typedef u16    u16x4_t  __attribute__((ext_vector_type(4)));
typedef float  f32x4_t  __attribute__((ext_vector_type(4)));

static __device__ __forceinline__ u16 f2b(float f) {
  unsigned u = __builtin_bit_cast(unsigned, f);
  unsigned r = u + 0x7FFFu + ((u >> 16) & 1u);
  return (u16)(r >> 16);
}
static __device__ __forceinline__ float b2f(u16 h) {
  unsigned u = ((unsigned)h) << 16;
  return __builtin_bit_cast(float, u);
}
static __device__ __forceinline__ f32x4_t mfma_bf16(u16x8_t a, u16x8_t b, f32x4_t c) {
  return __builtin_amdgcn_mfma_f32_16x16x32_bf16(
      __builtin_bit_cast(bf16x8_t, a), __builtin_bit_cast(bf16x8_t, b), c, 0, 0, 0);
}

#define GLD16(gsrc, ldst)                                                        \
  __builtin_amdgcn_global_load_lds(                                             \
      (const __attribute__((address_space(1))) void*)(gsrc),                    \
      (__attribute__((address_space(3))) void*)(ldst), 16, 0, 0)

// ---------------------------------------------------------------- threefry
static __device__ __forceinline__ void tf2x32(unsigned k0, unsigned k1,
                                              unsigned x0, unsigned x1,
                                              unsigned& o0, unsigned& o1) {
  unsigned ks2 = 0x1BD11BDAu ^ k0 ^ k1;
  x0 += k0; x1 += k1;
#define TFR(r) { x0 += x1; x1 = (x1 << r) | (x1 >> (32 - r)); x1 ^= x0; }
  TFR(13) TFR(15) TFR(26) TFR(6)  x0 += k1;  x1 += ks2 + 1u;
  TFR(17) TFR(29) TFR(16) TFR(24) x0 += ks2; x1 += k0 + 2u;
  TFR(13) TFR(15) TFR(26) TFR(6)  x0 += k0;  x1 += k1 + 3u;
  TFR(17) TFR(29) TFR(16) TFR(24) x0 += k1;  x1 += ks2 + 4u;
  TFR(13) TFR(15) TFR(26) TFR(6)  x0 += ks2; x1 += k0 + 5u;
#undef TFR
  o0 = x0; o1 = x1;
}

__global__ __launch_bounds__(256) void idx_kernel(int* __restrict__ idx) {
  int i = blockIdx.x * 256 + threadIdx.x;           // 0..81919, grid 320
  unsigned c0, c1, o0, o1;
  tf2x32(0u, 42u, 0u, 1u, c0, c1);                  // k2 = second split child
  tf2x32(c0, c1, 0u, (unsigned)i, o0, o1);
  idx[i] = (int)((o0 ^ o1) & 2047u);
}

// ---------------------------------------------------------------- prep
// W[K][N] f32 -> Wt[N][K] bf16
__global__ __launch_bounds__(256)
void wt_kernel(const float* __restrict__ in, u16* __restrict__ outp, int K, int N) {
  __shared__ float t[64][65];
  int k0 = blockIdx.y * 64, n0 = blockIdx.x * 64;
  int c = threadIdx.x & 63, r4 = threadIdx.x >> 6;
#pragma unroll
  for (int i = 0; i < 16; ++i) {
    int r = r4 * 16 + i;
    t[r][c] = in[(size_t)(k0 + r) * N + n0 + c];
  }
  __syncthreads();
#pragma unroll
  for (int i = 0; i < 16; ++i) {
    int r = r4 * 16 + i;
    outp[(size_t)(n0 + r) * K + k0 + c] = f2b(t[c][r]);
  }
}

// W[K][N] f32 -> WhT, WlT [N][K] bf16 (Dekker split)
__global__ __launch_bounds__(256)
void wsplit_kernel(const float* __restrict__ in, u16* __restrict__ oh,
                   u16* __restrict__ ol, int K, int N) {
  __shared__ float t[64][65];
  int k0 = blockIdx.y * 64, n0 = blockIdx.x * 64;
  int c = threadIdx.x & 63, r4 = threadIdx.x >> 6;
#pragma unroll
  for (int i = 0; i < 16; ++i) {
    int r = r4 * 16 + i;
    t[r][c] = in[(size_t)(k0 + r) * N + n0 + c];
  }
  __syncthreads();
#pragma unroll
  for (int i = 0; i < 16; ++i) {
    int r = r4 * 16 + i;
    float f = t[c][r];
    u16 h = f2b(f);
    oh[(size_t)(n0 + r) * K + k0 + c] = h;
    ol[(size_t)(n0 + r) * K + k0 + c] = f2b(f - b2f(h));
  }
}

__global__ __launch_bounds__(256)
void conv_kernel(const float* __restrict__ in, u16* __restrict__ outp) {
  int i = blockIdx.x * 256 + threadIdx.x;
  f32x4_t v = *(const f32x4_t*)(in + (size_t)i * 4);
  u16x4_t o;
  o[0] = f2b(v[0]); o[1] = f2b(v[1]); o[2] = f2b(v[2]); o[3] = f2b(v[3]);
  *(u16x4_t*)(outp + (size_t)i * 4) = o;
}

__global__ __launch_bounds__(256)
void split_kernel(const float* __restrict__ in, u16* __restrict__ oh,
                  u16* __restrict__ ol) {
  int i = blockIdx.x * 256 + threadIdx.x;
  f32x4_t v = *(const f32x4_t*)(in + (size_t)i * 4);
  u16x4_t h, l;
#pragma unroll
  for (int d = 0; d < 4; ++d) {
    u16 hh = f2b(v[d]); h[d] = hh; l[d] = f2b(v[d] - b2f(hh));
  }
  *(u16x4_t*)(oh + (size_t)i * 4) = h;
  *(u16x4_t*)(ol + (size_t)i * 4) = l;
}

// ---------------------------------------------------------------- bf16 GEMM
// C[M,N] = A_bf[M,K] @ Bt_bf[N,K]^T + bias. 128x64 tile, BK=32, dbuf + gload_lds.
// Involutive source-side swizzle: L = P ^ (((P>>7)&3)<<4)  (XOR byte bits 4,5).
__global__ __launch_bounds__(256)
void gemm_bf(const u16* __restrict__ A, const u16* __restrict__ Bt,
             const float* __restrict__ bias, float* __restrict__ Cf,
             u16* __restrict__ Cb, int M, int N, int K, int relu) {
  __shared__ __align__(16) u16 sA[2][128 * 32];
  __shared__ __align__(16) u16 sB[2][64 * 32];
  const int tid = threadIdx.x;
  const int wave = tid >> 6, lane = tid & 63;
  const int m0 = blockIdx.x * 128, n0 = blockIdx.y * 64;
  const int wr = (wave >> 1) * 64, wc = (wave & 1) * 32;
  const int lr = lane & 15, kg = lane >> 4;
  const int wv = __builtin_amdgcn_readfirstlane(wave);

  // staging source coords (logical <- physical, involution)
  int rowA[2], c8A[2];
#pragma unroll
  for (int rep = 0; rep < 2; ++rep) {
    int P = (rep * 256 + tid) << 4;
    int L = P ^ (((P >> 7) & 3) << 4);
    rowA[rep] = L >> 6; c8A[rep] = (L >> 4) & 3;
  }
  int rowB, c8B;
  {
    int P = tid << 4;
    int L = P ^ (((P >> 7) & 3) << 4);
    rowB = L >> 6; c8B = (L >> 4) & 3;
  }

  f32x4_t acc[4][2];
#pragma unroll
  for (int i = 0; i < 4; ++i)
#pragma unroll
    for (int j = 0; j < 2; ++j) acc[i][j] = f32x4_t{0.f, 0.f, 0.f, 0.f};

  auto STAGE = [&](int buf, int k0) {
#pragma unroll
    for (int rep = 0; rep < 2; ++rep)
      GLD16(A + (size_t)(m0 + rowA[rep]) * K + k0 + c8A[rep] * 8,
            &sA[buf][(rep * 256 + wv * 64) * 8]);
    GLD16(Bt + (size_t)(n0 + rowB) * K + k0 + c8B * 8,
          &sB[buf][(wv * 64) * 8]);
  };

  const int nk = K >> 5;
  STAGE(0, 0);
  __syncthreads();
  for (int t = 0; t < nk; ++t) {
    const int cur = t & 1;
    if (t + 1 < nk) STAGE(cur ^ 1, (t + 1) << 5);
    u16x8_t a8[4], b8[2];
#pragma unroll
    for (int mi = 0; mi < 4; ++mi) {
      int La = (wr + mi * 16 + lr) * 64 + kg * 16;
      a8[mi] = *(const u16x8_t*)((const char*)sA[cur] + (La ^ (((La >> 7) & 3) << 4)));
    }
#pragma unroll
    for (int ni = 0; ni < 2; ++ni) {
      int Lb = (wc + ni * 16 + lr) * 64 + kg * 16;
      b8[ni] = *(const u16x8_t*)((const char*)sB[cur] + (Lb ^ (((Lb >> 7) & 3) << 4)));
    }
#pragma unroll
    for (int mi = 0; mi < 4; ++mi)
#pragma unroll
      for (int ni = 0; ni < 2; ++ni)
        acc[mi][ni] = mfma_bf16(a8[mi], b8[ni], acc[mi][ni]);
    __syncthreads();
  }
#pragma unroll
  for (int ni = 0; ni < 2; ++ni) {
    int col = n0 + wc + ni * 16 + lr;
    float bc = bias[col];
#pragma unroll
    for (int mi = 0; mi < 4; ++mi)
#pragma unroll
      for (int r = 0; r < 4; ++r) {
        int row = m0 + wr + mi * 16 + kg * 4 + r;
        float vv = acc[mi][ni][r] + bc;
        if (relu) vv = fmaxf(vv, 0.f);
        if (Cf) Cf[(size_t)row * N + col] = vv;
        if (Cb) Cb[(size_t)row * N + col] = f2b(vv);
      }
  }
}

// 4-term split GEMM (f32-equivalent) from pre-split bf16 inputs.
__global__ __launch_bounds__(256)
void gemm4_bf(const u16* __restrict__ Ah, const u16* __restrict__ Al,
              const u16* __restrict__ Bh, const u16* __restrict__ Bl,
              const float* __restrict__ bias, float* __restrict__ Cf,
              int M, int N, int K) {
  __shared__ __align__(16) u16 sAh[2][128 * 32];
  __shared__ __align__(16) u16 sAl[2][128 * 32];
  __shared__ __align__(16) u16 sBh[2][64 * 32];
  __shared__ __align__(16) u16 sBl[2][64 * 32];
  const int tid = threadIdx.x;
  const int wave = tid >> 6, lane = tid & 63;
  const int m0 = blockIdx.x * 128, n0 = blockIdx.y * 64;
  const int wr = (wave >> 1) * 64, wc = (wave & 1) * 32;
  const int lr = lane & 15, kg = lane >> 4;
  const int wv = __builtin_amdgcn_readfirstlane(wave);

  int rowA[2], c8A[2];
#pragma unroll
  for (int rep = 0; rep < 2; ++rep) {
    int P = (rep * 256 + tid) << 4;
    int L = P ^ (((P >> 7) & 3) << 4);
    rowA[rep] = L >> 6; c8A[rep] = (L >> 4) & 3;
  }
  int rowB, c8B;
  {
    int P = tid << 4;
    int L = P ^ (((P >> 7) & 3) << 4);
    rowB = L >> 6; c8B = (L >> 4) & 3;
  }

  f32x4_t acc[4][2];
#pragma unroll
  for (int i = 0; i < 4; ++i)
#pragma unroll
    for (int j = 0; j < 2; ++j) acc[i][j] = f32x4_t{0.f, 0.f, 0.f, 0.f};

  auto STAGE = [&](int buf, int k0) {
#pragma unroll
    for (int rep = 0; rep < 2; ++rep) {
      GLD16(Ah + (size_t)(m0 + rowA[rep]) * K + k0 + c8A[rep] * 8,
            &sAh[buf][(rep * 256 + wv * 64) * 8]);
      GLD16(Al + (size_t)(m0 + rowA[rep]) * K + k0 + c8A[rep] * 8,
            &sAl[buf][(rep * 256 + wv * 64) * 8]);
    }
    GLD16(Bh + (size_t)(n0 + rowB) * K + k0 + c8B * 8, &sBh[buf][(wv * 64) * 8]);
    GLD16(Bl + (size_t)(n0 + rowB) * K + k0 + c8B * 8, &sBl[buf][(wv * 64) * 8]);
  };

  const int nk = K >> 5;
  STAGE(0, 0);
  __syncthreads();
  for (int t = 0; t < nk; ++t) {
    const int cur = t & 1;
    if (t + 1 < nk) STAGE(cur ^ 1, (t + 1) << 5);
    u16x8_t ah[4], al[4], bh[2], bl[2];
#pragma unroll
    for (int mi = 0; mi < 4; ++mi) {
      int La = (wr + mi * 16 + lr) * 64 + kg * 16;
      int off = La ^ (((La >> 7) & 3) << 4);
      ah[mi] = *(const u16x8_t*)((const char*)sAh[cur] + off);
      al[mi] = *(const u16x8_t*)((const char*)sAl[cur] + off);
    }
#pragma unroll
    for (int ni = 0; ni < 2; ++ni) {
      int Lb = (wc + ni * 16 + lr) * 64 + kg * 16;
      int off = Lb ^ (((Lb >> 7) & 3) << 4);
      bh[ni] = *(const u16x8_t*)((const char*)sBh[cur] + off);
      bl[ni] = *(const u16x8_t*)((const char*)sBl[cur] + off);
    }
#pragma unroll
    for (int mi = 0; mi < 4; ++mi)
#pragma unroll
      for (int ni = 0; ni < 2; ++ni) {
        acc[mi][ni] = mfma_bf16(ah[mi], bh[ni], acc[mi][ni]);
        acc[mi][ni] = mfma_bf16(ah[mi], bl[ni], acc[mi][ni]);
        acc[mi][ni] = mfma_bf16(al[mi], bh[ni], acc[mi][ni]);
        acc[mi][ni] = mfma_bf16(al[mi], bl[ni], acc[mi][ni]);
      }
    __syncthreads();
  }
#pragma unroll
  for (int ni = 0; ni < 2; ++ni) {
    int col = n0 + wc + ni * 16 + lr;
    float bc = bias[col];
#pragma unroll
    for (int mi = 0; mi < 4; ++mi)
#pragma unroll
      for (int r = 0; r < 4; ++r) {
        int row = m0 + wr + mi * 16 + kg * 4 + r;
        Cf[(size_t)row * N + col] = acc[mi][ni][r] + bc;
      }
  }
}

// ---------------------------------------------------------------- ProbSparse
__global__ __launch_bounds__(256)
void probM_kernel(const float* __restrict__ q, const float* __restrict__ k,
                  const int* __restrict__ idx, float* __restrict__ Mv) {
  int gw = blockIdx.x * 4 + (threadIdx.x >> 6);
  int lane = threadIdx.x & 63;
  int l = gw & (SEQ - 1);
  int hh = (gw >> 11) & (NHEADS - 1);
  int b = gw >> 15;
  float qv = q[((size_t)b * SEQ + l) * DMODEL + hh * EHEAD + lane];
  const int* ip = idx + l * NTOP;
  float mmax = -3.0e38f, msum = 0.f;
  for (int u = 0; u < NTOP; ++u) {
    int ki = ip[u];
    float p = qv * k[((size_t)b * SEQ + ki) * DMODEL + hh * EHEAD + lane];
#pragma unroll
    for (int m = 1; m < 64; m <<= 1) p += __shfl_xor(p, m);
    mmax = fmaxf(mmax, p);
    msum += p;
  }
  if (lane == 0) Mv[gw] = mmax - msum * (1.f / 2048.f);
}

__global__ __launch_bounds__(256)
void topk_kernel(const float* __restrict__ Mv, int* __restrict__ Mtop) {
  int bh = blockIdx.x;
  int tid = threadIdx.x;
  __shared__ float vals[2048];
  __shared__ float rv[256];
  __shared__ int ri[256];
  for (int j = tid; j < 2048; j += 256) vals[j] = Mv[bh * 2048 + j];
  __syncthreads();
  for (int it = 0; it < NTOP; ++it) {
    float best = -3.0e38f;
    int bi = 1 << 30;
    for (int j = tid; j < 2048; j += 256) {
      float vv = vals[j];
      if (vv > best) { best = vv; bi = j; }
    }
    rv[tid] = best; ri[tid] = bi;
    __syncthreads();
    for (int st = 128; st > 0; st >>= 1) {
      if (tid < st) {
        if (rv[tid + st] > rv[tid] ||
            (rv[tid + st] == rv[tid] && ri[tid + st] < ri[tid])) {
          rv[tid] = rv[tid + st]; ri[tid] = ri[tid + st];
        }
      }
      __syncthreads();
    }
    if (tid == 0) { Mtop[bh * NTOP + it] = ri[0]; vals[ri[0]] = -3.4e38f; }
    __syncthreads();
  }
}

// transpose [B][L][h*64+e] f32 -> [bh][e][L] bf16
__global__ __launch_bounds__(256)
void th_f32_bf16(const float* __restrict__ in, u16* __restrict__ outp) {
  int bh = blockIdx.x;
  int b = bh >> 4, hh = bh & 15;
  int l0 = blockIdx.y * 64;
  __shared__ float t[64][65];
  int c = threadIdx.x & 63, r4 = threadIdx.x >> 6;
  for (int i = 0; i < 16; ++i) {
    int row = r4 * 16 + i;
    t[row][c] = in[((size_t)b * SEQ + l0 + row) * DMODEL + hh * EHEAD + c];
  }
  __syncthreads();
  for (int i = 0; i < 16; ++i) {
    int er = r4 * 16 + i;
    outp[((size_t)bh * EHEAD + er) * SEQ + l0 + c] = f2b(t[c][er]);
  }
}

// transpose [B][L][h*64+e] bf16 -> [bh][e][L] bf16
__global__ __launch_bounds__(256)
void th_bf16_bf16(const u16* __restrict__ in, u16* __restrict__ outp) {
  int bh = blockIdx.x;
  int b = bh >> 4, hh = bh & 15;
  int l0 = blockIdx.y * 64;
  __shared__ u16 t[64][65];
  int c = threadIdx.x & 63, r4 = threadIdx.x >> 6;
  for (int i = 0; i < 16; ++i) {
    int row = r4 * 16 + i;
    t[row][c] = in[((size_t)b * SEQ + l0 + row) * DMODEL + hh * EHEAD + c];
  }
  __syncthreads();
  for (int i = 0; i < 16; ++i) {
    int er = r4 * 16 + i;
    outp[((size_t)bh * EHEAD + er) * SEQ + l0 + c] = t[c][er];
  }
}

// attention for the selected 40 queries/head. grid (BH, 5), wave = 2 queries.
__global__ __launch_bounds__(256)
void probAttn_kernel(const float* __restrict__ q, const u16* __restrict__ kT,
                     const u16* __restrict__ vT, const int* __restrict__ Mtop,
                     float* __restrict__ upd) {
  int bh = blockIdx.x, b = bh >> 4, hh = bh & 15;
  int wave = threadIdx.x >> 6, lane = threadIdx.x & 63;
  int qg = blockIdx.y * 8 + wave * 2;
  int i0 = Mtop[bh * NTOP + qg], i1 = Mtop[bh * NTOP + qg + 1];
  float qv0 = q[((size_t)b * SEQ + i0) * DMODEL + hh * EHEAD + lane];
  float qv1 = q[((size_t)b * SEQ + i1) * DMODEL + hh * EHEAD + lane];
  const u16* kb = kT + (size_t)bh * EHEAD * SEQ;
  const u16* vb = vT + (size_t)bh * EHEAD * SEQ;
  float s0[32], s1[32];
#pragma unroll
  for (int kk = 0; kk < 32; ++kk) { s0[kk] = 0.f; s1[kk] = 0.f; }
  for (int e = 0; e < 64; ++e) {
    float qe0 = __shfl(qv0, e), qe1 = __shfl(qv1, e);
    const u16* kr = kb + (size_t)e * SEQ;
#pragma unroll
    for (int kk = 0; kk < 32; ++kk) {
      float kv = b2f(kr[kk * 64 + lane]);
      s0[kk] += qe0 * kv; s1[kk] += qe1 * kv;
    }
  }
  float m0 = -3e38f, m1 = -3e38f;
#pragma unroll
  for (int kk = 0; kk < 32; ++kk) {
    int key = kk * 64 + lane;
    s0[kk] = (key > i0) ? -1e9f : s0[kk] * 0.125f;
    s1[kk] = (key > i1) ? -1e9f : s1[kk] * 0.125f;
    m0 = fmaxf(m0, s0[kk]); m1 = fmaxf(m1, s1[kk]);
  }
#pragma unroll
  for (int m = 1; m < 64; m <<= 1) {
    m0 = fmaxf(m0, __shfl_xor(m0, m));
    m1 = fmaxf(m1, __shfl_xor(m1, m));
  }
  float sum0 = 0.f, sum1 = 0.f;
#pragma unroll
  for (int kk = 0; kk < 32; ++kk) {
    s0[kk] = __expf(s0[kk] - m0); sum0 += s0[kk];
    s1[kk] = __expf(s1[kk] - m1); sum1 += s1[kk];
  }
#pragma unroll
  for (int m = 1; m < 64; m <<= 1) {
    sum0 += __shfl_xor(sum0, m);
    sum1 += __shfl_xor(sum1, m);
  }
  float o0 = 0.f, o1 = 0.f;
  for (int e = 0; e < 64; ++e) {
    const u16* vr = vb + (size_t)e * SEQ;
    float a0 = 0.f, a1 = 0.f;
#pragma unroll
    for (int kk = 0; kk < 32; ++kk) {
      float vv = b2f(vr[kk * 64 + lane]);
      a0 += s0[kk] * vv; a1 += s1[kk] * vv;
    }
#pragma unroll
    for (int m = 1; m < 64; m <<= 1) {
      a0 += __shfl_xor(a0, m);
      a1 += __shfl_xor(a1, m);
    }
    if (lane == e) { o0 = a0; o1 = a1; }
  }
  upd[((size_t)bh * NTOP + qg) * EHEAD + lane] = o0 / sum0;
  upd[((size_t)bh * NTOP + qg + 1) * EHEAD + lane] = o1 / sum1;
}

// cumsum over l from bf16 v, f32 accum / f32 ctx out.
__global__ __launch_bounds__(64)
void scan1_kernel(const u16* __restrict__ v, float* __restrict__ ctx,
                  float* __restrict__ csum) {
  int bh = blockIdx.x, c = blockIdx.y;
  int b = bh >> 4, hh = bh & 15, e = threadIdx.x;
  size_t base = ((size_t)b * SEQ + c * 128) * DMODEL + hh * EHEAD + e;
  float run = 0.f;
  for (int i = 0; i < 128; ++i) {
    run += b2f(v[base + (size_t)i * DMODEL]);
    ctx[base + (size_t)i * DMODEL] = run;
  }
  csum[(bh * 16 + c) * 64 + e] = run;
}
__global__ __launch_bounds__(64)
void scan2_kernel(const float* __restrict__ csum, float* __restrict__ ctx) {
  int bh = blockIdx.x, c = blockIdx.y + 1;
  int b = bh >> 4, hh = bh & 15, e = threadIdx.x;
  float off = 0.f;
  for (int cc = 0; cc < c; ++cc) off += csum[(bh * 16 + cc) * 64 + e];
  size_t base = ((size_t)b * SEQ + c * 128) * DMODEL + hh * EHEAD + e;
  for (int i = 0; i < 128; ++i) ctx[base + (size_t)i * DMODEL] += off;
}

__global__ __launch_bounds__(256)
void scatter_kernel(const float* __restrict__ upd, const int* __restrict__ Mtop,
                    float* __restrict__ ctx) {
  int i = blockIdx.x * 256 + threadIdx.x;  // < 81920
  int e = i & 63;
  int t = i >> 6;          // bh*40+u
  int bh = t / NTOP;
  int b = bh >> 4, hh = bh & 15;
  int row = Mtop[t];
  ctx[((size_t)b * SEQ + row) * DMODEL + hh * EHEAD + e] = upd[i];
}

// ---------------------------------------------------------------- cross attn
// flash attention, 64-q tile, 4 waves x 16 q, 128-key chunks, MFMA, bf16 out.
__global__ __launch_bounds__(256)
void cross_attn_kernel(const float* __restrict__ q2, const u16* __restrict__ k2b,
                       const u16* __restrict__ vTb, u16* __restrict__ cab) {
  int bh = blockIdx.x, b = bh >> 4, hh = bh & 15;
  int qt0 = blockIdx.y * 64;
  int tid = threadIdx.x, wave = tid >> 6, lane = tid & 63;
  int lr = lane & 15, kg = lane >> 4;
  __shared__ __align__(16) u16 Qs[64 * 64];
  __shared__ __align__(16) u16 Ps[4][16 * 128];
#pragma unroll
  for (int i = 0; i < 4; ++i) {   // stage Q (scaled by 1/8) bf16 swizzled
    int j = tid + 256 * i;
    int row = j >> 4, c4 = j & 15;
    f32x4_t v4 = *(const f32x4_t*)(q2 + ((size_t)b * SEQ + qt0 + row) * DMODEL + hh * EHEAD + c4 * 4);
    u16x4_t b4;
    b4[0] = f2b(v4[0] * 0.125f); b4[1] = f2b(v4[1] * 0.125f);
    b4[2] = f2b(v4[2] * 0.125f); b4[3] = f2b(v4[3] * 0.125f);
    *(u16x4_t*)((char*)Qs + ((row * 128 + c4 * 8) ^ ((row & 7) << 4))) = b4;
  }
  __syncthreads();
  u16x8_t aq[2];
  {
    int qrow = wave * 16 + lr;
#pragma unroll
    for (int ks = 0; ks < 2; ++ks)
      aq[ks] = *(u16x8_t*)((char*)Qs + ((qrow * 128 + ks * 64 + kg * 16) ^ ((qrow & 7) << 4)));
  }
  const u16* kbase = k2b + ((size_t)b * SEQ) * DMODEL + hh * EHEAD;  // [key][e] stride 1024
  const u16* vbase = vTb + (size_t)bh * EHEAD * SEQ;                 // [e][key]
  f32x4_t oacc[4];
#pragma unroll
  for (int i = 0; i < 4; ++i) oacc[i] = f32x4_t{0.f, 0.f, 0.f, 0.f};
  float mrun[4] = {-3e38f, -3e38f, -3e38f, -3e38f};
  float lrun[4] = {0.f, 0.f, 0.f, 0.f};
  u16* pw = &Ps[wave][0];

  for (int kt = 0; kt < SEQ; kt += 128) {
    f32x4_t s[8];
#pragma unroll
    for (int i = 0; i < 8; ++i) s[i] = f32x4_t{0.f, 0.f, 0.f, 0.f};
#pragma unroll
    for (int ks = 0; ks < 2; ++ks) {
#pragma unroll
      for (int nt = 0; nt < 8; ++nt) {
        int key = kt + nt * 16 + lr;
        u16x8_t bk = *(const u16x8_t*)(kbase + (size_t)key * DMODEL + ks * 32 + kg * 8);
        s[nt] = mfma_bf16(aq[ks], bk, s[nt]);
      }
    }
    float al[4];
#pragma unroll
    for (int r = 0; r < 4; ++r) {
      float mx = s[0][r];
#pragma unroll
      for (int nt = 1; nt < 8; ++nt) mx = fmaxf(mx, s[nt][r]);
#pragma unroll
      for (int m = 1; m < 16; m <<= 1) mx = fmaxf(mx, __shfl_xor(mx, m));
      float mnew = fmaxf(mrun[r], mx);
      float a = __expf(mrun[r] - mnew);
      float sum = 0.f;
#pragma unroll
      for (int nt = 0; nt < 8; ++nt) {
        float p = __expf(s[nt][r] - mnew);
        s[nt][r] = p; sum += p;
      }
#pragma unroll
      for (int m = 1; m < 16; m <<= 1) sum += __shfl_xor(sum, m);
      lrun[r] = lrun[r] * a + sum;
      mrun[r] = mnew;
      al[r] = a;
    }
#pragma unroll
    for (int ne = 0; ne < 4; ++ne)
#pragma unroll
      for (int r = 0; r < 4; ++r) oacc[ne][r] *= al[r];
    // P (C-layout) -> LDS bf16 [16 q][128 key], XOR bits 4-6 with q-row
#pragma unroll
    for (int nt = 0; nt < 8; ++nt)
#pragma unroll
      for (int r = 0; r < 4; ++r) {
        int qq = kg * 4 + r;
        int L = qq * 256 + (nt * 16 + lr) * 2;
        *(u16*)((char*)pw + (L ^ ((qq & 7) << 4))) = f2b(s[nt][r]);
      }
#pragma unroll
    for (int ks2 = 0; ks2 < 4; ++ks2) {
      int L = lr * 256 + ks2 * 64 + kg * 16;
      u16x8_t ap = *(u16x8_t*)((char*)pw + (L ^ ((lr & 7) << 4)));
#pragma unroll
      for (int ne = 0; ne < 4; ++ne) {
        int e = ne * 16 + lr;
        u16x8_t bv = *(const u16x8_t*)(vbase + (size_t)e * SEQ + kt + ks2 * 32 + kg * 8);
        oacc[ne] = mfma_bf16(ap, bv, oacc[ne]);
      }
    }
  }
#pragma unroll
  for (int ne = 0; ne < 4; ++ne)
#pragma unroll
    for (int r = 0; r < 4; ++r) {
      int row = qt0 + wave * 16 + kg * 4 + r;
      int col = hh * EHEAD + ne * 16 + lr;
      cab[((size_t)b * SEQ + row) * DMODEL + col] = f2b(oacc[ne][r] / lrun[r]);
    }
}

// ---------------------------------------------------------------- layernorm
__global__ __launch_bounds__(256)
void ln_kernel(const float* __restrict__ x, const float* __restrict__ r,
               const float* __restrict__ g, const float* __restrict__ be,
               float* __restrict__ outf, u16* __restrict__ outb) {
  int row = blockIdx.x, tid = threadIdx.x;
  size_t base = (size_t)row * DMODEL;
  float v[4];
  float s = 0.f, sq = 0.f;
#pragma unroll
  for (int i = 0; i < 4; ++i) {
    int c = tid + i * 256;
    float t = x[base + c] + r[base + c];
    v[i] = t; s += t; sq += t * t;
  }
  __shared__ float rs[256], rq[256];
  rs[tid] = s; rq[tid] = sq;
  __syncthreads();
  for (int st = 128; st > 0; st >>= 1) {
    if (tid < st) { rs[tid] += rs[tid + st]; rq[tid] += rq[tid + st]; }
    __syncthreads();
  }
  float mean = rs[0] * (1.f / DMODEL);
  float var = rq[0] * (1.f / DMODEL) - mean * mean;
  float rstd = rsqrtf(var + 1e-5f);
#pragma unroll
  for (int i = 0; i < 4; ++i) {
    int c = tid + i * 256;
    float o = (v[i] - mean) * rstd * g[c] + be[c];
    if (outf) outf[base + c] = o;
    if (outb) outb[base + c] = f2b(o);
  }
}

// ---------------------------------------------------------------- host side
static inline void gemm(const u16* A, const u16* Bt, const float* bias, float* Cf,
                        u16* Cb, int M, int N, int K, int relu, hipStream_t s) {
  gemm_bf<<<dim3(M / 128, N / 64), 256, 0, s>>>(A, Bt, bias, Cf, Cb, M, N, K, relu);
}
static inline void gemm4(const u16* Ah, const u16* Al, const u16* Bh, const u16* Bl,
                         const float* bias, float* Cf, int M, int N, int K, hipStream_t s) {
  gemm4_bf<<<dim3(M / 128, N / 64), 256, 0, s>>>(Ah, Al, Bh, Bl, bias, Cf, M, N, K);
}

extern "C" void kernel_launch(void* const* d_in, const int* in_sizes, int n_in,
                              void* d_out, int out_size, void* d_ws, size_t ws_size,
                              hipStream_t stream) {
  const float* x   = (const float*)d_in[0];
  const float* mem = (const float*)d_in[1];
  const float* sWq = (const float*)d_in[2];  const float* sbq = (const float*)d_in[3];
  const float* sWk = (const float*)d_in[4];  const float* sbk = (const float*)d_in[5];
  const float* sWv = (const float*)d_in[6];  const float* sbv = (const float*)d_in[7];
  const float* sWo = (const float*)d_in[8];  const float* sbo = (const float*)d_in[9];
  const float* cWq = (const float*)d_in[10]; const float* cbq = (const float*)d_in[11];
  const float* cWk = (const float*)d_in[12]; const float* cbk = (const float*)d_in[13];
  const float* cWv = (const float*)d_in[14]; const float* cbv = (const float*)d_in[15];
  const float* cWo = (const float*)d_in[16]; const float* cbo = (const float*)d_in[17];
  const float* W1  = (const float*)d_in[18]; const float* b1  = (const float*)d_in[19];
  const float* W2  = (const float*)d_in[20]; const float* b2  = (const float*)d_in[21];
  const float* g1  = (const float*)d_in[22]; const float* be1 = (const float*)d_in[23];
  const float* g2  = (const float*)d_in[24]; const float* be2 = (const float*)d_in[25];
  const float* g3  = (const float*)d_in[26]; const float* be3 = (const float*)d_in[27];
  float* outp = (float*)d_out;
  char* ws = (char*)d_ws;
  const size_t MB = 1ull << 20;

  int*   idx  = (int*)(ws);
  float* Mv   = (float*)(ws + 0x60000);
  int*   Mtop = (int*)(ws + 0xA0000);
  float* upd  = (float*)(ws + 0xA2000);
  float* csum = (float*)(ws + 0x100000);

  u16* WqhT = (u16*)(ws + 2 * MB);   u16* WqlT = (u16*)(ws + 4 * MB);
  u16* WkhT = (u16*)(ws + 6 * MB);   u16* WklT = (u16*)(ws + 8 * MB);
  u16* sWvT = (u16*)(ws + 10 * MB);  u16* sWoT = (u16*)(ws + 12 * MB);
  u16* cWqT = (u16*)(ws + 14 * MB);  u16* cWkT = (u16*)(ws + 16 * MB);
  u16* cWvT = (u16*)(ws + 18 * MB);  u16* cWoT = (u16*)(ws + 20 * MB);
  u16* W1T  = (u16*)(ws + 22 * MB);  u16* W2T  = (u16*)(ws + 30 * MB);
  u16* xh   = (u16*)(ws + 38 * MB);  u16* xl   = (u16*)(ws + 46 * MB);
  u16* memb = (u16*)(ws + 54 * MB);

  float* q    = (float*)(ws + 62 * MB);   // dead after probAttn
  float* k    = (float*)(ws + 78 * MB);   // dead after th_f32_bf16
  float* ctxf = (float*)(ws + 78 * MB);
  u16*   vbf  = (u16*)(ws + 94 * MB);
  u16*   kTb  = (u16*)(ws + 102 * MB);
  u16*   vTb  = (u16*)(ws + 46 * MB);     // reuse xl
  u16*   ctxb = (u16*)(ws + 62 * MB);     // reuse q
  float* sa   = (float*)(ws + 94 * MB);   // reuse vbf+kTb
  float* x1   = (float*)(ws + 62 * MB);
  u16*   x1b  = (u16*)(ws + 78 * MB);
  float* q2   = (float*)(ws + 86 * MB);
  u16*   k2b  = (u16*)(ws + 102 * MB);
  u16*   v2b  = (u16*)(ws + 46 * MB);
  u16*   vT2b = (u16*)(ws + 54 * MB);     // reuse memb
  u16*   cab  = (u16*)(ws + 46 * MB);
  float* ca2  = (float*)(ws + 86 * MB);
  float* x2   = (float*)(ws + 38 * MB);
  u16*   x2b  = (u16*)(ws + 54 * MB);
  u16*   hbb  = (u16*)(ws + 78 * MB);     // 32MB [78,110)
  float* yb   = (float*)(ws + 62 * MB);

  const int MROWS = BATCH * SEQ;  // 4096

  // ---- prep: RNG, weight transposes, input conversions ----
  idx_kernel<<<320, 256, 0, stream>>>(idx);
  wsplit_kernel<<<dim3(16, 16), 256, 0, stream>>>(sWq, WqhT, WqlT, 1024, 1024);
  wsplit_kernel<<<dim3(16, 16), 256, 0, stream>>>(sWk, WkhT, WklT, 1024, 1024);
  wt_kernel<<<dim3(16, 16), 256, 0, stream>>>(sWv, sWvT, 1024, 1024);
  wt_kernel<<<dim3(16, 16), 256, 0, stream>>>(sWo, sWoT, 1024, 1024);
  wt_kernel<<<dim3(16, 16), 256, 0, stream>>>(cWq, cWqT, 1024, 1024);
  wt_kernel<<<dim3(16, 16), 256, 0, stream>>>(cWk, cWkT, 1024, 1024);
  wt_kernel<<<dim3(16, 16), 256, 0, stream>>>(cWv, cWvT, 1024, 1024);
  wt_kernel<<<dim3(16, 16), 256, 0, stream>>>(cWo, cWoT, 1024, 1024);
  wt_kernel<<<dim3(64, 16), 256, 0, stream>>>(W1, W1T, 1024, 4096);
  wt_kernel<<<dim3(16, 64), 256, 0, stream>>>(W2, W2T, 4096, 1024);
  split_kernel<<<4096, 256, 0, stream>>>(x, xh, xl);
  conv_kernel<<<4096, 256, 0, stream>>>(mem, memb);

  // ---- self attention (ProbSparse) ----
  gemm4(xh, xl, WqhT, WqlT, sbq, q, MROWS, DMODEL, DMODEL, stream);
  gemm4(xh, xl, WkhT, WklT, sbk, k, MROWS, DMODEL, DMODEL, stream);
  gemm(xh, sWvT, sbv, nullptr, vbf, MROWS, DMODEL, DMODEL, 0, stream);
  probM_kernel<<<BATCH * NHEADS * SEQ / 4, 256, 0, stream>>>(q, k, idx, Mv);
  topk_kernel<<<BATCH * NHEADS, 256, 0, stream>>>(Mv, Mtop);
  th_f32_bf16<<<dim3(BATCH * NHEADS, SEQ / 64), 256, 0, stream>>>(k, kTb);
  th_bf16_bf16<<<dim3(BATCH * NHEADS, SEQ / 64), 256, 0, stream>>>(vbf, vTb);
  probAttn_kernel<<<dim3(BATCH * NHEADS, 5), 256, 0, stream>>>(q, kTb, vTb, Mtop, upd);
  scan1_kernel<<<dim3(BATCH * NHEADS, 16), 64, 0, stream>>>(vbf, ctxf, csum);
  scan2_kernel<<<dim3(BATCH * NHEADS, 15), 64, 0, stream>>>(csum, ctxf);
  scatter_kernel<<<BATCH * NHEADS * NTOP * EHEAD / 256, 256, 0, stream>>>(upd, Mtop, ctxf);
  conv_kernel<<<4096, 256, 0, stream>>>(ctxf, ctxb);
  gemm(ctxb, sWoT, sbo, sa, nullptr, MROWS, DMODEL, DMODEL, 0, stream);
  ln_kernel<<<MROWS, 256, 0, stream>>>(x, sa, g1, be1, x1, x1b);

  // ---- cross attention ----
  gemm(x1b, cWqT, cbq, q2, nullptr, MROWS, DMODEL, DMODEL, 0, stream);
  gemm(memb, cWkT, cbk, nullptr, k2b, MROWS, DMODEL, DMODEL, 0, stream);
  gemm(memb, cWvT, cbv, nullptr, v2b, MROWS, DMODEL, DMODEL, 0, stream);
  th_bf16_bf16<<<dim3(BATCH * NHEADS, SEQ / 64), 256, 0, stream>>>(v2b, vT2b);
  cross_attn_kernel<<<dim3(BATCH * NHEADS, SEQ / 64), 256, 0, stream>>>(q2, k2b, vT2b, cab);
  gemm(cab, cWoT, cbo, ca2, nullptr, MROWS, DMODEL, DMODEL, 0, stream);
  ln_kernel<<<MROWS, 256, 0, stream>>>(x1, ca2, g2, be2, x2, x2b);

  // ---- FFN ----
  gemm(x2b, W1T, b1, nullptr, hbb, MROWS, DFF, DMODEL, 1, stream);
  gemm(hbb, W2T, b2, yb, nullptr, MROWS, DMODEL, DFF, 0, stream);
  ln_kernel<<<MROWS, 256, 0, stream>>>(x2, yb, g3, be3, outp, nullptr);
}

// Round 3
// 810.617 us; speedup vs baseline: 1.4736x; 1.2089x over previous
//
#include <hip/hip_runtime.h>

static constexpr int BATCH  = 2;
static constexpr int SEQ    = 2048;
static constexpr int DMODEL = 1024;
static constexpr int NHEADS = 16;
static constexpr int EHEAD  = 64;
static constexpr int DFF    = 4096;
static constexpr int NTOP   = 40;

typedef unsigned short u16;
typedef __bf16 bf16x8_t __attribute__((ext_vector_type(8)));
typedef u16    u16x8_t  __attribute__((ext_vector_type(8)));
typedef u16    u16x4_t  __attribute__((ext_vector_type(4)));
typedef float  f32x4_t  __attribute__((ext_vector_type(4)));

static __device__ __forceinline__ u16 f2b(float f) {
  unsigned u = __builtin_bit_cast(unsigned, f);
  unsigned r = u + 0x7FFFu + ((u >> 16) & 1u);
  return (u16)(r >> 16);
}
static __device__ __forceinline__ float b2f(u16 h) {
  unsigned u = ((unsigned)h) << 16;
  return __builtin_bit_cast(float, u);
}
static __device__ __forceinline__ f32x4_t mfma_bf16(u16x8_t a, u16x8_t b, f32x4_t c) {
  return __builtin_amdgcn_mfma_f32_16x16x32_bf16(
      __builtin_bit_cast(bf16x8_t, a), __builtin_bit_cast(bf16x8_t, b), c, 0, 0, 0);
}

#define GLD16(gsrc, ldst)                                                        \
  __builtin_amdgcn_global_load_lds(                                             \
      (const __attribute__((address_space(1))) void*)(gsrc),                    \
      (__attribute__((address_space(3))) void*)(ldst), 16, 0, 0)

// ---------------------------------------------------------------- threefry
static __device__ __forceinline__ void tf2x32(unsigned k0, unsigned k1,
                                              unsigned x0, unsigned x1,
                                              unsigned& o0, unsigned& o1) {
  unsigned ks2 = 0x1BD11BDAu ^ k0 ^ k1;
  x0 += k0; x1 += k1;
#define TFR(r) { x0 += x1; x1 = (x1 << r) | (x1 >> (32 - r)); x1 ^= x0; }
  TFR(13) TFR(15) TFR(26) TFR(6)  x0 += k1;  x1 += ks2 + 1u;
  TFR(17) TFR(29) TFR(16) TFR(24) x0 += ks2; x1 += k0 + 2u;
  TFR(13) TFR(15) TFR(26) TFR(6)  x0 += k0;  x1 += k1 + 3u;
  TFR(17) TFR(29) TFR(16) TFR(24) x0 += k1;  x1 += ks2 + 4u;
  TFR(13) TFR(15) TFR(26) TFR(6)  x0 += ks2; x1 += k0 + 5u;
#undef TFR
  o0 = x0; o1 = x1;
}

__global__ __launch_bounds__(256) void idx_kernel(int* __restrict__ idx) {
  int i = blockIdx.x * 256 + threadIdx.x;           // 0..81919, grid 320
  unsigned c0, c1, o0, o1;
  tf2x32(0u, 42u, 0u, 1u, c0, c1);                  // k2 = second split child
  tf2x32(c0, c1, 0u, (unsigned)i, o0, o1);
  idx[i] = (int)((o0 ^ o1) & 2047u);
}

// ---------------------------------------------------------------- prep
__global__ __launch_bounds__(256)
void wt_kernel(const float* __restrict__ in, u16* __restrict__ outp, int K, int N) {
  __shared__ float t[64][65];
  int k0 = blockIdx.y * 64, n0 = blockIdx.x * 64;
  int c = threadIdx.x & 63, r4 = threadIdx.x >> 6;
#pragma unroll
  for (int i = 0; i < 16; ++i) {
    int r = r4 * 16 + i;
    t[r][c] = in[(size_t)(k0 + r) * N + n0 + c];
  }
  __syncthreads();
#pragma unroll
  for (int i = 0; i < 16; ++i) {
    int r = r4 * 16 + i;
    outp[(size_t)(n0 + r) * K + k0 + c] = f2b(t[c][r]);
  }
}

__global__ __launch_bounds__(256)
void wsplit_kernel(const float* __restrict__ in, u16* __restrict__ oh,
                   u16* __restrict__ ol, int K, int N) {
  __shared__ float t[64][65];
  int k0 = blockIdx.y * 64, n0 = blockIdx.x * 64;
  int c = threadIdx.x & 63, r4 = threadIdx.x >> 6;
#pragma unroll
  for (int i = 0; i < 16; ++i) {
    int r = r4 * 16 + i;
    t[r][c] = in[(size_t)(k0 + r) * N + n0 + c];
  }
  __syncthreads();
#pragma unroll
  for (int i = 0; i < 16; ++i) {
    int r = r4 * 16 + i;
    float f = t[c][r];
    u16 h = f2b(f);
    oh[(size_t)(n0 + r) * K + k0 + c] = h;
    ol[(size_t)(n0 + r) * K + k0 + c] = f2b(f - b2f(h));
  }
}

__global__ __launch_bounds__(256)
void conv_kernel(const float* __restrict__ in, u16* __restrict__ outp) {
  int i = blockIdx.x * 256 + threadIdx.x;
  f32x4_t v = *(const f32x4_t*)(in + (size_t)i * 4);
  u16x4_t o;
  o[0] = f2b(v[0]); o[1] = f2b(v[1]); o[2] = f2b(v[2]); o[3] = f2b(v[3]);
  *(u16x4_t*)(outp + (size_t)i * 4) = o;
}

__global__ __launch_bounds__(256)
void split_kernel(const float* __restrict__ in, u16* __restrict__ oh,
                  u16* __restrict__ ol) {
  int i = blockIdx.x * 256 + threadIdx.x;
  f32x4_t v = *(const f32x4_t*)(in + (size_t)i * 4);
  u16x4_t h, l;
#pragma unroll
  for (int d = 0; d < 4; ++d) {
    u16 hh = f2b(v[d]); h[d] = hh; l[d] = f2b(v[d] - b2f(hh));
  }
  *(u16x4_t*)(oh + (size_t)i * 4) = h;
  *(u16x4_t*)(ol + (size_t)i * 4) = l;
}

__global__ __launch_bounds__(256)
void pack2_kernel(const float* __restrict__ a, const float* __restrict__ b,
                  float* __restrict__ o, int n) {
  int i = blockIdx.x * 256 + threadIdx.x;
  if (i < 2 * n) o[i] = (i < n) ? a[i] : b[i - n];
}

// ---------------------------------------------------------------- bf16 GEMM
__global__ __launch_bounds__(256)
void gemm_bf(const u16* __restrict__ A, const u16* __restrict__ Bt,
             const float* __restrict__ bias, float* __restrict__ Cf,
             u16* __restrict__ Cb, int M, int N, int K, int relu) {
  __shared__ __align__(16) u16 sA[2][128 * 32];
  __shared__ __align__(16) u16 sB[2][64 * 32];
  const int tid = threadIdx.x;
  const int wave = tid >> 6, lane = tid & 63;
  const int m0 = blockIdx.x * 128, n0 = blockIdx.y * 64;
  const int wr = (wave >> 1) * 64, wc = (wave & 1) * 32;
  const int lr = lane & 15, kg = lane >> 4;
  const int wv = __builtin_amdgcn_readfirstlane(wave);

  int rowA[2], c8A[2];
#pragma unroll
  for (int rep = 0; rep < 2; ++rep) {
    int P = (rep * 256 + tid) << 4;
    int L = P ^ (((P >> 7) & 3) << 4);
    rowA[rep] = L >> 6; c8A[rep] = (L >> 4) & 3;
  }
  int rowB, c8B;
  {
    int P = tid << 4;
    int L = P ^ (((P >> 7) & 3) << 4);
    rowB = L >> 6; c8B = (L >> 4) & 3;
  }

  f32x4_t acc[4][2];
#pragma unroll
  for (int i = 0; i < 4; ++i)
#pragma unroll
    for (int j = 0; j < 2; ++j) acc[i][j] = f32x4_t{0.f, 0.f, 0.f, 0.f};

  auto STAGE = [&](int buf, int k0) {
#pragma unroll
    for (int rep = 0; rep < 2; ++rep)
      GLD16(A + (size_t)(m0 + rowA[rep]) * K + k0 + c8A[rep] * 8,
            &sA[buf][(rep * 256 + wv * 64) * 8]);
    GLD16(Bt + (size_t)(n0 + rowB) * K + k0 + c8B * 8,
          &sB[buf][(wv * 64) * 8]);
  };

  const int nk = K >> 5;
  STAGE(0, 0);
  __syncthreads();
  for (int t = 0; t < nk; ++t) {
    const int cur = t & 1;
    if (t + 1 < nk) STAGE(cur ^ 1, (t + 1) << 5);
    u16x8_t a8[4], b8[2];
#pragma unroll
    for (int mi = 0; mi < 4; ++mi) {
      int La = (wr + mi * 16 + lr) * 64 + kg * 16;
      a8[mi] = *(const u16x8_t*)((const char*)sA[cur] + (La ^ (((La >> 7) & 3) << 4)));
    }
#pragma unroll
    for (int ni = 0; ni < 2; ++ni) {
      int Lb = (wc + ni * 16 + lr) * 64 + kg * 16;
      b8[ni] = *(const u16x8_t*)((const char*)sB[cur] + (Lb ^ (((Lb >> 7) & 3) << 4)));
    }
#pragma unroll
    for (int mi = 0; mi < 4; ++mi)
#pragma unroll
      for (int ni = 0; ni < 2; ++ni)
        acc[mi][ni] = mfma_bf16(a8[mi], b8[ni], acc[mi][ni]);
    __syncthreads();
  }
#pragma unroll
  for (int ni = 0; ni < 2; ++ni) {
    int col = n0 + wc + ni * 16 + lr;
    float bc = bias[col];
#pragma unroll
    for (int mi = 0; mi < 4; ++mi)
#pragma unroll
      for (int r = 0; r < 4; ++r) {
        int row = m0 + wr + mi * 16 + kg * 4 + r;
        float vv = acc[mi][ni][r] + bc;
        if (relu) vv = fmaxf(vv, 0.f);
        if (Cf) Cf[(size_t)row * N + col] = vv;
        if (Cb) Cb[(size_t)row * N + col] = f2b(vv);
      }
  }
}

__global__ __launch_bounds__(256)
void gemm4_bf(const u16* __restrict__ Ah, const u16* __restrict__ Al,
              const u16* __restrict__ Bh, const u16* __restrict__ Bl,
              const float* __restrict__ bias, float* __restrict__ Cf,
              int M, int N, int K) {
  __shared__ __align__(16) u16 sAh[2][128 * 32];
  __shared__ __align__(16) u16 sAl[2][128 * 32];
  __shared__ __align__(16) u16 sBh[2][64 * 32];
  __shared__ __align__(16) u16 sBl[2][64 * 32];
  const int tid = threadIdx.x;
  const int wave = tid >> 6, lane = tid & 63;
  const int m0 = blockIdx.x * 128, n0 = blockIdx.y * 64;
  const int wr = (wave >> 1) * 64, wc = (wave & 1) * 32;
  const int lr = lane & 15, kg = lane >> 4;
  const int wv = __builtin_amdgcn_readfirstlane(wave);

  int rowA[2], c8A[2];
#pragma unroll
  for (int rep = 0; rep < 2; ++rep) {
    int P = (rep * 256 + tid) << 4;
    int L = P ^ (((P >> 7) & 3) << 4);
    rowA[rep] = L >> 6; c8A[rep] = (L >> 4) & 3;
  }
  int rowB, c8B;
  {
    int P = tid << 4;
    int L = P ^ (((P >> 7) & 3) << 4);
    rowB = L >> 6; c8B = (L >> 4) & 3;
  }

  f32x4_t acc[4][2];
#pragma unroll
  for (int i = 0; i < 4; ++i)
#pragma unroll
    for (int j = 0; j < 2; ++j) acc[i][j] = f32x4_t{0.f, 0.f, 0.f, 0.f};

  auto STAGE = [&](int buf, int k0) {
#pragma unroll
    for (int rep = 0; rep < 2; ++rep) {
      GLD16(Ah + (size_t)(m0 + rowA[rep]) * K + k0 + c8A[rep] * 8,
            &sAh[buf][(rep * 256 + wv * 64) * 8]);
      GLD16(Al + (size_t)(m0 + rowA[rep]) * K + k0 + c8A[rep] * 8,
            &sAl[buf][(rep * 256 + wv * 64) * 8]);
    }
    GLD16(Bh + (size_t)(n0 + rowB) * K + k0 + c8B * 8, &sBh[buf][(wv * 64) * 8]);
    GLD16(Bl + (size_t)(n0 + rowB) * K + k0 + c8B * 8, &sBl[buf][(wv * 64) * 8]);
  };

  const int nk = K >> 5;
  STAGE(0, 0);
  __syncthreads();
  for (int t = 0; t < nk; ++t) {
    const int cur = t & 1;
    if (t + 1 < nk) STAGE(cur ^ 1, (t + 1) << 5);
    u16x8_t ah[4], al[4], bh[2], bl[2];
#pragma unroll
    for (int mi = 0; mi < 4; ++mi) {
      int La = (wr + mi * 16 + lr) * 64 + kg * 16;
      int off = La ^ (((La >> 7) & 3) << 4);
      ah[mi] = *(const u16x8_t*)((const char*)sAh[cur] + off);
      al[mi] = *(const u16x8_t*)((const char*)sAl[cur] + off);
    }
#pragma unroll
    for (int ni = 0; ni < 2; ++ni) {
      int Lb = (wc + ni * 16 + lr) * 64 + kg * 16;
      int off = Lb ^ (((Lb >> 7) & 3) << 4);
      bh[ni] = *(const u16x8_t*)((const char*)sBh[cur] + off);
      bl[ni] = *(const u16x8_t*)((const char*)sBl[cur] + off);
    }
#pragma unroll
    for (int mi = 0; mi < 4; ++mi)
#pragma unroll
      for (int ni = 0; ni < 2; ++ni) {
        acc[mi][ni] = mfma_bf16(ah[mi], bh[ni], acc[mi][ni]);
        acc[mi][ni] = mfma_bf16(ah[mi], bl[ni], acc[mi][ni]);
        acc[mi][ni] = mfma_bf16(al[mi], bh[ni], acc[mi][ni]);
        acc[mi][ni] = mfma_bf16(al[mi], bl[ni], acc[mi][ni]);
      }
    __syncthreads();
  }
#pragma unroll
  for (int ni = 0; ni < 2; ++ni) {
    int col = n0 + wc + ni * 16 + lr;
    float bc = bias[col];
#pragma unroll
    for (int mi = 0; mi < 4; ++mi)
#pragma unroll
      for (int r = 0; r < 4; ++r) {
        int row = m0 + wr + mi * 16 + kg * 4 + r;
        Cf[(size_t)row * N + col] = acc[mi][ni][r] + bc;
      }
  }
}

// ---------------------------------------------------------------- ProbSparse
// q at qk[row][0..1023], k at qk[row][1024..2047]
__global__ __launch_bounds__(256)
void probM_kernel(const float* __restrict__ qk, const int* __restrict__ idx,
                  float* __restrict__ Mv) {
  int gw = blockIdx.x * 4 + (threadIdx.x >> 6);
  int lane = threadIdx.x & 63;
  int l = gw & (SEQ - 1);
  int hh = (gw >> 11) & (NHEADS - 1);
  int b = gw >> 15;
  float qv = qk[((size_t)b * SEQ + l) * 2048 + hh * EHEAD + lane];
  const int* ip = idx + l * NTOP;
  float mmax = -3.0e38f, msum = 0.f;
  for (int u = 0; u < NTOP; ++u) {
    int ki = ip[u];
    float p = qv * qk[((size_t)b * SEQ + ki) * 2048 + 1024 + hh * EHEAD + lane];
#pragma unroll
    for (int m = 1; m < 64; m <<= 1) p += __shfl_xor(p, m);
    mmax = fmaxf(mmax, p);
    msum += p;
  }
  if (lane == 0) Mv[gw] = mmax - msum * (1.f / 2048.f);
}

__global__ __launch_bounds__(256)
void topk_kernel(const float* __restrict__ Mv, int* __restrict__ Mtop) {
  int bh = blockIdx.x;
  int tid = threadIdx.x;
  __shared__ float vals[2048];
  __shared__ float rv[256];
  __shared__ int ri[256];
  for (int j = tid; j < 2048; j += 256) vals[j] = Mv[bh * 2048 + j];
  __syncthreads();
  for (int it = 0; it < NTOP; ++it) {
    float best = -3.0e38f;
    int bi = 1 << 30;
    for (int j = tid; j < 2048; j += 256) {
      float vv = vals[j];
      if (vv > best) { best = vv; bi = j; }
    }
    rv[tid] = best; ri[tid] = bi;
    __syncthreads();
    for (int st = 128; st > 0; st >>= 1) {
      if (tid < st) {
        if (rv[tid + st] > rv[tid] ||
            (rv[tid + st] == rv[tid] && ri[tid + st] < ri[tid])) {
          rv[tid] = rv[tid + st]; ri[tid] = ri[tid + st];
        }
      }
      __syncthreads();
    }
    if (tid == 0) { Mtop[bh * NTOP + it] = ri[0]; vals[ri[0]] = -3.4e38f; }
    __syncthreads();
  }
}

// transpose [B][L][stride,colOff+h*64+e] f32 -> [bh][e][L] bf16
__global__ __launch_bounds__(256)
void th_f32_bf16(const float* __restrict__ in, u16* __restrict__ outp,
                 int rowStride, int colOff) {
  int bh = blockIdx.x;
  int b = bh >> 4, hh = bh & 15;
  int l0 = blockIdx.y * 64;
  __shared__ float t[64][65];
  int c = threadIdx.x & 63, r4 = threadIdx.x >> 6;
  for (int i = 0; i < 16; ++i) {
    int row = r4 * 16 + i;
    t[row][c] = in[((size_t)b * SEQ + l0 + row) * rowStride + colOff + hh * EHEAD + c];
  }
  __syncthreads();
  for (int i = 0; i < 16; ++i) {
    int er = r4 * 16 + i;
    outp[((size_t)bh * EHEAD + er) * SEQ + l0 + c] = f2b(t[c][er]);
  }
}

__global__ __launch_bounds__(256)
void th_bf16_bf16(const u16* __restrict__ in, u16* __restrict__ outp) {
  int bh = blockIdx.x;
  int b = bh >> 4, hh = bh & 15;
  int l0 = blockIdx.y * 64;
  __shared__ u16 t[64][65];
  int c = threadIdx.x & 63, r4 = threadIdx.x >> 6;
  for (int i = 0; i < 16; ++i) {
    int row = r4 * 16 + i;
    t[row][c] = in[((size_t)b * SEQ + l0 + row) * DMODEL + hh * EHEAD + c];
  }
  __syncthreads();
  for (int i = 0; i < 16; ++i) {
    int er = r4 * 16 + i;
    outp[((size_t)bh * EHEAD + er) * SEQ + l0 + c] = t[c][er];
  }
}

__global__ __launch_bounds__(256)
void probAttn_kernel(const float* __restrict__ qk, const u16* __restrict__ kT,
                     const u16* __restrict__ vT, const int* __restrict__ Mtop,
                     float* __restrict__ upd) {
  int bh = blockIdx.x, b = bh >> 4, hh = bh & 15;
  int wave = threadIdx.x >> 6, lane = threadIdx.x & 63;
  int qg = blockIdx.y * 8 + wave * 2;
  int i0 = Mtop[bh * NTOP + qg], i1 = Mtop[bh * NTOP + qg + 1];
  float qv0 = qk[((size_t)b * SEQ + i0) * 2048 + hh * EHEAD + lane];
  float qv1 = qk[((size_t)b * SEQ + i1) * 2048 + hh * EHEAD + lane];
  const u16* kb = kT + (size_t)bh * EHEAD * SEQ;
  const u16* vb = vT + (size_t)bh * EHEAD * SEQ;
  float s0[32], s1[32];
#pragma unroll
  for (int kk = 0; kk < 32; ++kk) { s0[kk] = 0.f; s1[kk] = 0.f; }
  for (int e = 0; e < 64; ++e) {
    float qe0 = __shfl(qv0, e), qe1 = __shfl(qv1, e);
    const u16* kr = kb + (size_t)e * SEQ;
#pragma unroll
    for (int kk = 0; kk < 32; ++kk) {
      float kv = b2f(kr[kk * 64 + lane]);
      s0[kk] += qe0 * kv; s1[kk] += qe1 * kv;
    }
  }
  float m0 = -3e38f, m1 = -3e38f;
#pragma unroll
  for (int kk = 0; kk < 32; ++kk) {
    int key = kk * 64 + lane;
    s0[kk] = (key > i0) ? -1e9f : s0[kk] * 0.125f;
    s1[kk] = (key > i1) ? -1e9f : s1[kk] * 0.125f;
    m0 = fmaxf(m0, s0[kk]); m1 = fmaxf(m1, s1[kk]);
  }
#pragma unroll
  for (int m = 1; m < 64; m <<= 1) {
    m0 = fmaxf(m0, __shfl_xor(m0, m));
    m1 = fmaxf(m1, __shfl_xor(m1, m));
  }
  float sum0 = 0.f, sum1 = 0.f;
#pragma unroll
  for (int kk = 0; kk < 32; ++kk) {
    s0[kk] = __expf(s0[kk] - m0); sum0 += s0[kk];
    s1[kk] = __expf(s1[kk] - m1); sum1 += s1[kk];
  }
#pragma unroll
  for (int m = 1; m < 64; m <<= 1) {
    sum0 += __shfl_xor(sum0, m);
    sum1 += __shfl_xor(sum1, m);
  }
  float o0 = 0.f, o1 = 0.f;
  for (int e = 0; e < 64; ++e) {
    const u16* vr = vb + (size_t)e * SEQ;
    float a0 = 0.f, a1 = 0.f;
#pragma unroll
    for (int kk = 0; kk < 32; ++kk) {
      float vv = b2f(vr[kk * 64 + lane]);
      a0 += s0[kk] * vv; a1 += s1[kk] * vv;
    }
#pragma unroll
    for (int m = 1; m < 64; m <<= 1) {
      a0 += __shfl_xor(a0, m);
      a1 += __shfl_xor(a1, m);
    }
    if (lane == e) { o0 = a0; o1 = a1; }
  }
  upd[((size_t)bh * NTOP + qg) * EHEAD + lane] = o0 / sum0;
  upd[((size_t)bh * NTOP + qg + 1) * EHEAD + lane] = o1 / sum1;
}

__global__ __launch_bounds__(64)
void scan1_kernel(const u16* __restrict__ v, float* __restrict__ ctx,
                  float* __restrict__ csum) {
  int bh = blockIdx.x, c = blockIdx.y;
  int b = bh >> 4, hh = bh & 15, e = threadIdx.x;
  size_t base = ((size_t)b * SEQ + c * 128) * DMODEL + hh * EHEAD + e;
  float run = 0.f;
  for (int i = 0; i < 128; ++i) {
    run += b2f(v[base + (size_t)i * DMODEL]);
    ctx[base + (size_t)i * DMODEL] = run;
  }
  csum[(bh * 16 + c) * 64 + e] = run;
}
__global__ __launch_bounds__(64)
void scan2_kernel(const float* __restrict__ csum, float* __restrict__ ctx) {
  int bh = blockIdx.x, c = blockIdx.y + 1;
  int b = bh >> 4, hh = bh & 15, e = threadIdx.x;
  float off = 0.f;
  for (int cc = 0; cc < c; ++cc) off += csum[(bh * 16 + cc) * 64 + e];
  size_t base = ((size_t)b * SEQ + c * 128) * DMODEL + hh * EHEAD + e;
  for (int i = 0; i < 128; ++i) ctx[base + (size_t)i * DMODEL] += off;
}

__global__ __launch_bounds__(256)
void scatter_kernel(const float* __restrict__ upd, const int* __restrict__ Mtop,
                    float* __restrict__ ctx) {
  int i = blockIdx.x * 256 + threadIdx.x;  // < 81920
  int e = i & 63;
  int t = i >> 6;
  int bh = t / NTOP;
  int b = bh >> 4, hh = bh & 15;
  int row = Mtop[t];
  ctx[((size_t)b * SEQ + row) * DMODEL + hh * EHEAD + e] = upd[i];
}

// ---------------------------------------------------------------- kv pack
// From kv2b [B][L][2048] (k cols 0..1023, v cols 1024..2047) produce:
//   kpack [bh][key][64e] bf16, e-block c stored at block c ^ slotK(key),
//     slotK(key) = (key&3) | ((key>>3)&1)<<2
//   vpack [bh][chunk64][e][64key] bf16, key-block c stored at c ^ (e&7)
__global__ __launch_bounds__(256)
void kvpack_kernel(const u16* __restrict__ kv, u16* __restrict__ kpack,
                   u16* __restrict__ vpack) {
  int bh = blockIdx.x, ch = blockIdx.y;
  int b = bh >> 4, hh = bh & 15;
  int tid = threadIdx.x;
  __shared__ u16 vt[64][80];
#pragma unroll
  for (int rep = 0; rep < 2; ++rep) {
    int u = rep * 256 + tid;
    int key = u >> 3, c = u & 7;
    u16x8_t d = *(const u16x8_t*)(kv + ((size_t)(b * SEQ + ch * 64 + key)) * 2048 + hh * 64 + c * 8);
    int slot = (key & 3) | (((key >> 3) & 1) << 2);
    *(u16x8_t*)(kpack + ((size_t)bh * SEQ + ch * 64 + key) * 64 + ((c ^ slot) * 8)) = d;
    u16x8_t dv = *(const u16x8_t*)(kv + ((size_t)(b * SEQ + ch * 64 + key)) * 2048 + 1024 + hh * 64 + c * 8);
    *(u16x8_t*)(&vt[key][c * 8]) = dv;
  }
  __syncthreads();
#pragma unroll
  for (int rep = 0; rep < 2; ++rep) {
    int u = rep * 256 + tid;
    int e = u >> 3, c = u & 7;
    int kb = (c ^ (e & 7)) * 8;
    u16x8_t d;
#pragma unroll
    for (int j = 0; j < 8; ++j) d[j] = vt[kb + j][e];
    *(u16x8_t*)(vpack + (((size_t)bh * 32 + ch) * 64 + e) * 64 + c * 8) = d;
  }
}

// ---------------------------------------------------------------- cross attn
// 8 waves, 128-q tile, 64-key chunks double-buffered in LDS (shared).
// Swapped QK^T (mfma(K,Q)) with permuted key->tile map so P stays in-register
// for PV. Per-lane q = lane&15; key(t4,r) = (t4>>1)*32 + kg*8 + (t4&1)*4 + r.
__global__ __launch_bounds__(512)
void cross_attn_kernel(const float* __restrict__ q2, const u16* __restrict__ kpack,
                       const u16* __restrict__ vpack, u16* __restrict__ cab) {
  const int bh = blockIdx.x, b = bh >> 4, hh = bh & 15;
  const int qt0 = blockIdx.y * 128;
  const int tid = threadIdx.x, wave = tid >> 6, lane = tid & 63;
  const int lr = lane & 15, kg = lane >> 4;
  const int wv = __builtin_amdgcn_readfirstlane(wave);
  __shared__ __align__(16) u16 Qs[128 * 64];
  __shared__ __align__(16) u16 Kt[2][64 * 64];
  __shared__ __align__(16) u16 Vt[2][64 * 64];

#pragma unroll
  for (int i = 0; i < 4; ++i) {   // stage Q (scaled 1/8), swizzled
    int j = tid + 512 * i;        // 0..2047
    int row = j >> 4, c4 = j & 15;
    f32x4_t v4 = *(const f32x4_t*)(q2 + ((size_t)b * SEQ + qt0 + row) * DMODEL + hh * EHEAD + c4 * 4);
    u16x4_t b4;
    b4[0] = f2b(v4[0] * 0.125f); b4[1] = f2b(v4[1] * 0.125f);
    b4[2] = f2b(v4[2] * 0.125f); b4[3] = f2b(v4[3] * 0.125f);
    *(u16x4_t*)((char*)Qs + ((row * 128 + c4 * 8) ^ ((row & 7) << 4))) = b4;
  }

  const char* kgl = (const char*)kpack + (size_t)bh * SEQ * 128;
  const char* vgl = (const char*)vpack + (size_t)bh * 32 * 8192;
  auto STAGE = [&](int buf, int t) {
    GLD16(kgl + (size_t)t * 8192 + wv * 1024 + lane * 16, (char*)Kt[buf] + wv * 1024);
    GLD16(vgl + (size_t)t * 8192 + wv * 1024 + lane * 16, (char*)Vt[buf] + wv * 1024);
  };

  STAGE(0, 0);
  __syncthreads();

  u16x8_t bq[2];
  {
    int qrow = wave * 16 + lr;
#pragma unroll
    for (int ks = 0; ks < 2; ++ks)
      bq[ks] = *(u16x8_t*)((char*)Qs + ((qrow * 128 + ks * 64 + kg * 16) ^ ((qrow & 7) << 4)));
  }

  f32x4_t oacc[4];
#pragma unroll
  for (int i = 0; i < 4; ++i) oacc[i] = f32x4_t{0.f, 0.f, 0.f, 0.f};
  float mrun = -3e38f, lrun = 0.f;

  for (int t = 0; t < 32; ++t) {
    const int cur = t & 1;
    if (t + 1 < 32) STAGE(cur ^ 1, t + 1);
    // QK^T swapped: A = K rows (permuted), B = Q
    f32x4_t s[4];
#pragma unroll
    for (int i = 0; i < 4; ++i) s[i] = f32x4_t{0.f, 0.f, 0.f, 0.f};
#pragma unroll
    for (int ks = 0; ks < 2; ++ks)
#pragma unroll
      for (int t4 = 0; t4 < 4; ++t4) {
        int arow = ((t4 >> 1) << 5) + ((lr >> 2) << 3) + ((t4 & 1) << 2) + (lr & 3);
        int slot = (arow & 3) | (((arow >> 3) & 1) << 2);
        int off = (arow << 7) + (ks << 6) + (kg << 4);
        u16x8_t ak = *(const u16x8_t*)((const char*)Kt[cur] + (off ^ (slot << 4)));
        s[t4] = mfma_bf16(ak, bq[ks], s[t4]);
      }
    // online softmax, per-lane q = lane&15
    float mx = s[0][0];
#pragma unroll
    for (int t4 = 0; t4 < 4; ++t4)
#pragma unroll
      for (int r = 0; r < 4; ++r) mx = fmaxf(mx, s[t4][r]);
    mx = fmaxf(mx, __shfl_xor(mx, 16));
    mx = fmaxf(mx, __shfl_xor(mx, 32));
    float mnew = fmaxf(mrun, mx);
    float a = __expf(mrun - mnew);
    float sum = 0.f;
#pragma unroll
    for (int t4 = 0; t4 < 4; ++t4)
#pragma unroll
      for (int r = 0; r < 4; ++r) {
        float p = __expf(s[t4][r] - mnew);
        s[t4][r] = p; sum += p;
      }
    sum += __shfl_xor(sum, 16);
    sum += __shfl_xor(sum, 32);
    lrun = lrun * a + sum;
    mrun = mnew;
    float ar[4];
#pragma unroll
    for (int r = 0; r < 4; ++r) ar[r] = __shfl(a, kg * 4 + r);
#pragma unroll
    for (int ne = 0; ne < 4; ++ne)
#pragma unroll
      for (int r = 0; r < 4; ++r) oacc[ne][r] *= ar[r];
    // pack P (in-register) and PV
#pragma unroll
    for (int ks2 = 0; ks2 < 2; ++ks2) {
      u16x8_t pa;
#pragma unroll
      for (int j = 0; j < 4; ++j) {
        pa[j] = f2b(s[2 * ks2][j]);
        pa[4 + j] = f2b(s[2 * ks2 + 1][j]);
      }
#pragma unroll
      for (int ne = 0; ne < 4; ++ne) {
        int e = ne * 16 + lr;
        int off = (e << 7) + (ks2 << 6) + (kg << 4);
        u16x8_t bv = *(const u16x8_t*)((const char*)Vt[cur] + (off ^ ((e & 7) << 4)));
        oacc[ne] = mfma_bf16(pa, bv, oacc[ne]);
      }
    }
    __syncthreads();
  }

  float lr4[4];
#pragma unroll
  for (int r = 0; r < 4; ++r) lr4[r] = __shfl(lrun, kg * 4 + r);
#pragma unroll
  for (int ne = 0; ne < 4; ++ne)
#pragma unroll
    for (int r = 0; r < 4; ++r) {
      int row = qt0 + wave * 16 + kg * 4 + r;
      int col = hh * EHEAD + ne * 16 + lr;
      cab[((size_t)b * SEQ + row) * DMODEL + col] = f2b(oacc[ne][r] / lr4[r]);
    }
}

// ---------------------------------------------------------------- layernorm
__global__ __launch_bounds__(256)
void ln_kernel(const float* __restrict__ x, const float* __restrict__ r,
               const float* __restrict__ g, const float* __restrict__ be,
               float* __restrict__ outf, u16* __restrict__ outb) {
  int row = blockIdx.x, tid = threadIdx.x;
  size_t base = (size_t)row * DMODEL;
  float v[4];
  float s = 0.f, sq = 0.f;
#pragma unroll
  for (int i = 0; i < 4; ++i) {
    int c = tid + i * 256;
    float t = x[base + c] + r[base + c];
    v[i] = t; s += t; sq += t * t;
  }
  __shared__ float rs[256], rq[256];
  rs[tid] = s; rq[tid] = sq;
  __syncthreads();
  for (int st = 128; st > 0; st >>= 1) {
    if (tid < st) { rs[tid] += rs[tid + st]; rq[tid] += rq[tid + st]; }
    __syncthreads();
  }
  float mean = rs[0] * (1.f / DMODEL);
  float var = rq[0] * (1.f / DMODEL) - mean * mean;
  float rstd = rsqrtf(var + 1e-5f);
#pragma unroll
  for (int i = 0; i < 4; ++i) {
    int c = tid + i * 256;
    float o = (v[i] - mean) * rstd * g[c] + be[c];
    if (outf) outf[base + c] = o;
    if (outb) outb[base + c] = f2b(o);
  }
}

// ---------------------------------------------------------------- host side
static inline void gemm(const u16* A, const u16* Bt, const float* bias, float* Cf,
                        u16* Cb, int M, int N, int K, int relu, hipStream_t s) {
  gemm_bf<<<dim3(M / 128, N / 64), 256, 0, s>>>(A, Bt, bias, Cf, Cb, M, N, K, relu);
}
static inline void gemm4(const u16* Ah, const u16* Al, const u16* Bh, const u16* Bl,
                         const float* bias, float* Cf, int M, int N, int K, hipStream_t s) {
  gemm4_bf<<<dim3(M / 128, N / 64), 256, 0, s>>>(Ah, Al, Bh, Bl, bias, Cf, M, N, K);
}

extern "C" void kernel_launch(void* const* d_in, const int* in_sizes, int n_in,
                              void* d_out, int out_size, void* d_ws, size_t ws_size,
                              hipStream_t stream) {
  const float* x   = (const float*)d_in[0];
  const float* mem = (const float*)d_in[1];
  const float* sWq = (const float*)d_in[2];  const float* sbq = (const float*)d_in[3];
  const float* sWk = (const float*)d_in[4];  const float* sbk = (const float*)d_in[5];
  const float* sWv = (const float*)d_in[6];  const float* sbv = (const float*)d_in[7];
  const float* sWo = (const float*)d_in[8];  const float* sbo = (const float*)d_in[9];
  const float* cWq = (const float*)d_in[10]; const float* cbq = (const float*)d_in[11];
  const float* cWk = (const float*)d_in[12]; const float* cbk = (const float*)d_in[13];
  const float* cWv = (const float*)d_in[14]; const float* cbv = (const float*)d_in[15];
  const float* cWo = (const float*)d_in[16]; const float* cbo = (const float*)d_in[17];
  const float* W1  = (const float*)d_in[18]; const float* b1  = (const float*)d_in[19];
  const float* W2  = (const float*)d_in[20]; const float* b2  = (const float*)d_in[21];
  const float* g1  = (const float*)d_in[22]; const float* be1 = (const float*)d_in[23];
  const float* g2  = (const float*)d_in[24]; const float* be2 = (const float*)d_in[25];
  const float* g3  = (const float*)d_in[26]; const float* be3 = (const float*)d_in[27];
  float* outp = (float*)d_out;
  char* ws = (char*)d_ws;
  const size_t MB = 1ull << 20;

  int*   idx    = (int*)(ws);
  float* Mv     = (float*)(ws + 0x60000);
  int*   Mtop   = (int*)(ws + 0xA0000);
  float* upd    = (float*)(ws + 0xA2000);
  float* csum   = (float*)(ws + 0x100000);
  float* biasqk = (float*)(ws + 0x120000);
  float* cbkv   = (float*)(ws + 0x122000);

  u16* WqkhT = (u16*)(ws + 2 * MB);    // [2048][1024]
  u16* WqklT = (u16*)(ws + 6 * MB);
  u16* sWvT  = (u16*)(ws + 10 * MB);
  u16* sWoT  = (u16*)(ws + 12 * MB);
  u16* cWqT  = (u16*)(ws + 14 * MB);
  u16* cWkvT = (u16*)(ws + 16 * MB);   // [2048][1024]
  u16* cWoT  = (u16*)(ws + 20 * MB);
  u16* W1T   = (u16*)(ws + 22 * MB);
  u16* W2T   = (u16*)(ws + 30 * MB);

  u16* xh   = (u16*)(ws + 38 * MB);
  u16* xl   = (u16*)(ws + 46 * MB);
  u16* memb = (u16*)(ws + 54 * MB);

  float* qk   = (float*)(ws + 62 * MB);    // [4096][2048] f32, 32MB [62,94)
  u16*   vbf  = (u16*)(ws + 94 * MB);
  u16*   kTb  = (u16*)(ws + 102 * MB);
  u16*   vTb  = (u16*)(ws + 46 * MB);      // reuse xl (dead after gemm4)
  float* ctxf = (float*)(ws + 62 * MB);    // reuse qk (dead after probAttn)
  u16*   ctxb = (u16*)(ws + 78 * MB);
  float* sa   = (float*)(ws + 94 * MB);    // reuse vbf+kTb
  float* x1   = (float*)(ws + 62 * MB);
  u16*   x1b  = (u16*)(ws + 78 * MB);
  float* q2   = (float*)(ws + 94 * MB);
  u16*   kv2b = (u16*)(ws + 38 * MB);      // [4096][2048] bf16, 16MB [38,54)
  u16*   kpk  = (u16*)(ws + 54 * MB);      // 8MB (over memb, dead)
  u16*   vpk  = (u16*)(ws + 110 * MB);     // 8MB
  u16*   cab  = (u16*)(ws + 38 * MB);      // over kv2b (dead after kvpack)
  float* ca2  = (float*)(ws + 94 * MB);    // over q2
  float* x2   = (float*)(ws + 38 * MB);
  u16*   x2b  = (u16*)(ws + 54 * MB);
  u16*   hbb  = (u16*)(ws + 62 * MB);      // 32MB [62,94)
  float* yb   = (float*)(ws + 94 * MB);

  const int MROWS = BATCH * SEQ;  // 4096

  // ---- prep ----
  idx_kernel<<<320, 256, 0, stream>>>(idx);
  wsplit_kernel<<<dim3(16, 16), 256, 0, stream>>>(sWq, WqkhT, WqklT, 1024, 1024);
  wsplit_kernel<<<dim3(16, 16), 256, 0, stream>>>(sWk, WqkhT + 1024 * 1024, WqklT + 1024 * 1024, 1024, 1024);
  wt_kernel<<<dim3(16, 16), 256, 0, stream>>>(sWv, sWvT, 1024, 1024);
  wt_kernel<<<dim3(16, 16), 256, 0, stream>>>(sWo, sWoT, 1024, 1024);
  wt_kernel<<<dim3(16, 16), 256, 0, stream>>>(cWq, cWqT, 1024, 1024);
  wt_kernel<<<dim3(16, 16), 256, 0, stream>>>(cWk, cWkvT, 1024, 1024);
  wt_kernel<<<dim3(16, 16), 256, 0, stream>>>(cWv, cWkvT + 1024 * 1024, 1024, 1024);
  wt_kernel<<<dim3(16, 16), 256, 0, stream>>>(cWo, cWoT, 1024, 1024);
  wt_kernel<<<dim3(64, 16), 256, 0, stream>>>(W1, W1T, 1024, 4096);
  wt_kernel<<<dim3(16, 64), 256, 0, stream>>>(W2, W2T, 4096, 1024);
  split_kernel<<<4096, 256, 0, stream>>>(x, xh, xl);
  conv_kernel<<<4096, 256, 0, stream>>>(mem, memb);
  pack2_kernel<<<8, 256, 0, stream>>>(sbq, sbk, biasqk, 1024);
  pack2_kernel<<<8, 256, 0, stream>>>(cbk, cbv, cbkv, 1024);

  // ---- self attention (ProbSparse) ----
  gemm4(xh, xl, WqkhT, WqklT, biasqk, qk, MROWS, 2048, DMODEL, stream);
  gemm(xh, sWvT, sbv, nullptr, vbf, MROWS, DMODEL, DMODEL, 0, stream);
  probM_kernel<<<BATCH * NHEADS * SEQ / 4, 256, 0, stream>>>(qk, idx, Mv);
  topk_kernel<<<BATCH * NHEADS, 256, 0, stream>>>(Mv, Mtop);
  th_f32_bf16<<<dim3(BATCH * NHEADS, SEQ / 64), 256, 0, stream>>>(qk, kTb, 2048, 1024);
  th_bf16_bf16<<<dim3(BATCH * NHEADS, SEQ / 64), 256, 0, stream>>>(vbf, vTb);
  probAttn_kernel<<<dim3(BATCH * NHEADS, 5), 256, 0, stream>>>(qk, kTb, vTb, Mtop, upd);
  scan1_kernel<<<dim3(BATCH * NHEADS, 16), 64, 0, stream>>>(vbf, ctxf, csum);
  scan2_kernel<<<dim3(BATCH * NHEADS, 15), 64, 0, stream>>>(csum, ctxf);
  scatter_kernel<<<BATCH * NHEADS * NTOP * EHEAD / 256, 256, 0, stream>>>(upd, Mtop, ctxf);
  conv_kernel<<<4096, 256, 0, stream>>>(ctxf, ctxb);
  gemm(ctxb, sWoT, sbo, sa, nullptr, MROWS, DMODEL, DMODEL, 0, stream);
  ln_kernel<<<MROWS, 256, 0, stream>>>(x, sa, g1, be1, x1, x1b);

  // ---- cross attention ----
  gemm(x1b, cWqT, cbq, q2, nullptr, MROWS, DMODEL, DMODEL, 0, stream);
  gemm(memb, cWkvT, cbkv, nullptr, kv2b, MROWS, 2048, DMODEL, 0, stream);
  kvpack_kernel<<<dim3(BATCH * NHEADS, SEQ / 64), 256, 0, stream>>>(kv2b, kpk, vpk);
  cross_attn_kernel<<<dim3(BATCH * NHEADS, SEQ / 128), 512, 0, stream>>>(q2, kpk, vpk, cab);
  gemm(cab, cWoT, cbo, ca2, nullptr, MROWS, DMODEL, DMODEL, 0, stream);
  ln_kernel<<<MROWS, 256, 0, stream>>>(x1, ca2, g2, be2, x2, x2b);

  // ---- FFN ----
  gemm(x2b, W1T, b1, nullptr, hbb, MROWS, DFF, DMODEL, 1, stream);
  gemm(hbb, W2T, b2, yb, nullptr, MROWS, DMODEL, DFF, 0, stream);
  ln_kernel<<<MROWS, 256, 0, stream>>>(x2, yb, g3, be3, outp, nullptr);
}

// Round 4
// 677.085 us; speedup vs baseline: 1.7642x; 1.1972x over previous
//
#include <hip/hip_runtime.h>

static constexpr int BATCH  = 2;
static constexpr int SEQ    = 2048;
static constexpr int DMODEL = 1024;
static constexpr int NHEADS = 16;
static constexpr int EHEAD  = 64;
static constexpr int DFF    = 4096;
static constexpr int NTOP   = 40;

typedef unsigned short u16;
typedef __bf16 bf16x8_t __attribute__((ext_vector_type(8)));
typedef u16    u16x8_t  __attribute__((ext_vector_type(8)));
typedef u16    u16x4_t  __attribute__((ext_vector_type(4)));
typedef float  f32x4_t  __attribute__((ext_vector_type(4)));

static __device__ __forceinline__ u16 f2b(float f) {
  unsigned u = __builtin_bit_cast(unsigned, f);
  unsigned r = u + 0x7FFFu + ((u >> 16) & 1u);
  return (u16)(r >> 16);
}
static __device__ __forceinline__ float b2f(u16 h) {
  unsigned u = ((unsigned)h) << 16;
  return __builtin_bit_cast(float, u);
}
static __device__ __forceinline__ f32x4_t mfma_bf16(u16x8_t a, u16x8_t b, f32x4_t c) {
  return __builtin_amdgcn_mfma_f32_16x16x32_bf16(
      __builtin_bit_cast(bf16x8_t, a), __builtin_bit_cast(bf16x8_t, b), c, 0, 0, 0);
}

#define GLD16(gsrc, ldst)                                                        \
  __builtin_amdgcn_global_load_lds(                                             \
      (const __attribute__((address_space(1))) void*)(gsrc),                    \
      (__attribute__((address_space(3))) void*)(ldst), 16, 0, 0)

// ---------------------------------------------------------------- threefry
static __device__ __forceinline__ void tf2x32(unsigned k0, unsigned k1,
                                              unsigned x0, unsigned x1,
                                              unsigned& o0, unsigned& o1) {
  unsigned ks2 = 0x1BD11BDAu ^ k0 ^ k1;
  x0 += k0; x1 += k1;
#define TFR(r) { x0 += x1; x1 = (x1 << r) | (x1 >> (32 - r)); x1 ^= x0; }
  TFR(13) TFR(15) TFR(26) TFR(6)  x0 += k1;  x1 += ks2 + 1u;
  TFR(17) TFR(29) TFR(16) TFR(24) x0 += ks2; x1 += k0 + 2u;
  TFR(13) TFR(15) TFR(26) TFR(6)  x0 += k0;  x1 += k1 + 3u;
  TFR(17) TFR(29) TFR(16) TFR(24) x0 += k1;  x1 += ks2 + 4u;
  TFR(13) TFR(15) TFR(26) TFR(6)  x0 += ks2; x1 += k0 + 5u;
#undef TFR
  o0 = x0; o1 = x1;
}

__global__ __launch_bounds__(256) void idx_kernel(int* __restrict__ idx) {
  int i = blockIdx.x * 256 + threadIdx.x;           // 0..81919, grid 320
  unsigned c0, c1, o0, o1;
  tf2x32(0u, 42u, 0u, 1u, c0, c1);                  // k2 = second split child
  tf2x32(c0, c1, 0u, (unsigned)i, o0, o1);
  idx[i] = (int)((o0 ^ o1) & 2047u);
}

// ---------------------------------------------------------------- prep
__global__ __launch_bounds__(256)
void wt_kernel(const float* __restrict__ in, u16* __restrict__ outp, int K, int N) {
  __shared__ float t[64][65];
  int k0 = blockIdx.y * 64, n0 = blockIdx.x * 64;
  int c = threadIdx.x & 63, r4 = threadIdx.x >> 6;
#pragma unroll
  for (int i = 0; i < 16; ++i) {
    int r = r4 * 16 + i;
    t[r][c] = in[(size_t)(k0 + r) * N + n0 + c];
  }
  __syncthreads();
#pragma unroll
  for (int i = 0; i < 16; ++i) {
    int r = r4 * 16 + i;
    outp[(size_t)(n0 + r) * K + k0 + c] = f2b(t[c][r]);
  }
}

__global__ __launch_bounds__(256)
void wsplit_kernel(const float* __restrict__ in, u16* __restrict__ oh,
                   u16* __restrict__ ol, int K, int N) {
  __shared__ float t[64][65];
  int k0 = blockIdx.y * 64, n0 = blockIdx.x * 64;
  int c = threadIdx.x & 63, r4 = threadIdx.x >> 6;
#pragma unroll
  for (int i = 0; i < 16; ++i) {
    int r = r4 * 16 + i;
    t[r][c] = in[(size_t)(k0 + r) * N + n0 + c];
  }
  __syncthreads();
#pragma unroll
  for (int i = 0; i < 16; ++i) {
    int r = r4 * 16 + i;
    float f = t[c][r];
    u16 h = f2b(f);
    oh[(size_t)(n0 + r) * K + k0 + c] = h;
    ol[(size_t)(n0 + r) * K + k0 + c] = f2b(f - b2f(h));
  }
}

__global__ __launch_bounds__(256)
void conv_kernel(const float* __restrict__ in, u16* __restrict__ outp) {
  int i = blockIdx.x * 256 + threadIdx.x;
  f32x4_t v = *(const f32x4_t*)(in + (size_t)i * 4);
  u16x4_t o;
  o[0] = f2b(v[0]); o[1] = f2b(v[1]); o[2] = f2b(v[2]); o[3] = f2b(v[3]);
  *(u16x4_t*)(outp + (size_t)i * 4) = o;
}

__global__ __launch_bounds__(256)
void split_kernel(const float* __restrict__ in, u16* __restrict__ oh,
                  u16* __restrict__ ol) {
  int i = blockIdx.x * 256 + threadIdx.x;
  f32x4_t v = *(const f32x4_t*)(in + (size_t)i * 4);
  u16x4_t h, l;
#pragma unroll
  for (int d = 0; d < 4; ++d) {
    u16 hh = f2b(v[d]); h[d] = hh; l[d] = f2b(v[d] - b2f(hh));
  }
  *(u16x4_t*)(oh + (size_t)i * 4) = h;
  *(u16x4_t*)(ol + (size_t)i * 4) = l;
}

__global__ __launch_bounds__(256)
void pack2_kernel(const float* __restrict__ a, const float* __restrict__ b,
                  float* __restrict__ o, int n) {
  int i = blockIdx.x * 256 + threadIdx.x;
  if (i < 2 * n) o[i] = (i < n) ? a[i] : b[i - n];
}

// ---------------------------------------------------------------- bf16 GEMM
// C[M,BNxgrid] = A_bf[M,K] @ Bt_bf[N,K]^T + bias. 128x(NF*32) tile, BK=32,
// dbuf + gload_lds, involutive source-side swizzle (XOR byte bits 4,5).
template<int NF>
__global__ __launch_bounds__(256)
void gemm_bf(const u16* __restrict__ A, const u16* __restrict__ Bt,
             const float* __restrict__ bias, float* __restrict__ Cf,
             u16* __restrict__ Cb, int M, int N, int K, int relu) {
  __shared__ __align__(16) u16 sA[2][128 * 32];
  __shared__ __align__(16) u16 sB[2][NF * 32 * 32];
  const int tid = threadIdx.x;
  const int wave = tid >> 6, lane = tid & 63;
  const int m0 = blockIdx.x * 128, n0 = blockIdx.y * (NF * 32);
  const int wr = (wave >> 1) * 64, wc = (wave & 1) * (NF * 16);
  const int lr = lane & 15, kg = lane >> 4;
  const int wv = __builtin_amdgcn_readfirstlane(wave);

  int rowA[2], c8A[2];
#pragma unroll
  for (int rep = 0; rep < 2; ++rep) {
    int P = (rep * 256 + tid) << 4;
    int L = P ^ (((P >> 7) & 3) << 4);
    rowA[rep] = L >> 6; c8A[rep] = (L >> 4) & 3;
  }
  int rowB[NF / 2], c8B[NF / 2];
#pragma unroll
  for (int rep = 0; rep < NF / 2; ++rep) {
    int P = (rep * 256 + tid) << 4;
    int L = P ^ (((P >> 7) & 3) << 4);
    rowB[rep] = L >> 6; c8B[rep] = (L >> 4) & 3;
  }

  f32x4_t acc[4][NF];
#pragma unroll
  for (int i = 0; i < 4; ++i)
#pragma unroll
    for (int j = 0; j < NF; ++j) acc[i][j] = f32x4_t{0.f, 0.f, 0.f, 0.f};

  auto STAGE = [&](int buf, int k0) {
#pragma unroll
    for (int rep = 0; rep < 2; ++rep)
      GLD16(A + (size_t)(m0 + rowA[rep]) * K + k0 + c8A[rep] * 8,
            &sA[buf][(rep * 256 + wv * 64) * 8]);
#pragma unroll
    for (int rep = 0; rep < NF / 2; ++rep)
      GLD16(Bt + (size_t)(n0 + rowB[rep]) * K + k0 + c8B[rep] * 8,
            &sB[buf][(rep * 256 + wv * 64) * 8]);
  };

  const int nk = K >> 5;
  STAGE(0, 0);
  __syncthreads();
  for (int t = 0; t < nk; ++t) {
    const int cur = t & 1;
    if (t + 1 < nk) STAGE(cur ^ 1, (t + 1) << 5);
    u16x8_t a8[4], b8[NF];
#pragma unroll
    for (int mi = 0; mi < 4; ++mi) {
      int La = (wr + mi * 16 + lr) * 64 + kg * 16;
      a8[mi] = *(const u16x8_t*)((const char*)sA[cur] + (La ^ (((La >> 7) & 3) << 4)));
    }
#pragma unroll
    for (int ni = 0; ni < NF; ++ni) {
      int Lb = (wc + ni * 16 + lr) * 64 + kg * 16;
      b8[ni] = *(const u16x8_t*)((const char*)sB[cur] + (Lb ^ (((Lb >> 7) & 3) << 4)));
    }
#pragma unroll
    for (int mi = 0; mi < 4; ++mi)
#pragma unroll
      for (int ni = 0; ni < NF; ++ni)
        acc[mi][ni] = mfma_bf16(a8[mi], b8[ni], acc[mi][ni]);
    __syncthreads();
  }
#pragma unroll
  for (int ni = 0; ni < NF; ++ni) {
    int col = n0 + wc + ni * 16 + lr;
    float bc = bias[col];
#pragma unroll
    for (int mi = 0; mi < 4; ++mi)
#pragma unroll
      for (int r = 0; r < 4; ++r) {
        int row = m0 + wr + mi * 16 + kg * 4 + r;
        float vv = acc[mi][ni][r] + bc;
        if (relu) vv = fmaxf(vv, 0.f);
        if (Cf) Cf[(size_t)row * N + col] = vv;
        if (Cb) Cb[(size_t)row * N + col] = f2b(vv);
      }
  }
}

// 4-term split GEMM (f32-equivalent) from pre-split bf16 inputs.
template<int NF>
__global__ __launch_bounds__(256)
void gemm4_bf(const u16* __restrict__ Ah, const u16* __restrict__ Al,
              const u16* __restrict__ Bh, const u16* __restrict__ Bl,
              const float* __restrict__ bias, float* __restrict__ Cf,
              int M, int N, int K) {
  __shared__ __align__(16) u16 sAh[2][128 * 32];
  __shared__ __align__(16) u16 sAl[2][128 * 32];
  __shared__ __align__(16) u16 sBh[2][NF * 32 * 32];
  __shared__ __align__(16) u16 sBl[2][NF * 32 * 32];
  const int tid = threadIdx.x;
  const int wave = tid >> 6, lane = tid & 63;
  const int m0 = blockIdx.x * 128, n0 = blockIdx.y * (NF * 32);
  const int wr = (wave >> 1) * 64, wc = (wave & 1) * (NF * 16);
  const int lr = lane & 15, kg = lane >> 4;
  const int wv = __builtin_amdgcn_readfirstlane(wave);

  int rowA[2], c8A[2];
#pragma unroll
  for (int rep = 0; rep < 2; ++rep) {
    int P = (rep * 256 + tid) << 4;
    int L = P ^ (((P >> 7) & 3) << 4);
    rowA[rep] = L >> 6; c8A[rep] = (L >> 4) & 3;
  }
  int rowB[NF / 2], c8B[NF / 2];
#pragma unroll
  for (int rep = 0; rep < NF / 2; ++rep) {
    int P = (rep * 256 + tid) << 4;
    int L = P ^ (((P >> 7) & 3) << 4);
    rowB[rep] = L >> 6; c8B[rep] = (L >> 4) & 3;
  }

  f32x4_t acc[4][NF];
#pragma unroll
  for (int i = 0; i < 4; ++i)
#pragma unroll
    for (int j = 0; j < NF; ++j) acc[i][j] = f32x4_t{0.f, 0.f, 0.f, 0.f};

  auto STAGE = [&](int buf, int k0) {
#pragma unroll
    for (int rep = 0; rep < 2; ++rep) {
      GLD16(Ah + (size_t)(m0 + rowA[rep]) * K + k0 + c8A[rep] * 8,
            &sAh[buf][(rep * 256 + wv * 64) * 8]);
      GLD16(Al + (size_t)(m0 + rowA[rep]) * K + k0 + c8A[rep] * 8,
            &sAl[buf][(rep * 256 + wv * 64) * 8]);
    }
#pragma unroll
    for (int rep = 0; rep < NF / 2; ++rep) {
      GLD16(Bh + (size_t)(n0 + rowB[rep]) * K + k0 + c8B[rep] * 8,
            &sBh[buf][(rep * 256 + wv * 64) * 8]);
      GLD16(Bl + (size_t)(n0 + rowB[rep]) * K + k0 + c8B[rep] * 8,
            &sBl[buf][(rep * 256 + wv * 64) * 8]);
    }
  };

  const int nk = K >> 5;
  STAGE(0, 0);
  __syncthreads();
  for (int t = 0; t < nk; ++t) {
    const int cur = t & 1;
    if (t + 1 < nk) STAGE(cur ^ 1, (t + 1) << 5);
    u16x8_t ah[4], al[4], bh[NF], bl[NF];
#pragma unroll
    for (int mi = 0; mi < 4; ++mi) {
      int La = (wr + mi * 16 + lr) * 64 + kg * 16;
      int off = La ^ (((La >> 7) & 3) << 4);
      ah[mi] = *(const u16x8_t*)((const char*)sAh[cur] + off);
      al[mi] = *(const u16x8_t*)((const char*)sAl[cur] + off);
    }
#pragma unroll
    for (int ni = 0; ni < NF; ++ni) {
      int Lb = (wc + ni * 16 + lr) * 64 + kg * 16;
      int off = Lb ^ (((Lb >> 7) & 3) << 4);
      bh[ni] = *(const u16x8_t*)((const char*)sBh[cur] + off);
      bl[ni] = *(const u16x8_t*)((const char*)sBl[cur] + off);
    }
#pragma unroll
    for (int mi = 0; mi < 4; ++mi)
#pragma unroll
      for (int ni = 0; ni < NF; ++ni) {
        acc[mi][ni] = mfma_bf16(ah[mi], bh[ni], acc[mi][ni]);
        acc[mi][ni] = mfma_bf16(ah[mi], bl[ni], acc[mi][ni]);
        acc[mi][ni] = mfma_bf16(al[mi], bh[ni], acc[mi][ni]);
        acc[mi][ni] = mfma_bf16(al[mi], bl[ni], acc[mi][ni]);
      }
    __syncthreads();
  }
#pragma unroll
  for (int ni = 0; ni < NF; ++ni) {
    int col = n0 + wc + ni * 16 + lr;
    float bc = bias[col];
#pragma unroll
    for (int mi = 0; mi < 4; ++mi)
#pragma unroll
      for (int r = 0; r < 4; ++r) {
        int row = m0 + wr + mi * 16 + kg * 4 + r;
        Cf[(size_t)row * N + col] = acc[mi][ni][r] + bc;
      }
  }
}

// ---------------------------------------------------------------- ProbSparse
// One wave per (b,l): all 16 heads at once. Lane owns 16 f32 of the row
// (4 lanes per head); per sampled key: full 4KB k-row read shared by heads.
__global__ __launch_bounds__(256)
void probM_kernel(const float* __restrict__ qk, const int* __restrict__ idx,
                  float* __restrict__ Mv) {
  int w = blockIdx.x * 4 + (threadIdx.x >> 6);   // 0..4095
  int lane = threadIdx.x & 63;
  int l = w & (SEQ - 1);
  int b = w >> 11;
  const float* qrow = qk + ((size_t)b * SEQ + l) * 2048 + lane * 16;
  f32x4_t qv0 = *(const f32x4_t*)(qrow);
  f32x4_t qv1 = *(const f32x4_t*)(qrow + 4);
  f32x4_t qv2 = *(const f32x4_t*)(qrow + 8);
  f32x4_t qv3 = *(const f32x4_t*)(qrow + 12);
  const int* ip = idx + l * NTOP;
  const float* kbase = qk + (size_t)b * SEQ * 2048 + 1024 + lane * 16;
  float mmax = -3.0e38f, msum = 0.f;
#pragma unroll 4
  for (int u = 0; u < NTOP; ++u) {
    int ki = ip[u];
    const float* kr = kbase + (size_t)ki * 2048;
    f32x4_t k0 = *(const f32x4_t*)(kr);
    f32x4_t k1 = *(const f32x4_t*)(kr + 4);
    f32x4_t k2 = *(const f32x4_t*)(kr + 8);
    f32x4_t k3 = *(const f32x4_t*)(kr + 12);
    float p = qv0[0] * k0[0] + qv0[1] * k0[1] + qv0[2] * k0[2] + qv0[3] * k0[3]
            + qv1[0] * k1[0] + qv1[1] * k1[1] + qv1[2] * k1[2] + qv1[3] * k1[3]
            + qv2[0] * k2[0] + qv2[1] * k2[1] + qv2[2] * k2[2] + qv2[3] * k2[3]
            + qv3[0] * k3[0] + qv3[1] * k3[1] + qv3[2] * k3[2] + qv3[3] * k3[3];
    p += __shfl_xor(p, 1);
    p += __shfl_xor(p, 2);
    mmax = fmaxf(mmax, p);
    msum += p;
  }
  if ((lane & 3) == 0) {
    int hh = lane >> 2;
    Mv[((size_t)b * NHEADS + hh) * SEQ + l] = mmax - msum * (1.f / 2048.f);
  }
}

__global__ __launch_bounds__(256)
void topk_kernel(const float* __restrict__ Mv, int* __restrict__ Mtop) {
  int bh = blockIdx.x;
  int tid = threadIdx.x;
  int lane = tid & 63, wv = tid >> 6;
  __shared__ float vals[2048];
  __shared__ float wrv[4];
  __shared__ int wri[4];
  for (int j = tid; j < 2048; j += 256) vals[j] = Mv[bh * 2048 + j];
  __syncthreads();
  for (int it = 0; it < NTOP; ++it) {
    float best = -3.0e38f;
    int bi = 1 << 30;
    for (int j = tid; j < 2048; j += 256) {
      float vv = vals[j];
      if (vv > best) { best = vv; bi = j; }
    }
#pragma unroll
    for (int m = 1; m < 64; m <<= 1) {
      float ov = __shfl_xor(best, m);
      int oi = __shfl_xor(bi, m);
      if (ov > best || (ov == best && oi < bi)) { best = ov; bi = oi; }
    }
    if (lane == 0) { wrv[wv] = best; wri[wv] = bi; }
    __syncthreads();
    if (tid == 0) {
      float bv = wrv[0]; int bbi = wri[0];
#pragma unroll
      for (int t = 1; t < 4; ++t)
        if (wrv[t] > bv || (wrv[t] == bv && wri[t] < bbi)) { bv = wrv[t]; bbi = wri[t]; }
      Mtop[bh * NTOP + it] = bbi;
      vals[bbi] = -3.4e38f;
    }
    __syncthreads();
  }
}

// transpose [B][L][stride,colOff+h*64+e] f32 -> [bh][e][L] bf16
__global__ __launch_bounds__(256)
void th_f32_bf16(const float* __restrict__ in, u16* __restrict__ outp,
                 int rowStride, int colOff) {
  int bh = blockIdx.x;
  int b = bh >> 4, hh = bh & 15;
  int l0 = blockIdx.y * 64;
  __shared__ float t[64][65];
  int c = threadIdx.x & 63, r4 = threadIdx.x >> 6;
  for (int i = 0; i < 16; ++i) {
    int row = r4 * 16 + i;
    t[row][c] = in[((size_t)b * SEQ + l0 + row) * rowStride + colOff + hh * EHEAD + c];
  }
  __syncthreads();
  for (int i = 0; i < 16; ++i) {
    int er = r4 * 16 + i;
    outp[((size_t)bh * EHEAD + er) * SEQ + l0 + c] = f2b(t[c][er]);
  }
}

__global__ __launch_bounds__(256)
void th_bf16_bf16(const u16* __restrict__ in, u16* __restrict__ outp) {
  int bh = blockIdx.x;
  int b = bh >> 4, hh = bh & 15;
  int l0 = blockIdx.y * 64;
  __shared__ u16 t[64][65];
  int c = threadIdx.x & 63, r4 = threadIdx.x >> 6;
  for (int i = 0; i < 16; ++i) {
    int row = r4 * 16 + i;
    t[row][c] = in[((size_t)b * SEQ + l0 + row) * DMODEL + hh * EHEAD + c];
  }
  __syncthreads();
  for (int i = 0; i < 16; ++i) {
    int er = r4 * 16 + i;
    outp[((size_t)bh * EHEAD + er) * SEQ + l0 + c] = t[c][er];
  }
}

__global__ __launch_bounds__(256)
void probAttn_kernel(const float* __restrict__ qk, const u16* __restrict__ kT,
                     const u16* __restrict__ vT, const int* __restrict__ Mtop,
                     float* __restrict__ upd) {
  int bh = blockIdx.x, b = bh >> 4, hh = bh & 15;
  int wave = threadIdx.x >> 6, lane = threadIdx.x & 63;
  int qg = blockIdx.y * 8 + wave * 2;
  int i0 = Mtop[bh * NTOP + qg], i1 = Mtop[bh * NTOP + qg + 1];
  float qv0 = qk[((size_t)b * SEQ + i0) * 2048 + hh * EHEAD + lane];
  float qv1 = qk[((size_t)b * SEQ + i1) * 2048 + hh * EHEAD + lane];
  const u16* kb = kT + (size_t)bh * EHEAD * SEQ;
  const u16* vb = vT + (size_t)bh * EHEAD * SEQ;
  float s0[32], s1[32];
#pragma unroll
  for (int kk = 0; kk < 32; ++kk) { s0[kk] = 0.f; s1[kk] = 0.f; }
  for (int e = 0; e < 64; ++e) {
    float qe0 = __shfl(qv0, e), qe1 = __shfl(qv1, e);
    const u16* kr = kb + (size_t)e * SEQ;
#pragma unroll
    for (int kk = 0; kk < 32; ++kk) {
      float kv = b2f(kr[kk * 64 + lane]);
      s0[kk] += qe0 * kv; s1[kk] += qe1 * kv;
    }
  }
  float m0 = -3e38f, m1 = -3e38f;
#pragma unroll
  for (int kk = 0; kk < 32; ++kk) {
    int key = kk * 64 + lane;
    s0[kk] = (key > i0) ? -1e9f : s0[kk] * 0.125f;
    s1[kk] = (key > i1) ? -1e9f : s1[kk] * 0.125f;
    m0 = fmaxf(m0, s0[kk]); m1 = fmaxf(m1, s1[kk]);
  }
#pragma unroll
  for (int m = 1; m < 64; m <<= 1) {
    m0 = fmaxf(m0, __shfl_xor(m0, m));
    m1 = fmaxf(m1, __shfl_xor(m1, m));
  }
  float sum0 = 0.f, sum1 = 0.f;
#pragma unroll
  for (int kk = 0; kk < 32; ++kk) {
    s0[kk] = __expf(s0[kk] - m0); sum0 += s0[kk];
    s1[kk] = __expf(s1[kk] - m1); sum1 += s1[kk];
  }
#pragma unroll
  for (int m = 1; m < 64; m <<= 1) {
    sum0 += __shfl_xor(sum0, m);
    sum1 += __shfl_xor(sum1, m);
  }
  float o0 = 0.f, o1 = 0.f;
  for (int e = 0; e < 64; ++e) {
    const u16* vr = vb + (size_t)e * SEQ;
    float a0 = 0.f, a1 = 0.f;
#pragma unroll
    for (int kk = 0; kk < 32; ++kk) {
      float vv = b2f(vr[kk * 64 + lane]);
      a0 += s0[kk] * vv; a1 += s1[kk] * vv;
    }
#pragma unroll
    for (int m = 1; m < 64; m <<= 1) {
      a0 += __shfl_xor(a0, m);
      a1 += __shfl_xor(a1, m);
    }
    if (lane == e) { o0 = a0; o1 = a1; }
  }
  upd[((size_t)bh * NTOP + qg) * EHEAD + lane] = o0 / sum0;
  upd[((size_t)bh * NTOP + qg + 1) * EHEAD + lane] = o1 / sum1;
}

__global__ __launch_bounds__(64)
void scan1_kernel(const u16* __restrict__ v, float* __restrict__ ctx,
                  float* __restrict__ csum) {
  int bh = blockIdx.x, c = blockIdx.y;
  int b = bh >> 4, hh = bh & 15, e = threadIdx.x;
  size_t base = ((size_t)b * SEQ + c * 128) * DMODEL + hh * EHEAD + e;
  float run = 0.f;
  for (int i = 0; i < 128; ++i) {
    run += b2f(v[base + (size_t)i * DMODEL]);
    ctx[base + (size_t)i * DMODEL] = run;
  }
  csum[(bh * 16 + c) * 64 + e] = run;
}

// add chunk offsets, write bf16 (single rounding)
__global__ __launch_bounds__(64)
void scan2_kernel(const float* __restrict__ csum, const float* __restrict__ ctxf,
                  u16* __restrict__ ctxb) {
  int bh = blockIdx.x, c = blockIdx.y;   // 0..15
  int b = bh >> 4, hh = bh & 15, e = threadIdx.x;
  float off = 0.f;
  for (int cc = 0; cc < c; ++cc) off += csum[(bh * 16 + cc) * 64 + e];
  size_t base = ((size_t)b * SEQ + c * 128) * DMODEL + hh * EHEAD + e;
  for (int i = 0; i < 128; ++i)
    ctxb[base + (size_t)i * DMODEL] = f2b(ctxf[base + (size_t)i * DMODEL] + off);
}

__global__ __launch_bounds__(256)
void scatter_kernel(const float* __restrict__ upd, const int* __restrict__ Mtop,
                    u16* __restrict__ ctxb) {
  int i = blockIdx.x * 256 + threadIdx.x;  // < 81920
  int e = i & 63;
  int t = i >> 6;
  int bh = t / NTOP;
  int b = bh >> 4, hh = bh & 15;
  int row = Mtop[t];
  ctxb[((size_t)b * SEQ + row) * DMODEL + hh * EHEAD + e] = f2b(upd[i]);
}

// ---------------------------------------------------------------- kv pack
__global__ __launch_bounds__(256)
void kvpack_kernel(const u16* __restrict__ kv, u16* __restrict__ kpack,
                   u16* __restrict__ vpack) {
  int bh = blockIdx.x, ch = blockIdx.y;
  int b = bh >> 4, hh = bh & 15;
  int tid = threadIdx.x;
  __shared__ u16 vt[64][80];
#pragma unroll
  for (int rep = 0; rep < 2; ++rep) {
    int u = rep * 256 + tid;
    int key = u >> 3, c = u & 7;
    u16x8_t d = *(const u16x8_t*)(kv + ((size_t)(b * SEQ + ch * 64 + key)) * 2048 + hh * 64 + c * 8);
    int slot = (key & 3) | (((key >> 3) & 1) << 2);
    *(u16x8_t*)(kpack + ((size_t)bh * SEQ + ch * 64 + key) * 64 + ((c ^ slot) * 8)) = d;
    u16x8_t dv = *(const u16x8_t*)(kv + ((size_t)(b * SEQ + ch * 64 + key)) * 2048 + 1024 + hh * 64 + c * 8);
    *(u16x8_t*)(&vt[key][c * 8]) = dv;
  }
  __syncthreads();
#pragma unroll
  for (int rep = 0; rep < 2; ++rep) {
    int u = rep * 256 + tid;
    int e = u >> 3, c = u & 7;
    int kb = (c ^ (e & 7)) * 8;
    u16x8_t d;
#pragma unroll
    for (int j = 0; j < 8; ++j) d[j] = vt[kb + j][e];
    *(u16x8_t*)(vpack + (((size_t)bh * 32 + ch) * 64 + e) * 64 + c * 8) = d;
  }
}

// ---------------------------------------------------------------- cross attn
__global__ __launch_bounds__(512)
void cross_attn_kernel(const float* __restrict__ q2, const u16* __restrict__ kpack,
                       const u16* __restrict__ vpack, u16* __restrict__ cab) {
  const int bh = blockIdx.x, b = bh >> 4, hh = bh & 15;
  const int qt0 = blockIdx.y * 128;
  const int tid = threadIdx.x, wave = tid >> 6, lane = tid & 63;
  const int lr = lane & 15, kg = lane >> 4;
  const int wv = __builtin_amdgcn_readfirstlane(wave);
  __shared__ __align__(16) u16 Qs[128 * 64];
  __shared__ __align__(16) u16 Kt[2][64 * 64];
  __shared__ __align__(16) u16 Vt[2][64 * 64];

#pragma unroll
  for (int i = 0; i < 4; ++i) {
    int j = tid + 512 * i;
    int row = j >> 4, c4 = j & 15;
    f32x4_t v4 = *(const f32x4_t*)(q2 + ((size_t)b * SEQ + qt0 + row) * DMODEL + hh * EHEAD + c4 * 4);
    u16x4_t b4;
    b4[0] = f2b(v4[0] * 0.125f); b4[1] = f2b(v4[1] * 0.125f);
    b4[2] = f2b(v4[2] * 0.125f); b4[3] = f2b(v4[3] * 0.125f);
    *(u16x4_t*)((char*)Qs + ((row * 128 + c4 * 8) ^ ((row & 7) << 4))) = b4;
  }

  const char* kgl = (const char*)kpack + (size_t)bh * SEQ * 128;
  const char* vgl = (const char*)vpack + (size_t)bh * 32 * 8192;
  auto STAGE = [&](int buf, int t) {
    GLD16(kgl + (size_t)t * 8192 + wv * 1024 + lane * 16, (char*)Kt[buf] + wv * 1024);
    GLD16(vgl + (size_t)t * 8192 + wv * 1024 + lane * 16, (char*)Vt[buf] + wv * 1024);
  };

  STAGE(0, 0);
  __syncthreads();

  u16x8_t bq[2];
  {
    int qrow = wave * 16 + lr;
#pragma unroll
    for (int ks = 0; ks < 2; ++ks)
      bq[ks] = *(u16x8_t*)((char*)Qs + ((qrow * 128 + ks * 64 + kg * 16) ^ ((qrow & 7) << 4)));
  }

  f32x4_t oacc[4];
#pragma unroll
  for (int i = 0; i < 4; ++i) oacc[i] = f32x4_t{0.f, 0.f, 0.f, 0.f};
  float mrun = -3e38f, lrun = 0.f;

  for (int t = 0; t < 32; ++t) {
    const int cur = t & 1;
    if (t + 1 < 32) STAGE(cur ^ 1, t + 1);
    f32x4_t s[4];
#pragma unroll
    for (int i = 0; i < 4; ++i) s[i] = f32x4_t{0.f, 0.f, 0.f, 0.f};
#pragma unroll
    for (int ks = 0; ks < 2; ++ks)
#pragma unroll
      for (int t4 = 0; t4 < 4; ++t4) {
        int arow = ((t4 >> 1) << 5) + ((lr >> 2) << 3) + ((t4 & 1) << 2) + (lr & 3);
        int slot = (arow & 3) | (((arow >> 3) & 1) << 2);
        int off = (arow << 7) + (ks << 6) + (kg << 4);
        u16x8_t ak = *(const u16x8_t*)((const char*)Kt[cur] + (off ^ (slot << 4)));
        s[t4] = mfma_bf16(ak, bq[ks], s[t4]);
      }
    float mx = s[0][0];
#pragma unroll
    for (int t4 = 0; t4 < 4; ++t4)
#pragma unroll
      for (int r = 0; r < 4; ++r) mx = fmaxf(mx, s[t4][r]);
    mx = fmaxf(mx, __shfl_xor(mx, 16));
    mx = fmaxf(mx, __shfl_xor(mx, 32));
    float mnew = fmaxf(mrun, mx);
    float a = __expf(mrun - mnew);
    float sum = 0.f;
#pragma unroll
    for (int t4 = 0; t4 < 4; ++t4)
#pragma unroll
      for (int r = 0; r < 4; ++r) {
        float p = __expf(s[t4][r] - mnew);
        s[t4][r] = p; sum += p;
      }
    sum += __shfl_xor(sum, 16);
    sum += __shfl_xor(sum, 32);
    lrun = lrun * a + sum;
    mrun = mnew;
    float ar[4];
#pragma unroll
    for (int r = 0; r < 4; ++r) ar[r] = __shfl(a, kg * 4 + r);
#pragma unroll
    for (int ne = 0; ne < 4; ++ne)
#pragma unroll
      for (int r = 0; r < 4; ++r) oacc[ne][r] *= ar[r];
#pragma unroll
    for (int ks2 = 0; ks2 < 2; ++ks2) {
      u16x8_t pa;
#pragma unroll
      for (int j = 0; j < 4; ++j) {
        pa[j] = f2b(s[2 * ks2][j]);
        pa[4 + j] = f2b(s[2 * ks2 + 1][j]);
      }
#pragma unroll
      for (int ne = 0; ne < 4; ++ne) {
        int e = ne * 16 + lr;
        int off = (e << 7) + (ks2 << 6) + (kg << 4);
        u16x8_t bv = *(const u16x8_t*)((const char*)Vt[cur] + (off ^ ((e & 7) << 4)));
        oacc[ne] = mfma_bf16(pa, bv, oacc[ne]);
      }
    }
    __syncthreads();
  }

  float lr4[4];
#pragma unroll
  for (int r = 0; r < 4; ++r) lr4[r] = __shfl(lrun, kg * 4 + r);
#pragma unroll
  for (int ne = 0; ne < 4; ++ne)
#pragma unroll
    for (int r = 0; r < 4; ++r) {
      int row = qt0 + wave * 16 + kg * 4 + r;
      int col = hh * EHEAD + ne * 16 + lr;
      cab[((size_t)b * SEQ + row) * DMODEL + col] = f2b(oacc[ne][r] / lr4[r]);
    }
}

// ---------------------------------------------------------------- layernorm
__global__ __launch_bounds__(256)
void ln_kernel(const float* __restrict__ x, const float* __restrict__ r,
               const float* __restrict__ g, const float* __restrict__ be,
               float* __restrict__ outf, u16* __restrict__ outb) {
  int row = blockIdx.x, tid = threadIdx.x;
  size_t base = (size_t)row * DMODEL;
  float v[4];
  float s = 0.f, sq = 0.f;
#pragma unroll
  for (int i = 0; i < 4; ++i) {
    int c = tid + i * 256;
    float t = x[base + c] + r[base + c];
    v[i] = t; s += t; sq += t * t;
  }
  __shared__ float rs[256], rq[256];
  rs[tid] = s; rq[tid] = sq;
  __syncthreads();
  for (int st = 128; st > 0; st >>= 1) {
    if (tid < st) { rs[tid] += rs[tid + st]; rq[tid] += rq[tid + st]; }
    __syncthreads();
  }
  float mean = rs[0] * (1.f / DMODEL);
  float var = rq[0] * (1.f / DMODEL) - mean * mean;
  float rstd = rsqrtf(var + 1e-5f);
#pragma unroll
  for (int i = 0; i < 4; ++i) {
    int c = tid + i * 256;
    float o = (v[i] - mean) * rstd * g[c] + be[c];
    if (outf) outf[base + c] = o;
    if (outb) outb[base + c] = f2b(o);
  }
}

// ---------------------------------------------------------------- host side
static inline void gemm(const u16* A, const u16* Bt, const float* bias, float* Cf,
                        u16* Cb, int M, int N, int K, int relu, hipStream_t s,
                        int big = 0) {
  if (big)
    gemm_bf<4><<<dim3(M / 128, N / 128), 256, 0, s>>>(A, Bt, bias, Cf, Cb, M, N, K, relu);
  else
    gemm_bf<2><<<dim3(M / 128, N / 64), 256, 0, s>>>(A, Bt, bias, Cf, Cb, M, N, K, relu);
}
static inline void gemm4(const u16* Ah, const u16* Al, const u16* Bh, const u16* Bl,
                         const float* bias, float* Cf, int M, int N, int K, hipStream_t s) {
  gemm4_bf<4><<<dim3(M / 128, N / 128), 256, 0, s>>>(Ah, Al, Bh, Bl, bias, Cf, M, N, K);
}

extern "C" void kernel_launch(void* const* d_in, const int* in_sizes, int n_in,
                              void* d_out, int out_size, void* d_ws, size_t ws_size,
                              hipStream_t stream) {
  const float* x   = (const float*)d_in[0];
  const float* mem = (const float*)d_in[1];
  const float* sWq = (const float*)d_in[2];  const float* sbq = (const float*)d_in[3];
  const float* sWk = (const float*)d_in[4];  const float* sbk = (const float*)d_in[5];
  const float* sWv = (const float*)d_in[6];  const float* sbv = (const float*)d_in[7];
  const float* sWo = (const float*)d_in[8];  const float* sbo = (const float*)d_in[9];
  const float* cWq = (const float*)d_in[10]; const float* cbq = (const float*)d_in[11];
  const float* cWk = (const float*)d_in[12]; const float* cbk = (const float*)d_in[13];
  const float* cWv = (const float*)d_in[14]; const float* cbv = (const float*)d_in[15];
  const float* cWo = (const float*)d_in[16]; const float* cbo = (const float*)d_in[17];
  const float* W1  = (const float*)d_in[18]; const float* b1  = (const float*)d_in[19];
  const float* W2  = (const float*)d_in[20]; const float* b2  = (const float*)d_in[21];
  const float* g1  = (const float*)d_in[22]; const float* be1 = (const float*)d_in[23];
  const float* g2  = (const float*)d_in[24]; const float* be2 = (const float*)d_in[25];
  const float* g3  = (const float*)d_in[26]; const float* be3 = (const float*)d_in[27];
  float* outp = (float*)d_out;
  char* ws = (char*)d_ws;
  const size_t MB = 1ull << 20;

  int*   idx    = (int*)(ws);
  float* Mv     = (float*)(ws + 0x60000);
  int*   Mtop   = (int*)(ws + 0xA0000);
  float* upd    = (float*)(ws + 0xA2000);
  float* csum   = (float*)(ws + 0x100000);
  float* biasqk = (float*)(ws + 0x120000);
  float* cbkv   = (float*)(ws + 0x122000);

  u16* WqkhT = (u16*)(ws + 2 * MB);    // [2048][1024]
  u16* WqklT = (u16*)(ws + 6 * MB);
  u16* sWvT  = (u16*)(ws + 10 * MB);
  u16* sWoT  = (u16*)(ws + 12 * MB);
  u16* cWqT  = (u16*)(ws + 14 * MB);
  u16* cWkvT = (u16*)(ws + 16 * MB);   // [2048][1024]
  u16* cWoT  = (u16*)(ws + 20 * MB);
  u16* W1T   = (u16*)(ws + 22 * MB);
  u16* W2T   = (u16*)(ws + 30 * MB);

  u16* xh   = (u16*)(ws + 38 * MB);
  u16* xl   = (u16*)(ws + 46 * MB);
  u16* memb = (u16*)(ws + 54 * MB);

  float* qk   = (float*)(ws + 62 * MB);    // [4096][2048] f32, 32MB [62,94)
  u16*   vbf  = (u16*)(ws + 94 * MB);
  u16*   kTb  = (u16*)(ws + 102 * MB);
  u16*   vTb  = (u16*)(ws + 46 * MB);      // reuse xl (dead after gemm4)
  float* ctxf = (float*)(ws + 62 * MB);    // reuse qk (dead after probAttn)
  u16*   ctxb = (u16*)(ws + 78 * MB);
  float* sa   = (float*)(ws + 94 * MB);    // reuse vbf+kTb
  float* x1   = (float*)(ws + 62 * MB);
  u16*   x1b  = (u16*)(ws + 78 * MB);
  float* q2   = (float*)(ws + 94 * MB);
  u16*   kv2b = (u16*)(ws + 38 * MB);      // [4096][2048] bf16, 16MB [38,54)
  u16*   kpk  = (u16*)(ws + 54 * MB);      // 8MB (over memb, dead)
  u16*   vpk  = (u16*)(ws + 110 * MB);     // 8MB
  u16*   cab  = (u16*)(ws + 38 * MB);      // over kv2b (dead after kvpack)
  float* ca2  = (float*)(ws + 94 * MB);    // over q2
  float* x2   = (float*)(ws + 38 * MB);
  u16*   x2b  = (u16*)(ws + 54 * MB);
  u16*   hbb  = (u16*)(ws + 62 * MB);      // 32MB [62,94)
  float* yb   = (float*)(ws + 94 * MB);

  const int MROWS = BATCH * SEQ;  // 4096

  // ---- prep ----
  idx_kernel<<<320, 256, 0, stream>>>(idx);
  wsplit_kernel<<<dim3(16, 16), 256, 0, stream>>>(sWq, WqkhT, WqklT, 1024, 1024);
  wsplit_kernel<<<dim3(16, 16), 256, 0, stream>>>(sWk, WqkhT + 1024 * 1024, WqklT + 1024 * 1024, 1024, 1024);
  wt_kernel<<<dim3(16, 16), 256, 0, stream>>>(sWv, sWvT, 1024, 1024);
  wt_kernel<<<dim3(16, 16), 256, 0, stream>>>(sWo, sWoT, 1024, 1024);
  wt_kernel<<<dim3(16, 16), 256, 0, stream>>>(cWq, cWqT, 1024, 1024);
  wt_kernel<<<dim3(16, 16), 256, 0, stream>>>(cWk, cWkvT, 1024, 1024);
  wt_kernel<<<dim3(16, 16), 256, 0, stream>>>(cWv, cWkvT + 1024 * 1024, 1024, 1024);
  wt_kernel<<<dim3(16, 16), 256, 0, stream>>>(cWo, cWoT, 1024, 1024);
  wt_kernel<<<dim3(64, 16), 256, 0, stream>>>(W1, W1T, 1024, 4096);
  wt_kernel<<<dim3(16, 64), 256, 0, stream>>>(W2, W2T, 4096, 1024);
  split_kernel<<<4096, 256, 0, stream>>>(x, xh, xl);
  conv_kernel<<<4096, 256, 0, stream>>>(mem, memb);
  pack2_kernel<<<8, 256, 0, stream>>>(sbq, sbk, biasqk, 1024);
  pack2_kernel<<<8, 256, 0, stream>>>(cbk, cbv, cbkv, 1024);

  // ---- self attention (ProbSparse) ----
  gemm4(xh, xl, WqkhT, WqklT, biasqk, qk, MROWS, 2048, DMODEL, stream);
  gemm(xh, sWvT, sbv, nullptr, vbf, MROWS, DMODEL, DMODEL, 0, stream);
  probM_kernel<<<BATCH * SEQ / 4, 256, 0, stream>>>(qk, idx, Mv);
  topk_kernel<<<BATCH * NHEADS, 256, 0, stream>>>(Mv, Mtop);
  th_f32_bf16<<<dim3(BATCH * NHEADS, SEQ / 64), 256, 0, stream>>>(qk, kTb, 2048, 1024);
  th_bf16_bf16<<<dim3(BATCH * NHEADS, SEQ / 64), 256, 0, stream>>>(vbf, vTb);
  probAttn_kernel<<<dim3(BATCH * NHEADS, 5), 256, 0, stream>>>(qk, kTb, vTb, Mtop, upd);
  scan1_kernel<<<dim3(BATCH * NHEADS, 16), 64, 0, stream>>>(vbf, ctxf, csum);
  scan2_kernel<<<dim3(BATCH * NHEADS, 16), 64, 0, stream>>>(csum, ctxf, ctxb);
  scatter_kernel<<<BATCH * NHEADS * NTOP * EHEAD / 256, 256, 0, stream>>>(upd, Mtop, ctxb);
  gemm(ctxb, sWoT, sbo, sa, nullptr, MROWS, DMODEL, DMODEL, 0, stream);
  ln_kernel<<<MROWS, 256, 0, stream>>>(x, sa, g1, be1, x1, x1b);

  // ---- cross attention ----
  gemm(x1b, cWqT, cbq, q2, nullptr, MROWS, DMODEL, DMODEL, 0, stream);
  gemm(memb, cWkvT, cbkv, nullptr, kv2b, MROWS, 2048, DMODEL, 0, stream, 1);
  kvpack_kernel<<<dim3(BATCH * NHEADS, SEQ / 64), 256, 0, stream>>>(kv2b, kpk, vpk);
  cross_attn_kernel<<<dim3(BATCH * NHEADS, SEQ / 128), 512, 0, stream>>>(q2, kpk, vpk, cab);
  gemm(cab, cWoT, cbo, ca2, nullptr, MROWS, DMODEL, DMODEL, 0, stream);
  ln_kernel<<<MROWS, 256, 0, stream>>>(x1, ca2, g2, be2, x2, x2b);

  // ---- FFN ----
  gemm(x2b, W1T, b1, nullptr, hbb, MROWS, DFF, DMODEL, 1, stream, 1);
  gemm(hbb, W2T, b2, yb, nullptr, MROWS, DMODEL, DFF, 0, stream);
  ln_kernel<<<MROWS, 256, 0, stream>>>(x2, yb, g3, be3, outp, nullptr);
}

// Round 5
// 675.050 us; speedup vs baseline: 1.7695x; 1.0030x over previous
//
#include <hip/hip_runtime.h>

static constexpr int BATCH  = 2;
static constexpr int SEQ    = 2048;
static constexpr int DMODEL = 1024;
static constexpr int NHEADS = 16;
static constexpr int EHEAD  = 64;
static constexpr int DFF    = 4096;
static constexpr int NTOP   = 40;

typedef unsigned short u16;
typedef __bf16 bf16x8_t __attribute__((ext_vector_type(8)));
typedef u16    u16x8_t  __attribute__((ext_vector_type(8)));
typedef u16    u16x4_t  __attribute__((ext_vector_type(4)));
typedef float  f32x4_t  __attribute__((ext_vector_type(4)));

static __device__ __forceinline__ u16 f2b(float f) {
  unsigned u = __builtin_bit_cast(unsigned, f);
  unsigned r = u + 0x7FFFu + ((u >> 16) & 1u);
  return (u16)(r >> 16);
}
static __device__ __forceinline__ float b2f(u16 h) {
  unsigned u = ((unsigned)h) << 16;
  return __builtin_bit_cast(float, u);
}
static __device__ __forceinline__ f32x4_t mfma_bf16(u16x8_t a, u16x8_t b, f32x4_t c) {
  return __builtin_amdgcn_mfma_f32_16x16x32_bf16(
      __builtin_bit_cast(bf16x8_t, a), __builtin_bit_cast(bf16x8_t, b), c, 0, 0, 0);
}

#define GLD16(gsrc, ldst)                                                        \
  __builtin_amdgcn_global_load_lds(                                             \
      (const __attribute__((address_space(1))) void*)(gsrc),                    \
      (__attribute__((address_space(3))) void*)(ldst), 16, 0, 0)

// ---------------------------------------------------------------- threefry
static __device__ __forceinline__ void tf2x32(unsigned k0, unsigned k1,
                                              unsigned x0, unsigned x1,
                                              unsigned& o0, unsigned& o1) {
  unsigned ks2 = 0x1BD11BDAu ^ k0 ^ k1;
  x0 += k0; x1 += k1;
#define TFR(r) { x0 += x1; x1 = (x1 << r) | (x1 >> (32 - r)); x1 ^= x0; }
  TFR(13) TFR(15) TFR(26) TFR(6)  x0 += k1;  x1 += ks2 + 1u;
  TFR(17) TFR(29) TFR(16) TFR(24) x0 += ks2; x1 += k0 + 2u;
  TFR(13) TFR(15) TFR(26) TFR(6)  x0 += k0;  x1 += k1 + 3u;
  TFR(17) TFR(29) TFR(16) TFR(24) x0 += k1;  x1 += ks2 + 4u;
  TFR(13) TFR(15) TFR(26) TFR(6)  x0 += ks2; x1 += k0 + 5u;
#undef TFR
  o0 = x0; o1 = x1;
}

__global__ __launch_bounds__(256) void idx_kernel(int* __restrict__ idx) {
  int i = blockIdx.x * 256 + threadIdx.x;           // 0..81919, grid 320
  unsigned c0, c1, o0, o1;
  tf2x32(0u, 42u, 0u, 1u, c0, c1);                  // k2 = second split child
  tf2x32(c0, c1, 0u, (unsigned)i, o0, o1);
  idx[i] = (int)((o0 ^ o1) & 2047u);
}

// ---------------------------------------------------------------- prep
__global__ __launch_bounds__(256)
void wt_kernel(const float* __restrict__ in, u16* __restrict__ outp, int K, int N) {
  __shared__ float t[64][65];
  int k0 = blockIdx.y * 64, n0 = blockIdx.x * 64;
  int c = threadIdx.x & 63, r4 = threadIdx.x >> 6;
#pragma unroll
  for (int i = 0; i < 16; ++i) {
    int r = r4 * 16 + i;
    t[r][c] = in[(size_t)(k0 + r) * N + n0 + c];
  }
  __syncthreads();
#pragma unroll
  for (int i = 0; i < 16; ++i) {
    int r = r4 * 16 + i;
    outp[(size_t)(n0 + r) * K + k0 + c] = f2b(t[c][r]);
  }
}

__global__ __launch_bounds__(256)
void wsplit_kernel(const float* __restrict__ in, u16* __restrict__ oh,
                   u16* __restrict__ ol, int K, int N) {
  __shared__ float t[64][65];
  int k0 = blockIdx.y * 64, n0 = blockIdx.x * 64;
  int c = threadIdx.x & 63, r4 = threadIdx.x >> 6;
#pragma unroll
  for (int i = 0; i < 16; ++i) {
    int r = r4 * 16 + i;
    t[r][c] = in[(size_t)(k0 + r) * N + n0 + c];
  }
  __syncthreads();
#pragma unroll
  for (int i = 0; i < 16; ++i) {
    int r = r4 * 16 + i;
    float f = t[c][r];
    u16 h = f2b(f);
    oh[(size_t)(n0 + r) * K + k0 + c] = h;
    ol[(size_t)(n0 + r) * K + k0 + c] = f2b(f - b2f(h));
  }
}

__global__ __launch_bounds__(256)
void conv_kernel(const float* __restrict__ in, u16* __restrict__ outp) {
  int i = blockIdx.x * 256 + threadIdx.x;
  f32x4_t v = *(const f32x4_t*)(in + (size_t)i * 4);
  u16x4_t o;
  o[0] = f2b(v[0]); o[1] = f2b(v[1]); o[2] = f2b(v[2]); o[3] = f2b(v[3]);
  *(u16x4_t*)(outp + (size_t)i * 4) = o;
}

__global__ __launch_bounds__(256)
void split_kernel(const float* __restrict__ in, u16* __restrict__ oh,
                  u16* __restrict__ ol) {
  int i = blockIdx.x * 256 + threadIdx.x;
  f32x4_t v = *(const f32x4_t*)(in + (size_t)i * 4);
  u16x4_t h, l;
#pragma unroll
  for (int d = 0; d < 4; ++d) {
    u16 hh = f2b(v[d]); h[d] = hh; l[d] = f2b(v[d] - b2f(hh));
  }
  *(u16x4_t*)(oh + (size_t)i * 4) = h;
  *(u16x4_t*)(ol + (size_t)i * 4) = l;
}

__global__ __launch_bounds__(256)
void pack2_kernel(const float* __restrict__ a, const float* __restrict__ b,
                  float* __restrict__ o, int n) {
  int i = blockIdx.x * 256 + threadIdx.x;
  if (i < 2 * n) o[i] = (i < n) ? a[i] : b[i - n];
}

// ---------------------------------------------------------------- bf16 GEMM
// C[M,BNxgrid] = A_bf[M,K] @ Bt_bf[N,K]^T + bias. 128x(NF*32) tile, BK=32,
// dbuf + gload_lds, involutive source-side swizzle (XOR byte bits 4,5).
template<int NF>
__global__ __launch_bounds__(256)
void gemm_bf(const u16* __restrict__ A, const u16* __restrict__ Bt,
             const float* __restrict__ bias, float* __restrict__ Cf,
             u16* __restrict__ Cb, int M, int N, int K, int relu) {
  __shared__ __align__(16) u16 sA[2][128 * 32];
  __shared__ __align__(16) u16 sB[2][NF * 32 * 32];
  const int tid = threadIdx.x;
  const int wave = tid >> 6, lane = tid & 63;
  const int m0 = blockIdx.x * 128, n0 = blockIdx.y * (NF * 32);
  const int wr = (wave >> 1) * 64, wc = (wave & 1) * (NF * 16);
  const int lr = lane & 15, kg = lane >> 4;
  const int wv = __builtin_amdgcn_readfirstlane(wave);

  int rowA[2], c8A[2];
#pragma unroll
  for (int rep = 0; rep < 2; ++rep) {
    int P = (rep * 256 + tid) << 4;
    int L = P ^ (((P >> 7) & 3) << 4);
    rowA[rep] = L >> 6; c8A[rep] = (L >> 4) & 3;
  }
  int rowB[NF / 2], c8B[NF / 2];
#pragma unroll
  for (int rep = 0; rep < NF / 2; ++rep) {
    int P = (rep * 256 + tid) << 4;
    int L = P ^ (((P >> 7) & 3) << 4);
    rowB[rep] = L >> 6; c8B[rep] = (L >> 4) & 3;
  }

  f32x4_t acc[4][NF];
#pragma unroll
  for (int i = 0; i < 4; ++i)
#pragma unroll
    for (int j = 0; j < NF; ++j) acc[i][j] = f32x4_t{0.f, 0.f, 0.f, 0.f};

  auto STAGE = [&](int buf, int k0) {
#pragma unroll
    for (int rep = 0; rep < 2; ++rep)
      GLD16(A + (size_t)(m0 + rowA[rep]) * K + k0 + c8A[rep] * 8,
            &sA[buf][(rep * 256 + wv * 64) * 8]);
#pragma unroll
    for (int rep = 0; rep < NF / 2; ++rep)
      GLD16(Bt + (size_t)(n0 + rowB[rep]) * K + k0 + c8B[rep] * 8,
            &sB[buf][(rep * 256 + wv * 64) * 8]);
  };

  const int nk = K >> 5;
  STAGE(0, 0);
  __syncthreads();
  for (int t = 0; t < nk; ++t) {
    const int cur = t & 1;
    if (t + 1 < nk) STAGE(cur ^ 1, (t + 1) << 5);
    u16x8_t a8[4], b8[NF];
#pragma unroll
    for (int mi = 0; mi < 4; ++mi) {
      int La = (wr + mi * 16 + lr) * 64 + kg * 16;
      a8[mi] = *(const u16x8_t*)((const char*)sA[cur] + (La ^ (((La >> 7) & 3) << 4)));
    }
#pragma unroll
    for (int ni = 0; ni < NF; ++ni) {
      int Lb = (wc + ni * 16 + lr) * 64 + kg * 16;
      b8[ni] = *(const u16x8_t*)((const char*)sB[cur] + (Lb ^ (((Lb >> 7) & 3) << 4)));
    }
#pragma unroll
    for (int mi = 0; mi < 4; ++mi)
#pragma unroll
      for (int ni = 0; ni < NF; ++ni)
        acc[mi][ni] = mfma_bf16(a8[mi], b8[ni], acc[mi][ni]);
    __syncthreads();
  }
#pragma unroll
  for (int ni = 0; ni < NF; ++ni) {
    int col = n0 + wc + ni * 16 + lr;
    float bc = bias[col];
#pragma unroll
    for (int mi = 0; mi < 4; ++mi)
#pragma unroll
      for (int r = 0; r < 4; ++r) {
        int row = m0 + wr + mi * 16 + kg * 4 + r;
        float vv = acc[mi][ni][r] + bc;
        if (relu) vv = fmaxf(vv, 0.f);
        if (Cf) Cf[(size_t)row * N + col] = vv;
        if (Cb) Cb[(size_t)row * N + col] = f2b(vv);
      }
  }
}

// 4-term split GEMM (f32-equivalent) from pre-split bf16 inputs.
template<int NF>
__global__ __launch_bounds__(256)
void gemm4_bf(const u16* __restrict__ Ah, const u16* __restrict__ Al,
              const u16* __restrict__ Bh, const u16* __restrict__ Bl,
              const float* __restrict__ bias, float* __restrict__ Cf,
              int M, int N, int K) {
  __shared__ __align__(16) u16 sAh[2][128 * 32];
  __shared__ __align__(16) u16 sAl[2][128 * 32];
  __shared__ __align__(16) u16 sBh[2][NF * 32 * 32];
  __shared__ __align__(16) u16 sBl[2][NF * 32 * 32];
  const int tid = threadIdx.x;
  const int wave = tid >> 6, lane = tid & 63;
  const int m0 = blockIdx.x * 128, n0 = blockIdx.y * (NF * 32);
  const int wr = (wave >> 1) * 64, wc = (wave & 1) * (NF * 16);
  const int lr = lane & 15, kg = lane >> 4;
  const int wv = __builtin_amdgcn_readfirstlane(wave);

  int rowA[2], c8A[2];
#pragma unroll
  for (int rep = 0; rep < 2; ++rep) {
    int P = (rep * 256 + tid) << 4;
    int L = P ^ (((P >> 7) & 3) << 4);
    rowA[rep] = L >> 6; c8A[rep] = (L >> 4) & 3;
  }
  int rowB[NF / 2], c8B[NF / 2];
#pragma unroll
  for (int rep = 0; rep < NF / 2; ++rep) {
    int P = (rep * 256 + tid) << 4;
    int L = P ^ (((P >> 7) & 3) << 4);
    rowB[rep] = L >> 6; c8B[rep] = (L >> 4) & 3;
  }

  f32x4_t acc[4][NF];
#pragma unroll
  for (int i = 0; i < 4; ++i)
#pragma unroll
    for (int j = 0; j < NF; ++j) acc[i][j] = f32x4_t{0.f, 0.f, 0.f, 0.f};

  auto STAGE = [&](int buf, int k0) {
#pragma unroll
    for (int rep = 0; rep < 2; ++rep) {
      GLD16(Ah + (size_t)(m0 + rowA[rep]) * K + k0 + c8A[rep] * 8,
            &sAh[buf][(rep * 256 + wv * 64) * 8]);
      GLD16(Al + (size_t)(m0 + rowA[rep]) * K + k0 + c8A[rep] * 8,
            &sAl[buf][(rep * 256 + wv * 64) * 8]);
    }
#pragma unroll
    for (int rep = 0; rep < NF / 2; ++rep) {
      GLD16(Bh + (size_t)(n0 + rowB[rep]) * K + k0 + c8B[rep] * 8,
            &sBh[buf][(rep * 256 + wv * 64) * 8]);
      GLD16(Bl + (size_t)(n0 + rowB[rep]) * K + k0 + c8B[rep] * 8,
            &sBl[buf][(rep * 256 + wv * 64) * 8]);
    }
  };

  const int nk = K >> 5;
  STAGE(0, 0);
  __syncthreads();
  for (int t = 0; t < nk; ++t) {
    const int cur = t & 1;
    if (t + 1 < nk) STAGE(cur ^ 1, (t + 1) << 5);
    u16x8_t ah[4], al[4], bh[NF], bl[NF];
#pragma unroll
    for (int mi = 0; mi < 4; ++mi) {
      int La = (wr + mi * 16 + lr) * 64 + kg * 16;
      int off = La ^ (((La >> 7) & 3) << 4);
      ah[mi] = *(const u16x8_t*)((const char*)sAh[cur] + off);
      al[mi] = *(const u16x8_t*)((const char*)sAl[cur] + off);
    }
#pragma unroll
    for (int ni = 0; ni < NF; ++ni) {
      int Lb = (wc + ni * 16 + lr) * 64 + kg * 16;
      int off = Lb ^ (((Lb >> 7) & 3) << 4);
      bh[ni] = *(const u16x8_t*)((const char*)sBh[cur] + off);
      bl[ni] = *(const u16x8_t*)((const char*)sBl[cur] + off);
    }
#pragma unroll
    for (int mi = 0; mi < 4; ++mi)
#pragma unroll
      for (int ni = 0; ni < NF; ++ni) {
        acc[mi][ni] = mfma_bf16(ah[mi], bh[ni], acc[mi][ni]);
        acc[mi][ni] = mfma_bf16(ah[mi], bl[ni], acc[mi][ni]);
        acc[mi][ni] = mfma_bf16(al[mi], bh[ni], acc[mi][ni]);
        acc[mi][ni] = mfma_bf16(al[mi], bl[ni], acc[mi][ni]);
      }
    __syncthreads();
  }
#pragma unroll
  for (int ni = 0; ni < NF; ++ni) {
    int col = n0 + wc + ni * 16 + lr;
    float bc = bias[col];
#pragma unroll
    for (int mi = 0; mi < 4; ++mi)
#pragma unroll
      for (int r = 0; r < 4; ++r) {
        int row = m0 + wr + mi * 16 + kg * 4 + r;
        Cf[(size_t)row * N + col] = acc[mi][ni][r] + bc;
      }
  }
}

// ---------------------------------------------------------------- ProbSparse
// One wave per (b,l): all 16 heads at once. Lane owns 16 f32 of the row
// (4 lanes per head); per sampled key: full 4KB k-row read shared by heads.
__global__ __launch_bounds__(256)
void probM_kernel(const float* __restrict__ qk, const int* __restrict__ idx,
                  float* __restrict__ Mv) {
  int w = blockIdx.x * 4 + (threadIdx.x >> 6);   // 0..4095
  int lane = threadIdx.x & 63;
  int l = w & (SEQ - 1);
  int b = w >> 11;
  const float* qrow = qk + ((size_t)b * SEQ + l) * 2048 + lane * 16;
  f32x4_t qv0 = *(const f32x4_t*)(qrow);
  f32x4_t qv1 = *(const f32x4_t*)(qrow + 4);
  f32x4_t qv2 = *(const f32x4_t*)(qrow + 8);
  f32x4_t qv3 = *(const f32x4_t*)(qrow + 12);
  const int* ip = idx + l * NTOP;
  const float* kbase = qk + (size_t)b * SEQ * 2048 + 1024 + lane * 16;
  float mmax = -3.0e38f, msum = 0.f;
#pragma unroll 4
  for (int u = 0; u < NTOP; ++u) {
    int ki = ip[u];
    const float* kr = kbase + (size_t)ki * 2048;
    f32x4_t k0 = *(const f32x4_t*)(kr);
    f32x4_t k1 = *(const f32x4_t*)(kr + 4);
    f32x4_t k2 = *(const f32x4_t*)(kr + 8);
    f32x4_t k3 = *(const f32x4_t*)(kr + 12);
    float p = qv0[0] * k0[0] + qv0[1] * k0[1] + qv0[2] * k0[2] + qv0[3] * k0[3]
            + qv1[0] * k1[0] + qv1[1] * k1[1] + qv1[2] * k1[2] + qv1[3] * k1[3]
            + qv2[0] * k2[0] + qv2[1] * k2[1] + qv2[2] * k2[2] + qv2[3] * k2[3]
            + qv3[0] * k3[0] + qv3[1] * k3[1] + qv3[2] * k3[2] + qv3[3] * k3[3];
    p += __shfl_xor(p, 1);
    p += __shfl_xor(p, 2);
    mmax = fmaxf(mmax, p);
    msum += p;
  }
  if ((lane & 3) == 0) {
    int hh = lane >> 2;
    Mv[((size_t)b * NHEADS + hh) * SEQ + l] = mmax - msum * (1.f / 2048.f);
  }
}

__global__ __launch_bounds__(256)
void topk_kernel(const float* __restrict__ Mv, int* __restrict__ Mtop) {
  int bh = blockIdx.x;
  int tid = threadIdx.x;
  int lane = tid & 63, wv = tid >> 6;
  __shared__ float vals[2048];
  __shared__ float wrv[4];
  __shared__ int wri[4];
  for (int j = tid; j < 2048; j += 256) vals[j] = Mv[bh * 2048 + j];
  __syncthreads();
  for (int it = 0; it < NTOP; ++it) {
    float best = -3.0e38f;
    int bi = 1 << 30;
    for (int j = tid; j < 2048; j += 256) {
      float vv = vals[j];
      if (vv > best) { best = vv; bi = j; }
    }
#pragma unroll
    for (int m = 1; m < 64; m <<= 1) {
      float ov = __shfl_xor(best, m);
      int oi = __shfl_xor(bi, m);
      if (ov > best || (ov == best && oi < bi)) { best = ov; bi = oi; }
    }
    if (lane == 0) { wrv[wv] = best; wri[wv] = bi; }
    __syncthreads();
    if (tid == 0) {
      float bv = wrv[0]; int bbi = wri[0];
#pragma unroll
      for (int t = 1; t < 4; ++t)
        if (wrv[t] > bv || (wrv[t] == bv && wri[t] < bbi)) { bv = wrv[t]; bbi = wri[t]; }
      Mtop[bh * NTOP + it] = bbi;
      vals[bbi] = -3.4e38f;
    }
    __syncthreads();
  }
}

// transpose [B][L][stride,colOff+h*64+e] f32 -> [bh][e][L] bf16
__global__ __launch_bounds__(256)
void th_f32_bf16(const float* __restrict__ in, u16* __restrict__ outp,
                 int rowStride, int colOff) {
  int bh = blockIdx.x;
  int b = bh >> 4, hh = bh & 15;
  int l0 = blockIdx.y * 64;
  __shared__ float t[64][65];
  int c = threadIdx.x & 63, r4 = threadIdx.x >> 6;
  for (int i = 0; i < 16; ++i) {
    int row = r4 * 16 + i;
    t[row][c] = in[((size_t)b * SEQ + l0 + row) * rowStride + colOff + hh * EHEAD + c];
  }
  __syncthreads();
  for (int i = 0; i < 16; ++i) {
    int er = r4 * 16 + i;
    outp[((size_t)bh * EHEAD + er) * SEQ + l0 + c] = f2b(t[c][er]);
  }
}

__global__ __launch_bounds__(256)
void th_bf16_bf16(const u16* __restrict__ in, u16* __restrict__ outp) {
  int bh = blockIdx.x;
  int b = bh >> 4, hh = bh & 15;
  int l0 = blockIdx.y * 64;
  __shared__ u16 t[64][65];
  int c = threadIdx.x & 63, r4 = threadIdx.x >> 6;
  for (int i = 0; i < 16; ++i) {
    int row = r4 * 16 + i;
    t[row][c] = in[((size_t)b * SEQ + l0 + row) * DMODEL + hh * EHEAD + c];
  }
  __syncthreads();
  for (int i = 0; i < 16; ++i) {
    int er = r4 * 16 + i;
    outp[((size_t)bh * EHEAD + er) * SEQ + l0 + c] = t[c][er];
  }
}

__global__ __launch_bounds__(256)
void probAttn_kernel(const float* __restrict__ qk, const u16* __restrict__ kT,
                     const u16* __restrict__ vT, const int* __restrict__ Mtop,
                     float* __restrict__ upd) {
  int bh = blockIdx.x, b = bh >> 4, hh = bh & 15;
  int wave = threadIdx.x >> 6, lane = threadIdx.x & 63;
  int qg = blockIdx.y * 8 + wave * 2;
  int i0 = Mtop[bh * NTOP + qg], i1 = Mtop[bh * NTOP + qg + 1];
  float qv0 = qk[((size_t)b * SEQ + i0) * 2048 + hh * EHEAD + lane];
  float qv1 = qk[((size_t)b * SEQ + i1) * 2048 + hh * EHEAD + lane];
  const u16* kb = kT + (size_t)bh * EHEAD * SEQ;
  const u16* vb = vT + (size_t)bh * EHEAD * SEQ;
  float s0[32], s1[32];
#pragma unroll
  for (int kk = 0; kk < 32; ++kk) { s0[kk] = 0.f; s1[kk] = 0.f; }
  for (int e = 0; e < 64; ++e) {
    float qe0 = __shfl(qv0, e), qe1 = __shfl(qv1, e);
    const u16* kr = kb + (size_t)e * SEQ;
#pragma unroll
    for (int kk = 0; kk < 32; ++kk) {
      float kv = b2f(kr[kk * 64 + lane]);
      s0[kk] += qe0 * kv; s1[kk] += qe1 * kv;
    }
  }
  float m0 = -3e38f, m1 = -3e38f;
#pragma unroll
  for (int kk = 0; kk < 32; ++kk) {
    int key = kk * 64 + lane;
    s0[kk] = (key > i0) ? -1e9f : s0[kk] * 0.125f;
    s1[kk] = (key > i1) ? -1e9f : s1[kk] * 0.125f;
    m0 = fmaxf(m0, s0[kk]); m1 = fmaxf(m1, s1[kk]);
  }
#pragma unroll
  for (int m = 1; m < 64; m <<= 1) {
    m0 = fmaxf(m0, __shfl_xor(m0, m));
    m1 = fmaxf(m1, __shfl_xor(m1, m));
  }
  float sum0 = 0.f, sum1 = 0.f;
#pragma unroll
  for (int kk = 0; kk < 32; ++kk) {
    s0[kk] = __expf(s0[kk] - m0); sum0 += s0[kk];
    s1[kk] = __expf(s1[kk] - m1); sum1 += s1[kk];
  }
#pragma unroll
  for (int m = 1; m < 64; m <<= 1) {
    sum0 += __shfl_xor(sum0, m);
    sum1 += __shfl_xor(sum1, m);
  }
  float o0 = 0.f, o1 = 0.f;
  for (int e = 0; e < 64; ++e) {
    const u16* vr = vb + (size_t)e * SEQ;
    float a0 = 0.f, a1 = 0.f;
#pragma unroll
    for (int kk = 0; kk < 32; ++kk) {
      float vv = b2f(vr[kk * 64 + lane]);
      a0 += s0[kk] * vv; a1 += s1[kk] * vv;
    }
#pragma unroll
    for (int m = 1; m < 64; m <<= 1) {
      a0 += __shfl_xor(a0, m);
      a1 += __shfl_xor(a1, m);
    }
    if (lane == e) { o0 = a0; o1 = a1; }
  }
  upd[((size_t)bh * NTOP + qg) * EHEAD + lane] = o0 / sum0;
  upd[((size_t)bh * NTOP + qg + 1) * EHEAD + lane] = o1 / sum1;
}

__global__ __launch_bounds__(64)
void scan1_kernel(const u16* __restrict__ v, float* __restrict__ ctx,
                  float* __restrict__ csum) {
  int bh = blockIdx.x, c = blockIdx.y;
  int b = bh >> 4, hh = bh & 15, e = threadIdx.x;
  size_t base = ((size_t)b * SEQ + c * 128) * DMODEL + hh * EHEAD + e;
  float run = 0.f;
  for (int i = 0; i < 128; ++i) {
    run += b2f(v[base + (size_t)i * DMODEL]);
    ctx[base + (size_t)i * DMODEL] = run;
  }
  csum[(bh * 16 + c) * 64 + e] = run;
}

// add chunk offsets, write bf16 (single rounding)
__global__ __launch_bounds__(64)
void scan2_kernel(const float* __restrict__ csum, const float* __restrict__ ctxf,
                  u16* __restrict__ ctxb) {
  int bh = blockIdx.x, c = blockIdx.y;   // 0..15
  int b = bh >> 4, hh = bh & 15, e = threadIdx.x;
  float off = 0.f;
  for (int cc = 0; cc < c; ++cc) off += csum[(bh * 16 + cc) * 64 + e];
  size_t base = ((size_t)b * SEQ + c * 128) * DMODEL + hh * EHEAD + e;
  for (int i = 0; i < 128; ++i)
    ctxb[base + (size_t)i * DMODEL] = f2b(ctxf[base + (size_t)i * DMODEL] + off);
}

__global__ __launch_bounds__(256)
void scatter_kernel(const float* __restrict__ upd, const int* __restrict__ Mtop,
                    u16* __restrict__ ctxb) {
  int i = blockIdx.x * 256 + threadIdx.x;  // < 81920
  int e = i & 63;
  int t = i >> 6;
  int bh = t / NTOP;
  int b = bh >> 4, hh = bh & 15;
  int row = Mtop[t];
  ctxb[((size_t)b * SEQ + row) * DMODEL + hh * EHEAD + e] = f2b(upd[i]);
}

// ---------------------------------------------------------------- kv pack
__global__ __launch_bounds__(256)
void kvpack_kernel(const u16* __restrict__ kv, u16* __restrict__ kpack,
                   u16* __restrict__ vpack) {
  int bh = blockIdx.x, ch = blockIdx.y;
  int b = bh >> 4, hh = bh & 15;
  int tid = threadIdx.x;
  __shared__ u16 vt[64][80];
#pragma unroll
  for (int rep = 0; rep < 2; ++rep) {
    int u = rep * 256 + tid;
    int key = u >> 3, c = u & 7;
    u16x8_t d = *(const u16x8_t*)(kv + ((size_t)(b * SEQ + ch * 64 + key)) * 2048 + hh * 64 + c * 8);
    int slot = (key & 3) | (((key >> 3) & 1) << 2);
    *(u16x8_t*)(kpack + ((size_t)bh * SEQ + ch * 64 + key) * 64 + ((c ^ slot) * 8)) = d;
    u16x8_t dv = *(const u16x8_t*)(kv + ((size_t)(b * SEQ + ch * 64 + key)) * 2048 + 1024 + hh * 64 + c * 8);
    *(u16x8_t*)(&vt[key][c * 8]) = dv;
  }
  __syncthreads();
#pragma unroll
  for (int rep = 0; rep < 2; ++rep) {
    int u = rep * 256 + tid;
    int e = u >> 3, c = u & 7;
    int kb = (c ^ (e & 7)) * 8;
    u16x8_t d;
#pragma unroll
    for (int j = 0; j < 8; ++j) d[j] = vt[kb + j][e];
    *(u16x8_t*)(vpack + (((size_t)bh * 32 + ch) * 64 + e) * 64 + c * 8) = d;
  }
}

// ---------------------------------------------------------------- cross attn
__global__ __launch_bounds__(512)
void cross_attn_kernel(const float* __restrict__ q2, const u16* __restrict__ kpack,
                       const u16* __restrict__ vpack, u16* __restrict__ cab) {
  const int bh = blockIdx.x, b = bh >> 4, hh = bh & 15;
  const int qt0 = blockIdx.y * 128;
  const int tid = threadIdx.x, wave = tid >> 6, lane = tid & 63;
  const int lr = lane & 15, kg = lane >> 4;
  const int wv = __builtin_amdgcn_readfirstlane(wave);
  __shared__ __align__(16) u16 Qs[128 * 64];
  __shared__ __align__(16) u16 Kt[2][64 * 64];
  __shared__ __align__(16) u16 Vt[2][64 * 64];

#pragma unroll
  for (int i = 0; i < 4; ++i) {
    int j = tid + 512 * i;
    int row = j >> 4, c4 = j & 15;
    f32x4_t v4 = *(const f32x4_t*)(q2 + ((size_t)b * SEQ + qt0 + row) * DMODEL + hh * EHEAD + c4 * 4);
    u16x4_t b4;
    b4[0] = f2b(v4[0] * 0.125f); b4[1] = f2b(v4[1] * 0.125f);
    b4[2] = f2b(v4[2] * 0.125f); b4[3] = f2b(v4[3] * 0.125f);
    *(u16x4_t*)((char*)Qs + ((row * 128 + c4 * 8) ^ ((row & 7) << 4))) = b4;
  }

  const char* kgl = (const char*)kpack + (size_t)bh * SEQ * 128;
  const char* vgl = (const char*)vpack + (size_t)bh * 32 * 8192;
  auto STAGE = [&](int buf, int t) {
    GLD16(kgl + (size_t)t * 8192 + wv * 1024 + lane * 16, (char*)Kt[buf] + wv * 1024);
    GLD16(vgl + (size_t)t * 8192 + wv * 1024 + lane * 16, (char*)Vt[buf] + wv * 1024);
  };

  STAGE(0, 0);
  __syncthreads();

  u16x8_t bq[2];
  {
    int qrow = wave * 16 + lr;
#pragma unroll
    for (int ks = 0; ks < 2; ++ks)
      bq[ks] = *(u16x8_t*)((char*)Qs + ((qrow * 128 + ks * 64 + kg * 16) ^ ((qrow & 7) << 4)));
  }

  f32x4_t oacc[4];
#pragma unroll
  for (int i = 0; i < 4; ++i) oacc[i] = f32x4_t{0.f, 0.f, 0.f, 0.f};
  float mrun = -3e38f, lrun = 0.f;

  for (int t = 0; t < 32; ++t) {
    const int cur = t & 1;
    if (t + 1 < 32) STAGE(cur ^ 1, t + 1);
    f32x4_t s[4];
#pragma unroll
    for (int i = 0; i < 4; ++i) s[i] = f32x4_t{0.f, 0.f, 0.f, 0.f};
#pragma unroll
    for (int ks = 0; ks < 2; ++ks)
#pragma unroll
      for (int t4 = 0; t4 < 4; ++t4) {
        int arow = ((t4 >> 1) << 5) + ((lr >> 2) << 3) + ((t4 & 1) << 2) + (lr & 3);
        int slot = (arow & 3) | (((arow >> 3) & 1) << 2);
        int off = (arow << 7) + (ks << 6) + (kg << 4);
        u16x8_t ak = *(const u16x8_t*)((const char*)Kt[cur] + (off ^ (slot << 4)));
        s[t4] = mfma_bf16(ak, bq[ks], s[t4]);
      }
    float mx = s[0][0];
#pragma unroll
    for (int t4 = 0; t4 < 4; ++t4)
#pragma unroll
      for (int r = 0; r < 4; ++r) mx = fmaxf(mx, s[t4][r]);
    mx = fmaxf(mx, __shfl_xor(mx, 16));
    mx = fmaxf(mx, __shfl_xor(mx, 32));
    float mnew = fmaxf(mrun, mx);
    float a = __expf(mrun - mnew);
    float sum = 0.f;
#pragma unroll
    for (int t4 = 0; t4 < 4; ++t4)
#pragma unroll
      for (int r = 0; r < 4; ++r) {
        float p = __expf(s[t4][r] - mnew);
        s[t4][r] = p; sum += p;
      }
    sum += __shfl_xor(sum, 16);
    sum += __shfl_xor(sum, 32);
    lrun = lrun * a + sum;
    mrun = mnew;
    float ar[4];
#pragma unroll
    for (int r = 0; r < 4; ++r) ar[r] = __shfl(a, kg * 4 + r);
#pragma unroll
    for (int ne = 0; ne < 4; ++ne)
#pragma unroll
      for (int r = 0; r < 4; ++r) oacc[ne][r] *= ar[r];
#pragma unroll
    for (int ks2 = 0; ks2 < 2; ++ks2) {
      u16x8_t pa;
#pragma unroll
      for (int j = 0; j < 4; ++j) {
        pa[j] = f2b(s[2 * ks2][j]);
        pa[4 + j] = f2b(s[2 * ks2 + 1][j]);
      }
#pragma unroll
      for (int ne = 0; ne < 4; ++ne) {
        int e = ne * 16 + lr;
        int off = (e << 7) + (ks2 << 6) + (kg << 4);
        u16x8_t bv = *(const u16x8_t*)((const char*)Vt[cur] + (off ^ ((e & 7) << 4)));
        oacc[ne] = mfma_bf16(pa, bv, oacc[ne]);
      }
    }
    __syncthreads();
  }

  float lr4[4];
#pragma unroll
  for (int r = 0; r < 4; ++r) lr4[r] = __shfl(lrun, kg * 4 + r);
#pragma unroll
  for (int ne = 0; ne < 4; ++ne)
#pragma unroll
    for (int r = 0; r < 4; ++r) {
      int row = qt0 + wave * 16 + kg * 4 + r;
      int col = hh * EHEAD + ne * 16 + lr;
      cab[((size_t)b * SEQ + row) * DMODEL + col] = f2b(oacc[ne][r] / lr4[r]);
    }
}

// ---------------------------------------------------------------- layernorm
__global__ __launch_bounds__(256)
void ln_kernel(const float* __restrict__ x, const float* __restrict__ r,
               const float* __restrict__ g, const float* __restrict__ be,
               float* __restrict__ outf, u16* __restrict__ outb) {
  int row = blockIdx.x, tid = threadIdx.x;
  size_t base = (size_t)row * DMODEL;
  float v[4];
  float s = 0.f, sq = 0.f;
#pragma unroll
  for (int i = 0; i < 4; ++i) {
    int c = tid + i * 256;
    float t = x[base + c] + r[base + c];
    v[i] = t; s += t; sq += t * t;
  }
  __shared__ float rs[256], rq[256];
  rs[tid] = s; rq[tid] = sq;
  __syncthreads();
  for (int st = 128; st > 0; st >>= 1) {
    if (tid < st) { rs[tid] += rs[tid + st]; rq[tid] += rq[tid + st]; }
    __syncthreads();
  }
  float mean = rs[0] * (1.f / DMODEL);
  float var = rq[0] * (1.f / DMODEL) - mean * mean;
  float rstd = rsqrtf(var + 1e-5f);
#pragma unroll
  for (int i = 0; i < 4; ++i) {
    int c = tid + i * 256;
    float o = (v[i] - mean) * rstd * g[c] + be[c];
    if (outf) outf[base + c] = o;
    if (outb) outb[base + c] = f2b(o);
  }
}

// ---------------------------------------------------------------- host side
static inline void gemm(const u16* A, const u16* Bt, const float* bias, float* Cf,
                        u16* Cb, int M, int N, int K, int relu, hipStream_t s,
                        int big = 0) {
  if (big)
    gemm_bf<4><<<dim3(M / 128, N / 128), 256, 0, s>>>(A, Bt, bias, Cf, Cb, M, N, K, relu);
  else
    gemm_bf<2><<<dim3(M / 128, N / 64), 256, 0, s>>>(A, Bt, bias, Cf, Cb, M, N, K, relu);
}
static inline void gemm4(const u16* Ah, const u16* Al, const u16* Bh, const u16* Bl,
                         const float* bias, float* Cf, int M, int N, int K, hipStream_t s) {
  gemm4_bf<4><<<dim3(M / 128, N / 128), 256, 0, s>>>(Ah, Al, Bh, Bl, bias, Cf, M, N, K);
}

extern "C" void kernel_launch(void* const* d_in, const int* in_sizes, int n_in,
                              void* d_out, int out_size, void* d_ws, size_t ws_size,
                              hipStream_t stream) {
  const float* x   = (const float*)d_in[0];
  const float* mem = (const float*)d_in[1];
  const float* sWq = (const float*)d_in[2];  const float* sbq = (const float*)d_in[3];
  const float* sWk = (const float*)d_in[4];  const float* sbk = (const float*)d_in[5];
  const float* sWv = (const float*)d_in[6];  const float* sbv = (const float*)d_in[7];
  const float* sWo = (const float*)d_in[8];  const float* sbo = (const float*)d_in[9];
  const float* cWq = (const float*)d_in[10]; const float* cbq = (const float*)d_in[11];
  const float* cWk = (const float*)d_in[12]; const float* cbk = (const float*)d_in[13];
  const float* cWv = (const float*)d_in[14]; const float* cbv = (const float*)d_in[15];
  const float* cWo = (const float*)d_in[16]; const float* cbo = (const float*)d_in[17];
  const float* W1  = (const float*)d_in[18]; const float* b1  = (const float*)d_in[19];
  const float* W2  = (const float*)d_in[20]; const float* b2  = (const float*)d_in[21];
  const float* g1  = (const float*)d_in[22]; const float* be1 = (const float*)d_in[23];
  const float* g2  = (const float*)d_in[24]; const float* be2 = (const float*)d_in[25];
  const float* g3  = (const float*)d_in[26]; const float* be3 = (const float*)d_in[27];
  float* outp = (float*)d_out;
  char* ws = (char*)d_ws;
  const size_t MB = 1ull << 20;

  int*   idx    = (int*)(ws);
  float* Mv     = (float*)(ws + 0x60000);
  int*   Mtop   = (int*)(ws + 0xA0000);
  float* upd    = (float*)(ws + 0xA2000);
  float* csum   = (float*)(ws + 0x100000);
  float* biasqk = (float*)(ws + 0x120000);
  float* cbkv   = (float*)(ws + 0x122000);

  u16* WqkhT = (u16*)(ws + 2 * MB);    // [2048][1024]
  u16* WqklT = (u16*)(ws + 6 * MB);
  u16* sWvT  = (u16*)(ws + 10 * MB);
  u16* sWoT  = (u16*)(ws + 12 * MB);
  u16* cWqT  = (u16*)(ws + 14 * MB);
  u16* cWkvT = (u16*)(ws + 16 * MB);   // [2048][1024]
  u16* cWoT  = (u16*)(ws + 20 * MB);
  u16* W1T   = (u16*)(ws + 22 * MB);
  u16* W2T   = (u16*)(ws + 30 * MB);

  u16* xh   = (u16*)(ws + 38 * MB);
  u16* xl   = (u16*)(ws + 46 * MB);
  u16* memb = (u16*)(ws + 54 * MB);

  float* qk   = (float*)(ws + 62 * MB);    // [4096][2048] f32, 32MB [62,94)
  u16*   vbf  = (u16*)(ws + 94 * MB);
  u16*   kTb  = (u16*)(ws + 102 * MB);
  u16*   vTb  = (u16*)(ws + 46 * MB);      // reuse xl (dead after gemm4)
  float* ctxf = (float*)(ws + 62 * MB);    // reuse qk (dead after probAttn)
  u16*   ctxb = (u16*)(ws + 78 * MB);
  float* sa   = (float*)(ws + 94 * MB);    // reuse vbf+kTb
  float* x1   = (float*)(ws + 62 * MB);
  u16*   x1b  = (u16*)(ws + 78 * MB);
  float* q2   = (float*)(ws + 94 * MB);
  u16*   kv2b = (u16*)(ws + 38 * MB);      // [4096][2048] bf16, 16MB [38,54)
  u16*   kpk  = (u16*)(ws + 54 * MB);      // 8MB (over memb, dead)
  u16*   vpk  = (u16*)(ws + 110 * MB);     // 8MB
  u16*   cab  = (u16*)(ws + 38 * MB);      // over kv2b (dead after kvpack)
  float* ca2  = (float*)(ws + 94 * MB);    // over q2
  float* x2   = (float*)(ws + 38 * MB);
  u16*   x2b  = (u16*)(ws + 54 * MB);
  u16*   hbb  = (u16*)(ws + 62 * MB);      // 32MB [62,94)
  float* yb   = (float*)(ws + 94 * MB);

  const int MROWS = BATCH * SEQ;  // 4096

  // ---- prep ----
  idx_kernel<<<320, 256, 0, stream>>>(idx);
  wsplit_kernel<<<dim3(16, 16), 256, 0, stream>>>(sWq, WqkhT, WqklT, 1024, 1024);
  wsplit_kernel<<<dim3(16, 16), 256, 0, stream>>>(sWk, WqkhT + 1024 * 1024, WqklT + 1024 * 1024, 1024, 1024);
  wt_kernel<<<dim3(16, 16), 256, 0, stream>>>(sWv, sWvT, 1024, 1024);
  wt_kernel<<<dim3(16, 16), 256, 0, stream>>>(sWo, sWoT, 1024, 1024);
  wt_kernel<<<dim3(16, 16), 256, 0, stream>>>(cWq, cWqT, 1024, 1024);
  wt_kernel<<<dim3(16, 16), 256, 0, stream>>>(cWk, cWkvT, 1024, 1024);
  wt_kernel<<<dim3(16, 16), 256, 0, stream>>>(cWv, cWkvT + 1024 * 1024, 1024, 1024);
  wt_kernel<<<dim3(16, 16), 256, 0, stream>>>(cWo, cWoT, 1024, 1024);
  wt_kernel<<<dim3(64, 16), 256, 0, stream>>>(W1, W1T, 1024, 4096);
  wt_kernel<<<dim3(16, 64), 256, 0, stream>>>(W2, W2T, 4096, 1024);
  split_kernel<<<4096, 256, 0, stream>>>(x, xh, xl);
  conv_kernel<<<4096, 256, 0, stream>>>(mem, memb);
  pack2_kernel<<<8, 256, 0, stream>>>(sbq, sbk, biasqk, 1024);
  pack2_kernel<<<8, 256, 0, stream>>>(cbk, cbv, cbkv, 1024);

  // ---- self attention (ProbSparse) ----
  gemm4(xh, xl, WqkhT, WqklT, biasqk, qk, MROWS, 2048, DMODEL, stream);
  gemm(xh, sWvT, sbv, nullptr, vbf, MROWS, DMODEL, DMODEL, 0, stream);
  probM_kernel<<<BATCH * SEQ / 4, 256, 0, stream>>>(qk, idx, Mv);
  topk_kernel<<<BATCH * NHEADS, 256, 0, stream>>>(Mv, Mtop);
  th_f32_bf16<<<dim3(BATCH * NHEADS, SEQ / 64), 256, 0, stream>>>(qk, kTb, 2048, 1024);
  th_bf16_bf16<<<dim3(BATCH * NHEADS, SEQ / 64), 256, 0, stream>>>(vbf, vTb);
  probAttn_kernel<<<dim3(BATCH * NHEADS, 5), 256, 0, stream>>>(qk, kTb, vTb, Mtop, upd);
  scan1_kernel<<<dim3(BATCH * NHEADS, 16), 64, 0, stream>>>(vbf, ctxf, csum);
  scan2_kernel<<<dim3(BATCH * NHEADS, 16), 64, 0, stream>>>(csum, ctxf, ctxb);
  scatter_kernel<<<BATCH * NHEADS * NTOP * EHEAD / 256, 256, 0, stream>>>(upd, Mtop, ctxb);
  gemm(ctxb, sWoT, sbo, sa, nullptr, MROWS, DMODEL, DMODEL, 0, stream);
  ln_kernel<<<MROWS, 256, 0, stream>>>(x, sa, g1, be1, x1, x1b);

  // ---- cross attention ----
  gemm(x1b, cWqT, cbq, q2, nullptr, MROWS, DMODEL, DMODEL, 0, stream);
  gemm(memb, cWkvT, cbkv, nullptr, kv2b, MROWS, 2048, DMODEL, 0, stream, 1);
  kvpack_kernel<<<dim3(BATCH * NHEADS, SEQ / 64), 256, 0, stream>>>(kv2b, kpk, vpk);
  cross_attn_kernel<<<dim3(BATCH * NHEADS, SEQ / 128), 512, 0, stream>>>(q2, kpk, vpk, cab);
  gemm(cab, cWoT, cbo, ca2, nullptr, MROWS, DMODEL, DMODEL, 0, stream);
  ln_kernel<<<MROWS, 256, 0, stream>>>(x1, ca2, g2, be2, x2, x2b);

  // ---- FFN ----
  gemm(x2b, W1T, b1, nullptr, hbb, MROWS, DFF, DMODEL, 1, stream, 1);
  gemm(hbb, W2T, b2, yb, nullptr, MROWS, DMODEL, DFF, 0, stream);
  ln_kernel<<<MROWS, 256, 0, stream>>>(x2, yb, g3, be3, outp, nullptr);
}

// Round 6
// 586.689 us; speedup vs baseline: 2.0360x; 1.1506x over previous
//
#include <hip/hip_runtime.h>

static constexpr int BATCH  = 2;
static constexpr int SEQ    = 2048;
static constexpr int DMODEL = 1024;
static constexpr int NHEADS = 16;
static constexpr int EHEAD  = 64;
static constexpr int DFF    = 4096;
static constexpr int NTOP   = 40;

typedef unsigned short u16;
typedef __bf16 bf16x8_t __attribute__((ext_vector_type(8)));
typedef u16    u16x8_t  __attribute__((ext_vector_type(8)));
typedef u16    u16x4_t  __attribute__((ext_vector_type(4)));
typedef float  f32x4_t  __attribute__((ext_vector_type(4)));

static __device__ __forceinline__ u16 f2b(float f) {
  unsigned u = __builtin_bit_cast(unsigned, f);
  unsigned r = u + 0x7FFFu + ((u >> 16) & 1u);
  return (u16)(r >> 16);
}
static __device__ __forceinline__ float b2f(u16 h) {
  unsigned u = ((unsigned)h) << 16;
  return __builtin_bit_cast(float, u);
}
static __device__ __forceinline__ f32x4_t mfma_bf16(u16x8_t a, u16x8_t b, f32x4_t c) {
  return __builtin_amdgcn_mfma_f32_16x16x32_bf16(
      __builtin_bit_cast(bf16x8_t, a), __builtin_bit_cast(bf16x8_t, b), c, 0, 0, 0);
}

#define GLD16(gsrc, ldst)                                                        \
  __builtin_amdgcn_global_load_lds(                                             \
      (const __attribute__((address_space(1))) void*)(gsrc),                    \
      (__attribute__((address_space(3))) void*)(ldst), 16, 0, 0)

// ---------------------------------------------------------------- threefry
static __device__ __forceinline__ void tf2x32(unsigned k0, unsigned k1,
                                              unsigned x0, unsigned x1,
                                              unsigned& o0, unsigned& o1) {
  unsigned ks2 = 0x1BD11BDAu ^ k0 ^ k1;
  x0 += k0; x1 += k1;
#define TFR(r) { x0 += x1; x1 = (x1 << r) | (x1 >> (32 - r)); x1 ^= x0; }
  TFR(13) TFR(15) TFR(26) TFR(6)  x0 += k1;  x1 += ks2 + 1u;
  TFR(17) TFR(29) TFR(16) TFR(24) x0 += ks2; x1 += k0 + 2u;
  TFR(13) TFR(15) TFR(26) TFR(6)  x0 += k0;  x1 += k1 + 3u;
  TFR(17) TFR(29) TFR(16) TFR(24) x0 += k1;  x1 += ks2 + 4u;
  TFR(13) TFR(15) TFR(26) TFR(6)  x0 += ks2; x1 += k0 + 5u;
#undef TFR
  o0 = x0; o1 = x1;
}

__global__ __launch_bounds__(256) void idx_kernel(int* __restrict__ idx) {
  int i = blockIdx.x * 256 + threadIdx.x;           // 0..81919, grid 320
  unsigned c0, c1, o0, o1;
  tf2x32(0u, 42u, 0u, 1u, c0, c1);                  // k2 = second split child
  tf2x32(c0, c1, 0u, (unsigned)i, o0, o1);
  idx[i] = (int)((o0 ^ o1) & 2047u);
}

// ---------------------------------------------------------------- prep
__global__ __launch_bounds__(256)
void wt_kernel(const float* __restrict__ in, u16* __restrict__ outp, int K, int N) {
  __shared__ float t[64][65];
  int k0 = blockIdx.y * 64, n0 = blockIdx.x * 64;
  int c = threadIdx.x & 63, r4 = threadIdx.x >> 6;
#pragma unroll
  for (int i = 0; i < 16; ++i) {
    int r = r4 * 16 + i;
    t[r][c] = in[(size_t)(k0 + r) * N + n0 + c];
  }
  __syncthreads();
#pragma unroll
  for (int i = 0; i < 16; ++i) {
    int r = r4 * 16 + i;
    outp[(size_t)(n0 + r) * K + k0 + c] = f2b(t[c][r]);
  }
}

__global__ __launch_bounds__(256)
void wsplit_kernel(const float* __restrict__ in, u16* __restrict__ oh,
                   u16* __restrict__ ol, int K, int N) {
  __shared__ float t[64][65];
  int k0 = blockIdx.y * 64, n0 = blockIdx.x * 64;
  int c = threadIdx.x & 63, r4 = threadIdx.x >> 6;
#pragma unroll
  for (int i = 0; i < 16; ++i) {
    int r = r4 * 16 + i;
    t[r][c] = in[(size_t)(k0 + r) * N + n0 + c];
  }
  __syncthreads();
#pragma unroll
  for (int i = 0; i < 16; ++i) {
    int r = r4 * 16 + i;
    float f = t[c][r];
    u16 h = f2b(f);
    oh[(size_t)(n0 + r) * K + k0 + c] = h;
    ol[(size_t)(n0 + r) * K + k0 + c] = f2b(f - b2f(h));
  }
}

__global__ __launch_bounds__(256)
void conv_kernel(const float* __restrict__ in, u16* __restrict__ outp) {
  int i = blockIdx.x * 256 + threadIdx.x;
  f32x4_t v = *(const f32x4_t*)(in + (size_t)i * 4);
  u16x4_t o;
  o[0] = f2b(v[0]); o[1] = f2b(v[1]); o[2] = f2b(v[2]); o[3] = f2b(v[3]);
  *(u16x4_t*)(outp + (size_t)i * 4) = o;
}

__global__ __launch_bounds__(256)
void split_kernel(const float* __restrict__ in, u16* __restrict__ oh,
                  u16* __restrict__ ol) {
  int i = blockIdx.x * 256 + threadIdx.x;
  f32x4_t v = *(const f32x4_t*)(in + (size_t)i * 4);
  u16x4_t h, l;
#pragma unroll
  for (int d = 0; d < 4; ++d) {
    u16 hh = f2b(v[d]); h[d] = hh; l[d] = f2b(v[d] - b2f(hh));
  }
  *(u16x4_t*)(oh + (size_t)i * 4) = h;
  *(u16x4_t*)(ol + (size_t)i * 4) = l;
}

__global__ __launch_bounds__(256)
void pack2_kernel(const float* __restrict__ a, const float* __restrict__ b,
                  float* __restrict__ o, int n) {
  int i = blockIdx.x * 256 + threadIdx.x;
  if (i < 2 * n) o[i] = (i < n) ? a[i] : b[i - n];
}

// ---------------------------------------------------------------- bf16 GEMM
template<int NF>
__global__ __launch_bounds__(256)
void gemm_bf(const u16* __restrict__ A, const u16* __restrict__ Bt,
             const float* __restrict__ bias, float* __restrict__ Cf,
             u16* __restrict__ Cb, int M, int N, int K, int relu) {
  __shared__ __align__(16) u16 sA[2][128 * 32];
  __shared__ __align__(16) u16 sB[2][NF * 32 * 32];
  const int tid = threadIdx.x;
  const int wave = tid >> 6, lane = tid & 63;
  const int m0 = blockIdx.x * 128, n0 = blockIdx.y * (NF * 32);
  const int wr = (wave >> 1) * 64, wc = (wave & 1) * (NF * 16);
  const int lr = lane & 15, kg = lane >> 4;
  const int wv = __builtin_amdgcn_readfirstlane(wave);

  int rowA[2], c8A[2];
#pragma unroll
  for (int rep = 0; rep < 2; ++rep) {
    int P = (rep * 256 + tid) << 4;
    int L = P ^ (((P >> 7) & 3) << 4);
    rowA[rep] = L >> 6; c8A[rep] = (L >> 4) & 3;
  }
  int rowB[NF / 2], c8B[NF / 2];
#pragma unroll
  for (int rep = 0; rep < NF / 2; ++rep) {
    int P = (rep * 256 + tid) << 4;
    int L = P ^ (((P >> 7) & 3) << 4);
    rowB[rep] = L >> 6; c8B[rep] = (L >> 4) & 3;
  }

  f32x4_t acc[4][NF];
#pragma unroll
  for (int i = 0; i < 4; ++i)
#pragma unroll
    for (int j = 0; j < NF; ++j) acc[i][j] = f32x4_t{0.f, 0.f, 0.f, 0.f};

  auto STAGE = [&](int buf, int k0) {
#pragma unroll
    for (int rep = 0; rep < 2; ++rep)
      GLD16(A + (size_t)(m0 + rowA[rep]) * K + k0 + c8A[rep] * 8,
            &sA[buf][(rep * 256 + wv * 64) * 8]);
#pragma unroll
    for (int rep = 0; rep < NF / 2; ++rep)
      GLD16(Bt + (size_t)(n0 + rowB[rep]) * K + k0 + c8B[rep] * 8,
            &sB[buf][(rep * 256 + wv * 64) * 8]);
  };

  const int nk = K >> 5;
  STAGE(0, 0);
  __syncthreads();
  for (int t = 0; t < nk; ++t) {
    const int cur = t & 1;
    if (t + 1 < nk) STAGE(cur ^ 1, (t + 1) << 5);
    u16x8_t a8[4], b8[NF];
#pragma unroll
    for (int mi = 0; mi < 4; ++mi) {
      int La = (wr + mi * 16 + lr) * 64 + kg * 16;
      a8[mi] = *(const u16x8_t*)((const char*)sA[cur] + (La ^ (((La >> 7) & 3) << 4)));
    }
#pragma unroll
    for (int ni = 0; ni < NF; ++ni) {
      int Lb = (wc + ni * 16 + lr) * 64 + kg * 16;
      b8[ni] = *(const u16x8_t*)((const char*)sB[cur] + (Lb ^ (((Lb >> 7) & 3) << 4)));
    }
#pragma unroll
    for (int mi = 0; mi < 4; ++mi)
#pragma unroll
      for (int ni = 0; ni < NF; ++ni)
        acc[mi][ni] = mfma_bf16(a8[mi], b8[ni], acc[mi][ni]);
    __syncthreads();
  }
#pragma unroll
  for (int ni = 0; ni < NF; ++ni) {
    int col = n0 + wc + ni * 16 + lr;
    float bc = bias[col];
#pragma unroll
    for (int mi = 0; mi < 4; ++mi)
#pragma unroll
      for (int r = 0; r < 4; ++r) {
        int row = m0 + wr + mi * 16 + kg * 4 + r;
        float vv = acc[mi][ni][r] + bc;
        if (relu) vv = fmaxf(vv, 0.f);
        if (Cf) Cf[(size_t)row * N + col] = vv;
        if (Cb) Cb[(size_t)row * N + col] = f2b(vv);
      }
  }
}

// 3-term split GEMM (f32-equivalent: hi*hi + hi*lo + lo*hi; lo*lo ~ 2^-18 negligible)
template<int NF>
__global__ __launch_bounds__(256)
void gemm4_bf(const u16* __restrict__ Ah, const u16* __restrict__ Al,
              const u16* __restrict__ Bh, const u16* __restrict__ Bl,
              const float* __restrict__ bias, float* __restrict__ Cf,
              int M, int N, int K) {
  __shared__ __align__(16) u16 sAh[2][128 * 32];
  __shared__ __align__(16) u16 sAl[2][128 * 32];
  __shared__ __align__(16) u16 sBh[2][NF * 32 * 32];
  __shared__ __align__(16) u16 sBl[2][NF * 32 * 32];
  const int tid = threadIdx.x;
  const int wave = tid >> 6, lane = tid & 63;
  const int m0 = blockIdx.x * 128, n0 = blockIdx.y * (NF * 32);
  const int wr = (wave >> 1) * 64, wc = (wave & 1) * (NF * 16);
  const int lr = lane & 15, kg = lane >> 4;
  const int wv = __builtin_amdgcn_readfirstlane(wave);

  int rowA[2], c8A[2];
#pragma unroll
  for (int rep = 0; rep < 2; ++rep) {
    int P = (rep * 256 + tid) << 4;
    int L = P ^ (((P >> 7) & 3) << 4);
    rowA[rep] = L >> 6; c8A[rep] = (L >> 4) & 3;
  }
  int rowB[NF / 2], c8B[NF / 2];
#pragma unroll
  for (int rep = 0; rep < NF / 2; ++rep) {
    int P = (rep * 256 + tid) << 4;
    int L = P ^ (((P >> 7) & 3) << 4);
    rowB[rep] = L >> 6; c8B[rep] = (L >> 4) & 3;
  }

  f32x4_t acc[4][NF];
#pragma unroll
  for (int i = 0; i < 4; ++i)
#pragma unroll
    for (int j = 0; j < NF; ++j) acc[i][j] = f32x4_t{0.f, 0.f, 0.f, 0.f};

  auto STAGE = [&](int buf, int k0) {
#pragma unroll
    for (int rep = 0; rep < 2; ++rep) {
      GLD16(Ah + (size_t)(m0 + rowA[rep]) * K + k0 + c8A[rep] * 8,
            &sAh[buf][(rep * 256 + wv * 64) * 8]);
      GLD16(Al + (size_t)(m0 + rowA[rep]) * K + k0 + c8A[rep] * 8,
            &sAl[buf][(rep * 256 + wv * 64) * 8]);
    }
#pragma unroll
    for (int rep = 0; rep < NF / 2; ++rep) {
      GLD16(Bh + (size_t)(n0 + rowB[rep]) * K + k0 + c8B[rep] * 8,
            &sBh[buf][(rep * 256 + wv * 64) * 8]);
      GLD16(Bl + (size_t)(n0 + rowB[rep]) * K + k0 + c8B[rep] * 8,
            &sBl[buf][(rep * 256 + wv * 64) * 8]);
    }
  };

  const int nk = K >> 5;
  STAGE(0, 0);
  __syncthreads();
  for (int t = 0; t < nk; ++t) {
    const int cur = t & 1;
    if (t + 1 < nk) STAGE(cur ^ 1, (t + 1) << 5);
    u16x8_t ah[4], al[4], bh[NF], bl[NF];
#pragma unroll
    for (int mi = 0; mi < 4; ++mi) {
      int La = (wr + mi * 16 + lr) * 64 + kg * 16;
      int off = La ^ (((La >> 7) & 3) << 4);
      ah[mi] = *(const u16x8_t*)((const char*)sAh[cur] + off);
      al[mi] = *(const u16x8_t*)((const char*)sAl[cur] + off);
    }
#pragma unroll
    for (int ni = 0; ni < NF; ++ni) {
      int Lb = (wc + ni * 16 + lr) * 64 + kg * 16;
      int off = Lb ^ (((Lb >> 7) & 3) << 4);
      bh[ni] = *(const u16x8_t*)((const char*)sBh[cur] + off);
      bl[ni] = *(const u16x8_t*)((const char*)sBl[cur] + off);
    }
#pragma unroll
    for (int mi = 0; mi < 4; ++mi)
#pragma unroll
      for (int ni = 0; ni < NF; ++ni) {
        acc[mi][ni] = mfma_bf16(ah[mi], bh[ni], acc[mi][ni]);
        acc[mi][ni] = mfma_bf16(ah[mi], bl[ni], acc[mi][ni]);
        acc[mi][ni] = mfma_bf16(al[mi], bh[ni], acc[mi][ni]);
      }
    __syncthreads();
  }
#pragma unroll
  for (int ni = 0; ni < NF; ++ni) {
    int col = n0 + wc + ni * 16 + lr;
    float bc = bias[col];
#pragma unroll
    for (int mi = 0; mi < 4; ++mi)
#pragma unroll
      for (int r = 0; r < 4; ++r) {
        int row = m0 + wr + mi * 16 + kg * 4 + r;
        Cf[(size_t)row * N + col] = acc[mi][ni][r] + bc;
      }
  }
}

// ---------------------------------------------------------------- ProbSparse
// One wave per (b,l), all 16 heads. Block->XCD pinning: XCDs 0-3 serve batch 0,
// XCDs 4-7 batch 1 (blockIdx round-robins XCDs; halves per-XCD gather set).
__global__ __launch_bounds__(256)
void probM_kernel(const float* __restrict__ qk, const int* __restrict__ idx,
                  float* __restrict__ Mv) {
  int blk = blockIdx.x;                        // 0..1023
  int xcd = blk & 7, j = blk >> 3;             // j: 0..127
  int b = xcd >> 2;
  int part = (xcd & 3) * 128 + j;              // 0..511
  int l = part * 4 + (threadIdx.x >> 6);
  int lane = threadIdx.x & 63;
  const float* qrow = qk + ((size_t)b * SEQ + l) * 2048 + lane * 16;
  f32x4_t qv0 = *(const f32x4_t*)(qrow);
  f32x4_t qv1 = *(const f32x4_t*)(qrow + 4);
  f32x4_t qv2 = *(const f32x4_t*)(qrow + 8);
  f32x4_t qv3 = *(const f32x4_t*)(qrow + 12);
  const int* ip = idx + l * NTOP;
  const float* kbase = qk + (size_t)b * SEQ * 2048 + 1024 + lane * 16;
  float mmax = -3.0e38f, msum = 0.f;
#pragma unroll 4
  for (int u = 0; u < NTOP; ++u) {
    int ki = ip[u];
    const float* kr = kbase + (size_t)ki * 2048;
    f32x4_t k0 = *(const f32x4_t*)(kr);
    f32x4_t k1 = *(const f32x4_t*)(kr + 4);
    f32x4_t k2 = *(const f32x4_t*)(kr + 8);
    f32x4_t k3 = *(const f32x4_t*)(kr + 12);
    float p = qv0[0] * k0[0] + qv0[1] * k0[1] + qv0[2] * k0[2] + qv0[3] * k0[3]
            + qv1[0] * k1[0] + qv1[1] * k1[1] + qv1[2] * k1[2] + qv1[3] * k1[3]
            + qv2[0] * k2[0] + qv2[1] * k2[1] + qv2[2] * k2[2] + qv2[3] * k2[3]
            + qv3[0] * k3[0] + qv3[1] * k3[1] + qv3[2] * k3[2] + qv3[3] * k3[3];
    p += __shfl_xor(p, 1);
    p += __shfl_xor(p, 2);
    mmax = fmaxf(mmax, p);
    msum += p;
  }
  if ((lane & 3) == 0) {
    int hh = lane >> 2;
    Mv[((size_t)b * NHEADS + hh) * SEQ + l] = mmax - msum * (1.f / 2048.f);
  }
}

__global__ __launch_bounds__(256)
void topk_kernel(const float* __restrict__ Mv, int* __restrict__ Mtop) {
  int bh = blockIdx.x;
  int tid = threadIdx.x;
  int lane = tid & 63, wv = tid >> 6;
  __shared__ float vals[2048];
  __shared__ float wrv[4];
  __shared__ int wri[4];
  for (int j = tid; j < 2048; j += 256) vals[j] = Mv[bh * 2048 + j];
  __syncthreads();
  for (int it = 0; it < NTOP; ++it) {
    float best = -3.0e38f;
    int bi = 1 << 30;
    for (int j = tid; j < 2048; j += 256) {
      float vv = vals[j];
      if (vv > best) { best = vv; bi = j; }
    }
#pragma unroll
    for (int m = 1; m < 64; m <<= 1) {
      float ov = __shfl_xor(best, m);
      int oi = __shfl_xor(bi, m);
      if (ov > best || (ov == best && oi < bi)) { best = ov; bi = oi; }
    }
    if (lane == 0) { wrv[wv] = best; wri[wv] = bi; }
    __syncthreads();
    if (tid == 0) {
      float bv = wrv[0]; int bbi = wri[0];
#pragma unroll
      for (int t = 1; t < 4; ++t)
        if (wrv[t] > bv || (wrv[t] == bv && wri[t] < bbi)) { bv = wrv[t]; bbi = wri[t]; }
      Mtop[bh * NTOP + it] = bbi;
      vals[bbi] = -3.4e38f;
    }
    __syncthreads();
  }
}

// ---------------------------------------------------------------- kv pack (self)
// K from qk f32 (cols 1024..2047), V from vbf bf16; same packed layouts as cross.
__global__ __launch_bounds__(256)
void kvpack_self(const float* __restrict__ qk, const u16* __restrict__ vbf,
                 u16* __restrict__ kpack, u16* __restrict__ vpack) {
  int bh = blockIdx.x, ch = blockIdx.y;
  int b = bh >> 4, hh = bh & 15;
  int tid = threadIdx.x;
  __shared__ u16 vt[64][80];
#pragma unroll
  for (int rep = 0; rep < 2; ++rep) {
    int u = rep * 256 + tid;
    int key = u >> 3, c = u & 7;
    const float* ksrc = qk + ((size_t)(b * SEQ + ch * 64 + key)) * 2048 + 1024 + hh * 64 + c * 8;
    f32x4_t k0 = *(const f32x4_t*)ksrc;
    f32x4_t k1 = *(const f32x4_t*)(ksrc + 4);
    u16x8_t d;
    d[0] = f2b(k0[0]); d[1] = f2b(k0[1]); d[2] = f2b(k0[2]); d[3] = f2b(k0[3]);
    d[4] = f2b(k1[0]); d[5] = f2b(k1[1]); d[6] = f2b(k1[2]); d[7] = f2b(k1[3]);
    int slot = (key & 3) | (((key >> 3) & 1) << 2);
    *(u16x8_t*)(kpack + ((size_t)bh * SEQ + ch * 64 + key) * 64 + ((c ^ slot) * 8)) = d;
    u16x8_t dv = *(const u16x8_t*)(vbf + ((size_t)(b * SEQ + ch * 64 + key)) * 1024 + hh * 64 + c * 8);
    *(u16x8_t*)(&vt[key][c * 8]) = dv;
  }
  __syncthreads();
#pragma unroll
  for (int rep = 0; rep < 2; ++rep) {
    int u = rep * 256 + tid;
    int e = u >> 3, c = u & 7;
    int kb = (c ^ (e & 7)) * 8;
    u16x8_t d;
#pragma unroll
    for (int j = 0; j < 8; ++j) d[j] = vt[kb + j][e];
    *(u16x8_t*)(vpack + (((size_t)bh * 32 + ch) * 64 + e) * 64 + c * 8) = d;
  }
}

// ---------------------------------------------------------------- probAttn (MFMA flash, key-split)
// grid (BH, 8 splits). 4 waves; waves 0-2 own q-tiles 0-2 (48 rows, 40 valid).
// Swapped QK^T (A=K, B=Q); causal mask key > iq -> -1e9; partial (m,l,O) out.
__global__ __launch_bounds__(256)
void probAttn_kernel(const float* __restrict__ qk, const u16* __restrict__ kpack,
                     const u16* __restrict__ vpack, const int* __restrict__ Mtop,
                     float* __restrict__ Opart, float* __restrict__ ml) {
  const int bh = blockIdx.x, b = bh >> 4, hh = bh & 15;
  const int split = blockIdx.y;                 // 0..7 (256 keys each)
  const int tid = threadIdx.x, wave = tid >> 6, lane = tid & 63;
  const int lr = lane & 15, kg = lane >> 4;
  const int wv = __builtin_amdgcn_readfirstlane(wave);
  __shared__ __align__(16) u16 Qs[48 * 64];
  __shared__ __align__(16) u16 Kt[2][64 * 64];
  __shared__ __align__(16) u16 Vt[2][64 * 64];

  // stage 48 gathered Q rows (scaled 1/8), cross-style swizzle
#pragma unroll
  for (int rep = 0; rep < 3; ++rep) {
    int j = tid + 256 * rep;        // 0..767
    int row = j >> 4, c4 = j & 15;
    int qi = Mtop[bh * NTOP + (row < NTOP ? row : NTOP - 1)];
    f32x4_t v4 = *(const f32x4_t*)(qk + ((size_t)b * SEQ + qi) * 2048 + hh * EHEAD + c4 * 4);
    u16x4_t b4;
    b4[0] = f2b(v4[0] * 0.125f); b4[1] = f2b(v4[1] * 0.125f);
    b4[2] = f2b(v4[2] * 0.125f); b4[3] = f2b(v4[3] * 0.125f);
    *(u16x4_t*)((char*)Qs + ((row * 128 + c4 * 8) ^ ((row & 7) << 4))) = b4;
  }

  const int qtile = (wave < 3) ? wave : 2;
  const int qrow_g = qtile * 16 + lr;
  const int iq = (qrow_g < NTOP) ? Mtop[bh * NTOP + qrow_g] : -1;

  const char* kgl = (const char*)kpack + (size_t)bh * SEQ * 128 + (size_t)split * 4 * 8192;
  const char* vgl = (const char*)vpack + (size_t)bh * 32 * 8192 + (size_t)split * 4 * 8192;
  auto STAGE = [&](int buf, int t) {
    GLD16(kgl + (size_t)t * 8192 + wv * 2048 + lane * 16, (char*)Kt[buf] + wv * 2048);
    GLD16(kgl + (size_t)t * 8192 + wv * 2048 + 1024 + lane * 16, (char*)Kt[buf] + wv * 2048 + 1024);
    GLD16(vgl + (size_t)t * 8192 + wv * 2048 + lane * 16, (char*)Vt[buf] + wv * 2048);
    GLD16(vgl + (size_t)t * 8192 + wv * 2048 + 1024 + lane * 16, (char*)Vt[buf] + wv * 2048 + 1024);
  };

  STAGE(0, 0);
  __syncthreads();

  u16x8_t bq[2];
  {
    int qrow = qtile * 16 + lr;
#pragma unroll
    for (int ks = 0; ks < 2; ++ks)
      bq[ks] = *(u16x8_t*)((char*)Qs + ((qrow * 128 + ks * 64 + kg * 16) ^ ((qrow & 7) << 4)));
  }

  f32x4_t oacc[4];
#pragma unroll
  for (int i = 0; i < 4; ++i) oacc[i] = f32x4_t{0.f, 0.f, 0.f, 0.f};
  float mrun = -3e38f, lrun = 0.f;

  for (int t = 0; t < 4; ++t) {
    const int cur = t & 1;
    if (t + 1 < 4) STAGE(cur ^ 1, t + 1);
    f32x4_t s[4];
#pragma unroll
    for (int i = 0; i < 4; ++i) s[i] = f32x4_t{0.f, 0.f, 0.f, 0.f};
#pragma unroll
    for (int ks = 0; ks < 2; ++ks)
#pragma unroll
      for (int t4 = 0; t4 < 4; ++t4) {
        int arow = ((t4 >> 1) << 5) + ((lr >> 2) << 3) + ((t4 & 1) << 2) + (lr & 3);
        int slot = (arow & 3) | (((arow >> 3) & 1) << 2);
        int off = (arow << 7) + (ks << 6) + (kg << 4);
        u16x8_t ak = *(const u16x8_t*)((const char*)Kt[cur] + (off ^ (slot << 4)));
        s[t4] = mfma_bf16(ak, bq[ks], s[t4]);
      }
    // causal mask: key = split*256 + t*64 + (t4>>1)*32 + kg*8 + (t4&1)*4 + r
    const int kb0 = split * 256 + t * 64;
#pragma unroll
    for (int t4 = 0; t4 < 4; ++t4)
#pragma unroll
      for (int r = 0; r < 4; ++r) {
        int gkey = kb0 + ((t4 >> 1) << 5) + (kg << 3) + ((t4 & 1) << 2) + r;
        if (gkey > iq) s[t4][r] = -1e9f;
      }
    float mx = s[0][0];
#pragma unroll
    for (int t4 = 0; t4 < 4; ++t4)
#pragma unroll
      for (int r = 0; r < 4; ++r) mx = fmaxf(mx, s[t4][r]);
    mx = fmaxf(mx, __shfl_xor(mx, 16));
    mx = fmaxf(mx, __shfl_xor(mx, 32));
    float mnew = fmaxf(mrun, mx);
    float a = __expf(mrun - mnew);
    float sum = 0.f;
#pragma unroll
    for (int t4 = 0; t4 < 4; ++t4)
#pragma unroll
      for (int r = 0; r < 4; ++r) {
        float p = __expf(s[t4][r] - mnew);
        s[t4][r] = p; sum += p;
      }
    sum += __shfl_xor(sum, 16);
    sum += __shfl_xor(sum, 32);
    lrun = lrun * a + sum;
    mrun = mnew;
    float ar[4];
#pragma unroll
    for (int r = 0; r < 4; ++r) ar[r] = __shfl(a, kg * 4 + r);
#pragma unroll
    for (int ne = 0; ne < 4; ++ne)
#pragma unroll
      for (int r = 0; r < 4; ++r) oacc[ne][r] *= ar[r];
#pragma unroll
    for (int ks2 = 0; ks2 < 2; ++ks2) {
      u16x8_t pa;
#pragma unroll
      for (int j = 0; j < 4; ++j) {
        pa[j] = f2b(s[2 * ks2][j]);
        pa[4 + j] = f2b(s[2 * ks2 + 1][j]);
      }
#pragma unroll
      for (int ne = 0; ne < 4; ++ne) {
        int e = ne * 16 + lr;
        int off = (e << 7) + (ks2 << 6) + (kg << 4);
        u16x8_t bv = *(const u16x8_t*)((const char*)Vt[cur] + (off ^ ((e & 7) << 4)));
        oacc[ne] = mfma_bf16(pa, bv, oacc[ne]);
      }
    }
    __syncthreads();
  }

  if (wave < 3) {
    float* ob = Opart + (((size_t)(bh * 8 + split)) * 48 + qtile * 16) * 64;
#pragma unroll
    for (int ne = 0; ne < 4; ++ne)
#pragma unroll
      for (int r = 0; r < 4; ++r)
        ob[(size_t)(kg * 4 + r) * 64 + ne * 16 + lr] = oacc[ne][r];
    if (kg == 0) {
      size_t mb = (((size_t)(bh * 8 + split)) * 48 + qtile * 16 + lr) * 2;
      ml[mb + 0] = mrun;
      ml[mb + 1] = lrun;
    }
  }
}

// combine partials across 8 splits + scatter into ctxb
__global__ __launch_bounds__(64)
void probCombine_kernel(const float* __restrict__ Opart, const float* __restrict__ ml,
                        const int* __restrict__ Mtop, u16* __restrict__ ctxb) {
  int bh = blockIdx.x / NTOP, q = blockIdx.x % NTOP;
  int e = threadIdx.x;
  int b = bh >> 4, hh = bh & 15;
  float ms[8], ls[8];
  float mstar = -3.0e38f;
#pragma unroll
  for (int s = 0; s < 8; ++s) {
    size_t mb = (((size_t)(bh * 8 + s)) * 48 + q) * 2;
    ms[s] = ml[mb + 0];
    ls[s] = ml[mb + 1];
    mstar = fmaxf(mstar, ms[s]);
  }
  float lstar = 0.f, acc = 0.f;
#pragma unroll
  for (int s = 0; s < 8; ++s) {
    float w = __expf(ms[s] - mstar);
    lstar += w * ls[s];
    acc += w * Opart[(((size_t)(bh * 8 + s)) * 48 + q) * 64 + e];
  }
  int row = Mtop[bh * NTOP + q];
  ctxb[((size_t)b * SEQ + row) * DMODEL + hh * EHEAD + e] = f2b(acc / lstar);
}

// ---------------------------------------------------------------- scans
__global__ __launch_bounds__(64)
void scan1_kernel(const u16* __restrict__ v, float* __restrict__ ctx,
                  float* __restrict__ csum) {
  int bh = blockIdx.x, c = blockIdx.y;
  int b = bh >> 4, hh = bh & 15, e = threadIdx.x;
  size_t base = ((size_t)b * SEQ + c * 128) * DMODEL + hh * EHEAD + e;
  float run = 0.f;
  for (int i = 0; i < 128; ++i) {
    run += b2f(v[base + (size_t)i * DMODEL]);
    ctx[base + (size_t)i * DMODEL] = run;
  }
  csum[(bh * 16 + c) * 64 + e] = run;
}

__global__ __launch_bounds__(64)
void scan2_kernel(const float* __restrict__ csum, const float* __restrict__ ctxf,
                  u16* __restrict__ ctxb) {
  int bh = blockIdx.x, c = blockIdx.y;   // 0..15
  int b = bh >> 4, hh = bh & 15, e = threadIdx.x;
  float off = 0.f;
  for (int cc = 0; cc < c; ++cc) off += csum[(bh * 16 + cc) * 64 + e];
  size_t base = ((size_t)b * SEQ + c * 128) * DMODEL + hh * EHEAD + e;
  for (int i = 0; i < 128; ++i)
    ctxb[base + (size_t)i * DMODEL] = f2b(ctxf[base + (size_t)i * DMODEL] + off);
}

// ---------------------------------------------------------------- kv pack (cross)
__global__ __launch_bounds__(256)
void kvpack_kernel(const u16* __restrict__ kv, u16* __restrict__ kpack,
                   u16* __restrict__ vpack) {
  int bh = blockIdx.x, ch = blockIdx.y;
  int b = bh >> 4, hh = bh & 15;
  int tid = threadIdx.x;
  __shared__ u16 vt[64][80];
#pragma unroll
  for (int rep = 0; rep < 2; ++rep) {
    int u = rep * 256 + tid;
    int key = u >> 3, c = u & 7;
    u16x8_t d = *(const u16x8_t*)(kv + ((size_t)(b * SEQ + ch * 64 + key)) * 2048 + hh * 64 + c * 8);
    int slot = (key & 3) | (((key >> 3) & 1) << 2);
    *(u16x8_t*)(kpack + ((size_t)bh * SEQ + ch * 64 + key) * 64 + ((c ^ slot) * 8)) = d;
    u16x8_t dv = *(const u16x8_t*)(kv + ((size_t)(b * SEQ + ch * 64 + key)) * 2048 + 1024 + hh * 64 + c * 8);
    *(u16x8_t*)(&vt[key][c * 8]) = dv;
  }
  __syncthreads();
#pragma unroll
  for (int rep = 0; rep < 2; ++rep) {
    int u = rep * 256 + tid;
    int e = u >> 3, c = u & 7;
    int kb = (c ^ (e & 7)) * 8;
    u16x8_t d;
#pragma unroll
    for (int j = 0; j < 8; ++j) d[j] = vt[kb + j][e];
    *(u16x8_t*)(vpack + (((size_t)bh * 32 + ch) * 64 + e) * 64 + c * 8) = d;
  }
}

// ---------------------------------------------------------------- cross attn
__global__ __launch_bounds__(512)
void cross_attn_kernel(const float* __restrict__ q2, const u16* __restrict__ kpack,
                       const u16* __restrict__ vpack, u16* __restrict__ cab) {
  const int bh = blockIdx.x, b = bh >> 4, hh = bh & 15;
  const int qt0 = blockIdx.y * 128;
  const int tid = threadIdx.x, wave = tid >> 6, lane = tid & 63;
  const int lr = lane & 15, kg = lane >> 4;
  const int wv = __builtin_amdgcn_readfirstlane(wave);
  __shared__ __align__(16) u16 Qs[128 * 64];
  __shared__ __align__(16) u16 Kt[2][64 * 64];
  __shared__ __align__(16) u16 Vt[2][64 * 64];

#pragma unroll
  for (int i = 0; i < 4; ++i) {
    int j = tid + 512 * i;
    int row = j >> 4, c4 = j & 15;
    f32x4_t v4 = *(const f32x4_t*)(q2 + ((size_t)b * SEQ + qt0 + row) * DMODEL + hh * EHEAD + c4 * 4);
    u16x4_t b4;
    b4[0] = f2b(v4[0] * 0.125f); b4[1] = f2b(v4[1] * 0.125f);
    b4[2] = f2b(v4[2] * 0.125f); b4[3] = f2b(v4[3] * 0.125f);
    *(u16x4_t*)((char*)Qs + ((row * 128 + c4 * 8) ^ ((row & 7) << 4))) = b4;
  }

  const char* kgl = (const char*)kpack + (size_t)bh * SEQ * 128;
  const char* vgl = (const char*)vpack + (size_t)bh * 32 * 8192;
  auto STAGE = [&](int buf, int t) {
    GLD16(kgl + (size_t)t * 8192 + wv * 1024 + lane * 16, (char*)Kt[buf] + wv * 1024);
    GLD16(vgl + (size_t)t * 8192 + wv * 1024 + lane * 16, (char*)Vt[buf] + wv * 1024);
  };

  STAGE(0, 0);
  __syncthreads();

  u16x8_t bq[2];
  {
    int qrow = wave * 16 + lr;
#pragma unroll
    for (int ks = 0; ks < 2; ++ks)
      bq[ks] = *(u16x8_t*)((char*)Qs + ((qrow * 128 + ks * 64 + kg * 16) ^ ((qrow & 7) << 4)));
  }

  f32x4_t oacc[4];
#pragma unroll
  for (int i = 0; i < 4; ++i) oacc[i] = f32x4_t{0.f, 0.f, 0.f, 0.f};
  float mrun = -3e38f, lrun = 0.f;

  for (int t = 0; t < 32; ++t) {
    const int cur = t & 1;
    if (t + 1 < 32) STAGE(cur ^ 1, t + 1);
    f32x4_t s[4];
#pragma unroll
    for (int i = 0; i < 4; ++i) s[i] = f32x4_t{0.f, 0.f, 0.f, 0.f};
#pragma unroll
    for (int ks = 0; ks < 2; ++ks)
#pragma unroll
      for (int t4 = 0; t4 < 4; ++t4) {
        int arow = ((t4 >> 1) << 5) + ((lr >> 2) << 3) + ((t4 & 1) << 2) + (lr & 3);
        int slot = (arow & 3) | (((arow >> 3) & 1) << 2);
        int off = (arow << 7) + (ks << 6) + (kg << 4);
        u16x8_t ak = *(const u16x8_t*)((const char*)Kt[cur] + (off ^ (slot << 4)));
        s[t4] = mfma_bf16(ak, bq[ks], s[t4]);
      }
    float mx = s[0][0];
#pragma unroll
    for (int t4 = 0; t4 < 4; ++t4)
#pragma unroll
      for (int r = 0; r < 4; ++r) mx = fmaxf(mx, s[t4][r]);
    mx = fmaxf(mx, __shfl_xor(mx, 16));
    mx = fmaxf(mx, __shfl_xor(mx, 32));
    float mnew = fmaxf(mrun, mx);
    float a = __expf(mrun - mnew);
    float sum = 0.f;
#pragma unroll
    for (int t4 = 0; t4 < 4; ++t4)
#pragma unroll
      for (int r = 0; r < 4; ++r) {
        float p = __expf(s[t4][r] - mnew);
        s[t4][r] = p; sum += p;
      }
    sum += __shfl_xor(sum, 16);
    sum += __shfl_xor(sum, 32);
    lrun = lrun * a + sum;
    mrun = mnew;
    float ar[4];
#pragma unroll
    for (int r = 0; r < 4; ++r) ar[r] = __shfl(a, kg * 4 + r);
#pragma unroll
    for (int ne = 0; ne < 4; ++ne)
#pragma unroll
      for (int r = 0; r < 4; ++r) oacc[ne][r] *= ar[r];
#pragma unroll
    for (int ks2 = 0; ks2 < 2; ++ks2) {
      u16x8_t pa;
#pragma unroll
      for (int j = 0; j < 4; ++j) {
        pa[j] = f2b(s[2 * ks2][j]);
        pa[4 + j] = f2b(s[2 * ks2 + 1][j]);
      }
#pragma unroll
      for (int ne = 0; ne < 4; ++ne) {
        int e = ne * 16 + lr;
        int off = (e << 7) + (ks2 << 6) + (kg << 4);
        u16x8_t bv = *(const u16x8_t*)((const char*)Vt[cur] + (off ^ ((e & 7) << 4)));
        oacc[ne] = mfma_bf16(pa, bv, oacc[ne]);
      }
    }
    __syncthreads();
  }

  float lr4[4];
#pragma unroll
  for (int r = 0; r < 4; ++r) lr4[r] = __shfl(lrun, kg * 4 + r);
#pragma unroll
  for (int ne = 0; ne < 4; ++ne)
#pragma unroll
    for (int r = 0; r < 4; ++r) {
      int row = qt0 + wave * 16 + kg * 4 + r;
      int col = hh * EHEAD + ne * 16 + lr;
      cab[((size_t)b * SEQ + row) * DMODEL + col] = f2b(oacc[ne][r] / lr4[r]);
    }
}

// ---------------------------------------------------------------- layernorm
__global__ __launch_bounds__(256)
void ln_kernel(const float* __restrict__ x, const float* __restrict__ r,
               const float* __restrict__ g, const float* __restrict__ be,
               float* __restrict__ outf, u16* __restrict__ outb) {
  int row = blockIdx.x, tid = threadIdx.x;
  size_t base = (size_t)row * DMODEL;
  float v[4];
  float s = 0.f, sq = 0.f;
#pragma unroll
  for (int i = 0; i < 4; ++i) {
    int c = tid + i * 256;
    float t = x[base + c] + r[base + c];
    v[i] = t; s += t; sq += t * t;
  }
  __shared__ float rs[256], rq[256];
  rs[tid] = s; rq[tid] = sq;
  __syncthreads();
  for (int st = 128; st > 0; st >>= 1) {
    if (tid < st) { rs[tid] += rs[tid + st]; rq[tid] += rq[tid + st]; }
    __syncthreads();
  }
  float mean = rs[0] * (1.f / DMODEL);
  float var = rq[0] * (1.f / DMODEL) - mean * mean;
  float rstd = rsqrtf(var + 1e-5f);
#pragma unroll
  for (int i = 0; i < 4; ++i) {
    int c = tid + i * 256;
    float o = (v[i] - mean) * rstd * g[c] + be[c];
    if (outf) outf[base + c] = o;
    if (outb) outb[base + c] = f2b(o);
  }
}

// ---------------------------------------------------------------- host side
static inline void gemm(const u16* A, const u16* Bt, const float* bias, float* Cf,
                        u16* Cb, int M, int N, int K, int relu, hipStream_t s,
                        int big = 0) {
  if (big)
    gemm_bf<4><<<dim3(M / 128, N / 128), 256, 0, s>>>(A, Bt, bias, Cf, Cb, M, N, K, relu);
  else
    gemm_bf<2><<<dim3(M / 128, N / 64), 256, 0, s>>>(A, Bt, bias, Cf, Cb, M, N, K, relu);
}
static inline void gemm4(const u16* Ah, const u16* Al, const u16* Bh, const u16* Bl,
                         const float* bias, float* Cf, int M, int N, int K, hipStream_t s) {
  gemm4_bf<4><<<dim3(M / 128, N / 128), 256, 0, s>>>(Ah, Al, Bh, Bl, bias, Cf, M, N, K);
}

extern "C" void kernel_launch(void* const* d_in, const int* in_sizes, int n_in,
                              void* d_out, int out_size, void* d_ws, size_t ws_size,
                              hipStream_t stream) {
  const float* x   = (const float*)d_in[0];
  const float* mem = (const float*)d_in[1];
  const float* sWq = (const float*)d_in[2];  const float* sbq = (const float*)d_in[3];
  const float* sWk = (const float*)d_in[4];  const float* sbk = (const float*)d_in[5];
  const float* sWv = (const float*)d_in[6];  const float* sbv = (const float*)d_in[7];
  const float* sWo = (const float*)d_in[8];  const float* sbo = (const float*)d_in[9];
  const float* cWq = (const float*)d_in[10]; const float* cbq = (const float*)d_in[11];
  const float* cWk = (const float*)d_in[12]; const float* cbk = (const float*)d_in[13];
  const float* cWv = (const float*)d_in[14]; const float* cbv = (const float*)d_in[15];
  const float* cWo = (const float*)d_in[16]; const float* cbo = (const float*)d_in[17];
  const float* W1  = (const float*)d_in[18]; const float* b1  = (const float*)d_in[19];
  const float* W2  = (const float*)d_in[20]; const float* b2  = (const float*)d_in[21];
  const float* g1  = (const float*)d_in[22]; const float* be1 = (const float*)d_in[23];
  const float* g2  = (const float*)d_in[24]; const float* be2 = (const float*)d_in[25];
  const float* g3  = (const float*)d_in[26]; const float* be3 = (const float*)d_in[27];
  float* outp = (float*)d_out;
  char* ws = (char*)d_ws;
  const size_t MB = 1ull << 20;

  int*   idx    = (int*)(ws);
  float* Mv     = (float*)(ws + 0x60000);
  int*   Mtop   = (int*)(ws + 0xA0000);
  float* csum   = (float*)(ws + 0x100000);
  float* biasqk = (float*)(ws + 0x120000);
  float* cbkv   = (float*)(ws + 0x122000);

  u16* WqkhT = (u16*)(ws + 2 * MB);    // [2048][1024]
  u16* WqklT = (u16*)(ws + 6 * MB);
  u16* sWvT  = (u16*)(ws + 10 * MB);
  u16* sWoT  = (u16*)(ws + 12 * MB);
  u16* cWqT  = (u16*)(ws + 14 * MB);
  u16* cWkvT = (u16*)(ws + 16 * MB);   // [2048][1024]
  u16* cWoT  = (u16*)(ws + 20 * MB);
  u16* W1T   = (u16*)(ws + 22 * MB);
  u16* W2T   = (u16*)(ws + 30 * MB);

  u16* xh   = (u16*)(ws + 38 * MB);
  u16* xl   = (u16*)(ws + 46 * MB);
  u16* memb = (u16*)(ws + 54 * MB);

  float* qk    = (float*)(ws + 62 * MB);   // [4096][2048] f32, 32MB [62,94)
  u16*   vbf   = (u16*)(ws + 94 * MB);     // 8MB [94,102)
  u16*   kpks  = (u16*)(ws + 102 * MB);    // 8MB [102,110) self K packed
  u16*   vpks  = (u16*)(ws + 46 * MB);     // 8MB (over xl, dead after gemm4)
  float* Opart = (float*)(ws + 110 * MB);  // 3MB [110,113)
  float* mlbuf = (float*)(ws + 113 * MB);  // 98KB
  float* ctxf  = (float*)(ws + 62 * MB);   // reuse qk (dead after probAttn)
  u16*   ctxb  = (u16*)(ws + 78 * MB);
  float* sa    = (float*)(ws + 94 * MB);   // reuse vbf+kpks
  float* x1    = (float*)(ws + 62 * MB);
  u16*   x1b   = (u16*)(ws + 78 * MB);
  float* q2    = (float*)(ws + 94 * MB);
  u16*   kv2b  = (u16*)(ws + 38 * MB);     // [4096][2048] bf16, 16MB [38,54)
  u16*   kpk   = (u16*)(ws + 54 * MB);     // 8MB (over memb, dead)
  u16*   vpk   = (u16*)(ws + 110 * MB);    // 8MB (over Opart, dead)
  u16*   cab   = (u16*)(ws + 38 * MB);
  float* ca2   = (float*)(ws + 94 * MB);
  float* x2    = (float*)(ws + 38 * MB);
  u16*   x2b   = (u16*)(ws + 54 * MB);
  u16*   hbb   = (u16*)(ws + 62 * MB);     // 32MB [62,94)
  float* yb    = (float*)(ws + 94 * MB);

  const int MROWS = BATCH * SEQ;  // 4096

  // ---- prep ----
  idx_kernel<<<320, 256, 0, stream>>>(idx);
  wsplit_kernel<<<dim3(16, 16), 256, 0, stream>>>(sWq, WqkhT, WqklT, 1024, 1024);
  wsplit_kernel<<<dim3(16, 16), 256, 0, stream>>>(sWk, WqkhT + 1024 * 1024, WqklT + 1024 * 1024, 1024, 1024);
  wt_kernel<<<dim3(16, 16), 256, 0, stream>>>(sWv, sWvT, 1024, 1024);
  wt_kernel<<<dim3(16, 16), 256, 0, stream>>>(sWo, sWoT, 1024, 1024);
  wt_kernel<<<dim3(16, 16), 256, 0, stream>>>(cWq, cWqT, 1024, 1024);
  wt_kernel<<<dim3(16, 16), 256, 0, stream>>>(cWk, cWkvT, 1024, 1024);
  wt_kernel<<<dim3(16, 16), 256, 0, stream>>>(cWv, cWkvT + 1024 * 1024, 1024, 1024);
  wt_kernel<<<dim3(16, 16), 256, 0, stream>>>(cWo, cWoT, 1024, 1024);
  wt_kernel<<<dim3(64, 16), 256, 0, stream>>>(W1, W1T, 1024, 4096);
  wt_kernel<<<dim3(16, 64), 256, 0, stream>>>(W2, W2T, 4096, 1024);
  split_kernel<<<4096, 256, 0, stream>>>(x, xh, xl);
  conv_kernel<<<4096, 256, 0, stream>>>(mem, memb);
  pack2_kernel<<<8, 256, 0, stream>>>(sbq, sbk, biasqk, 1024);
  pack2_kernel<<<8, 256, 0, stream>>>(cbk, cbv, cbkv, 1024);

  // ---- self attention (ProbSparse) ----
  gemm4(xh, xl, WqkhT, WqklT, biasqk, qk, MROWS, 2048, DMODEL, stream);
  gemm(xh, sWvT, sbv, nullptr, vbf, MROWS, DMODEL, DMODEL, 0, stream);
  probM_kernel<<<BATCH * SEQ / 4, 256, 0, stream>>>(qk, idx, Mv);
  topk_kernel<<<BATCH * NHEADS, 256, 0, stream>>>(Mv, Mtop);
  kvpack_self<<<dim3(BATCH * NHEADS, SEQ / 64), 256, 0, stream>>>(qk, vbf, kpks, vpks);
  probAttn_kernel<<<dim3(BATCH * NHEADS, 8), 256, 0, stream>>>(qk, kpks, vpks, Mtop, Opart, mlbuf);
  scan1_kernel<<<dim3(BATCH * NHEADS, 16), 64, 0, stream>>>(vbf, ctxf, csum);
  scan2_kernel<<<dim3(BATCH * NHEADS, 16), 64, 0, stream>>>(csum, ctxf, ctxb);
  probCombine_kernel<<<BATCH * NHEADS * NTOP, 64, 0, stream>>>(Opart, mlbuf, Mtop, ctxb);
  gemm(ctxb, sWoT, sbo, sa, nullptr, MROWS, DMODEL, DMODEL, 0, stream);
  ln_kernel<<<MROWS, 256, 0, stream>>>(x, sa, g1, be1, x1, x1b);

  // ---- cross attention ----
  gemm(x1b, cWqT, cbq, q2, nullptr, MROWS, DMODEL, DMODEL, 0, stream);
  gemm(memb, cWkvT, cbkv, nullptr, kv2b, MROWS, 2048, DMODEL, 0, stream, 1);
  kvpack_kernel<<<dim3(BATCH * NHEADS, SEQ / 64), 256, 0, stream>>>(kv2b, kpk, vpk);
  cross_attn_kernel<<<dim3(BATCH * NHEADS, SEQ / 128), 512, 0, stream>>>(q2, kpk, vpk, cab);
  gemm(cab, cWoT, cbo, ca2, nullptr, MROWS, DMODEL, DMODEL, 0, stream);
  ln_kernel<<<MROWS, 256, 0, stream>>>(x1, ca2, g2, be2, x2, x2b);

  // ---- FFN ----
  gemm(x2b, W1T, b1, nullptr, hbb, MROWS, DFF, DMODEL, 1, stream, 1);
  gemm(hbb, W2T, b2, yb, nullptr, MROWS, DMODEL, DFF, 0, stream);
  ln_kernel<<<MROWS, 256, 0, stream>>>(x2, yb, g3, be3, outp, nullptr);
}

// Round 7
// 551.461 us; speedup vs baseline: 2.1661x; 1.0639x over previous
//
#include <hip/hip_runtime.h>

static constexpr int BATCH  = 2;
static constexpr int SEQ    = 2048;
static constexpr int DMODEL = 1024;
static constexpr int NHEADS = 16;
static constexpr int EHEAD  = 64;
static constexpr int DFF    = 4096;
static constexpr int NTOP   = 40;

typedef unsigned short u16;
typedef __bf16 bf16x8_t __attribute__((ext_vector_type(8)));
typedef u16    u16x8_t  __attribute__((ext_vector_type(8)));
typedef u16    u16x4_t  __attribute__((ext_vector_type(4)));
typedef float  f32x4_t  __attribute__((ext_vector_type(4)));

static __device__ __forceinline__ u16 f2b(float f) {
  unsigned u = __builtin_bit_cast(unsigned, f);
  unsigned r = u + 0x7FFFu + ((u >> 16) & 1u);
  return (u16)(r >> 16);
}
static __device__ __forceinline__ float b2f(u16 h) {
  unsigned u = ((unsigned)h) << 16;
  return __builtin_bit_cast(float, u);
}
static __device__ __forceinline__ f32x4_t mfma_bf16(u16x8_t a, u16x8_t b, f32x4_t c) {
  return __builtin_amdgcn_mfma_f32_16x16x32_bf16(
      __builtin_bit_cast(bf16x8_t, a), __builtin_bit_cast(bf16x8_t, b), c, 0, 0, 0);
}

#define GLD16(gsrc, ldst)                                                        \
  __builtin_amdgcn_global_load_lds(                                             \
      (const __attribute__((address_space(1))) void*)(gsrc),                    \
      (__attribute__((address_space(3))) void*)(ldst), 16, 0, 0)

// ---------------------------------------------------------------- threefry
static __device__ __forceinline__ void tf2x32(unsigned k0, unsigned k1,
                                              unsigned x0, unsigned x1,
                                              unsigned& o0, unsigned& o1) {
  unsigned ks2 = 0x1BD11BDAu ^ k0 ^ k1;
  x0 += k0; x1 += k1;
#define TFR(r) { x0 += x1; x1 = (x1 << r) | (x1 >> (32 - r)); x1 ^= x0; }
  TFR(13) TFR(15) TFR(26) TFR(6)  x0 += k1;  x1 += ks2 + 1u;
  TFR(17) TFR(29) TFR(16) TFR(24) x0 += ks2; x1 += k0 + 2u;
  TFR(13) TFR(15) TFR(26) TFR(6)  x0 += k0;  x1 += k1 + 3u;
  TFR(17) TFR(29) TFR(16) TFR(24) x0 += k1;  x1 += ks2 + 4u;
  TFR(13) TFR(15) TFR(26) TFR(6)  x0 += ks2; x1 += k0 + 5u;
#undef TFR
  o0 = x0; o1 = x1;
}

__global__ __launch_bounds__(256) void idx_kernel(int* __restrict__ idx) {
  int i = blockIdx.x * 256 + threadIdx.x;           // 0..81919, grid 320
  unsigned c0, c1, o0, o1;
  tf2x32(0u, 42u, 0u, 1u, c0, c1);                  // k2 = second split child
  tf2x32(c0, c1, 0u, (unsigned)i, o0, o1);
  idx[i] = (int)((o0 ^ o1) & 2047u);
}

// ---------------------------------------------------------------- prep
__global__ __launch_bounds__(256)
void wt_kernel(const float* __restrict__ in, u16* __restrict__ outp, int K, int N) {
  __shared__ float t[64][65];
  int k0 = blockIdx.y * 64, n0 = blockIdx.x * 64;
  int c = threadIdx.x & 63, r4 = threadIdx.x >> 6;
#pragma unroll
  for (int i = 0; i < 16; ++i) {
    int r = r4 * 16 + i;
    t[r][c] = in[(size_t)(k0 + r) * N + n0 + c];
  }
  __syncthreads();
#pragma unroll
  for (int i = 0; i < 16; ++i) {
    int r = r4 * 16 + i;
    outp[(size_t)(n0 + r) * K + k0 + c] = f2b(t[c][r]);
  }
}

struct Ptr6 { const float* s[6]; u16* d[6]; };
// six 1024x1024 transposes in one launch, grid (16,16,6)
__global__ __launch_bounds__(256)
void wt6_kernel(Ptr6 p) {
  const float* in = p.s[blockIdx.z];
  u16* outp = p.d[blockIdx.z];
  __shared__ float t[64][65];
  int k0 = blockIdx.y * 64, n0 = blockIdx.x * 64;
  int c = threadIdx.x & 63, r4 = threadIdx.x >> 6;
#pragma unroll
  for (int i = 0; i < 16; ++i) {
    int r = r4 * 16 + i;
    t[r][c] = in[(size_t)(k0 + r) * 1024 + n0 + c];
  }
  __syncthreads();
#pragma unroll
  for (int i = 0; i < 16; ++i) {
    int r = r4 * 16 + i;
    outp[(size_t)(n0 + r) * 1024 + k0 + c] = f2b(t[c][r]);
  }
}

struct Ptr2 { const float* s[2]; u16* dh[2]; u16* dl[2]; };
// two 1024x1024 Dekker-split transposes, grid (16,16,2)
__global__ __launch_bounds__(256)
void wsplit2_kernel(Ptr2 p) {
  const float* in = p.s[blockIdx.z];
  u16* oh = p.dh[blockIdx.z];
  u16* ol = p.dl[blockIdx.z];
  __shared__ float t[64][65];
  int k0 = blockIdx.y * 64, n0 = blockIdx.x * 64;
  int c = threadIdx.x & 63, r4 = threadIdx.x >> 6;
#pragma unroll
  for (int i = 0; i < 16; ++i) {
    int r = r4 * 16 + i;
    t[r][c] = in[(size_t)(k0 + r) * 1024 + n0 + c];
  }
  __syncthreads();
#pragma unroll
  for (int i = 0; i < 16; ++i) {
    int r = r4 * 16 + i;
    float f = t[c][r];
    u16 h = f2b(f);
    oh[(size_t)(n0 + r) * 1024 + k0 + c] = h;
    ol[(size_t)(n0 + r) * 1024 + k0 + c] = f2b(f - b2f(h));
  }
}

// x -> (xh,xl) split and mem -> memb conv in one launch, grid 8192
__global__ __launch_bounds__(256)
void prep_inputs(const float* __restrict__ x, u16* __restrict__ xh,
                 u16* __restrict__ xl, const float* __restrict__ mem,
                 u16* __restrict__ memb) {
  int blk = blockIdx.x;
  if (blk < 4096) {
    int i = blk * 256 + threadIdx.x;
    f32x4_t v = *(const f32x4_t*)(x + (size_t)i * 4);
    u16x4_t h, l;
#pragma unroll
    for (int d = 0; d < 4; ++d) {
      u16 hh = f2b(v[d]); h[d] = hh; l[d] = f2b(v[d] - b2f(hh));
    }
    *(u16x4_t*)(xh + (size_t)i * 4) = h;
    *(u16x4_t*)(xl + (size_t)i * 4) = l;
  } else {
    int i = (blk - 4096) * 256 + threadIdx.x;
    f32x4_t v = *(const f32x4_t*)(mem + (size_t)i * 4);
    u16x4_t o;
    o[0] = f2b(v[0]); o[1] = f2b(v[1]); o[2] = f2b(v[2]); o[3] = f2b(v[3]);
    *(u16x4_t*)(memb + (size_t)i * 4) = o;
  }
}

__global__ __launch_bounds__(256)
void pack4_kernel(const float* __restrict__ a0, const float* __restrict__ a1,
                  float* __restrict__ o0, const float* __restrict__ b0,
                  const float* __restrict__ b1, float* __restrict__ o1) {
  int i = blockIdx.x * 256 + threadIdx.x;   // grid 16 -> 4096
  if (i < 1024) o0[i] = a0[i];
  else if (i < 2048) o0[i] = a1[i - 1024];
  else if (i < 3072) o1[i - 2048] = b0[i - 2048];
  else o1[i - 2048] = b1[i - 3072];
}

// ---------------------------------------------------------------- bf16 GEMM
template<int NF>
__global__ __launch_bounds__(256)
void gemm_bf(const u16* __restrict__ A, const u16* __restrict__ Bt,
             const float* __restrict__ bias, float* __restrict__ Cf,
             u16* __restrict__ Cb, int M, int N, int K, int relu) {
  __shared__ __align__(16) u16 sA[2][128 * 32];
  __shared__ __align__(16) u16 sB[2][NF * 32 * 32];
  const int tid = threadIdx.x;
  const int wave = tid >> 6, lane = tid & 63;
  const int m0 = blockIdx.x * 128, n0 = blockIdx.y * (NF * 32);
  const int wr = (wave >> 1) * 64, wc = (wave & 1) * (NF * 16);
  const int lr = lane & 15, kg = lane >> 4;
  const int wv = __builtin_amdgcn_readfirstlane(wave);

  int rowA[2], c8A[2];
#pragma unroll
  for (int rep = 0; rep < 2; ++rep) {
    int P = (rep * 256 + tid) << 4;
    int L = P ^ (((P >> 7) & 3) << 4);
    rowA[rep] = L >> 6; c8A[rep] = (L >> 4) & 3;
  }
  int rowB[NF / 2], c8B[NF / 2];
#pragma unroll
  for (int rep = 0; rep < NF / 2; ++rep) {
    int P = (rep * 256 + tid) << 4;
    int L = P ^ (((P >> 7) & 3) << 4);
    rowB[rep] = L >> 6; c8B[rep] = (L >> 4) & 3;
  }

  f32x4_t acc[4][NF];
#pragma unroll
  for (int i = 0; i < 4; ++i)
#pragma unroll
    for (int j = 0; j < NF; ++j) acc[i][j] = f32x4_t{0.f, 0.f, 0.f, 0.f};

  auto STAGE = [&](int buf, int k0) {
#pragma unroll
    for (int rep = 0; rep < 2; ++rep)
      GLD16(A + (size_t)(m0 + rowA[rep]) * K + k0 + c8A[rep] * 8,
            &sA[buf][(rep * 256 + wv * 64) * 8]);
#pragma unroll
    for (int rep = 0; rep < NF / 2; ++rep)
      GLD16(Bt + (size_t)(n0 + rowB[rep]) * K + k0 + c8B[rep] * 8,
            &sB[buf][(rep * 256 + wv * 64) * 8]);
  };

  const int nk = K >> 5;
  STAGE(0, 0);
  __syncthreads();
  for (int t = 0; t < nk; ++t) {
    const int cur = t & 1;
    if (t + 1 < nk) STAGE(cur ^ 1, (t + 1) << 5);
    u16x8_t a8[4], b8[NF];
#pragma unroll
    for (int mi = 0; mi < 4; ++mi) {
      int La = (wr + mi * 16 + lr) * 64 + kg * 16;
      a8[mi] = *(const u16x8_t*)((const char*)sA[cur] + (La ^ (((La >> 7) & 3) << 4)));
    }
#pragma unroll
    for (int ni = 0; ni < NF; ++ni) {
      int Lb = (wc + ni * 16 + lr) * 64 + kg * 16;
      b8[ni] = *(const u16x8_t*)((const char*)sB[cur] + (Lb ^ (((Lb >> 7) & 3) << 4)));
    }
#pragma unroll
    for (int mi = 0; mi < 4; ++mi)
#pragma unroll
      for (int ni = 0; ni < NF; ++ni)
        acc[mi][ni] = mfma_bf16(a8[mi], b8[ni], acc[mi][ni]);
    __syncthreads();
  }
#pragma unroll
  for (int ni = 0; ni < NF; ++ni) {
    int col = n0 + wc + ni * 16 + lr;
    float bc = bias[col];
#pragma unroll
    for (int mi = 0; mi < 4; ++mi)
#pragma unroll
      for (int r = 0; r < 4; ++r) {
        int row = m0 + wr + mi * 16 + kg * 4 + r;
        float vv = acc[mi][ni][r] + bc;
        if (relu) vv = fmaxf(vv, 0.f);
        if (Cf) Cf[(size_t)row * N + col] = vv;
        if (Cb) Cb[(size_t)row * N + col] = f2b(vv);
      }
  }
}

// 3-term split GEMM (f32-equivalent: hi*hi + hi*lo + lo*hi)
template<int NF>
__global__ __launch_bounds__(256)
void gemm4_bf(const u16* __restrict__ Ah, const u16* __restrict__ Al,
              const u16* __restrict__ Bh, const u16* __restrict__ Bl,
              const float* __restrict__ bias, float* __restrict__ Cf,
              int M, int N, int K) {
  __shared__ __align__(16) u16 sAh[2][128 * 32];
  __shared__ __align__(16) u16 sAl[2][128 * 32];
  __shared__ __align__(16) u16 sBh[2][NF * 32 * 32];
  __shared__ __align__(16) u16 sBl[2][NF * 32 * 32];
  const int tid = threadIdx.x;
  const int wave = tid >> 6, lane = tid & 63;
  const int m0 = blockIdx.x * 128, n0 = blockIdx.y * (NF * 32);
  const int wr = (wave >> 1) * 64, wc = (wave & 1) * (NF * 16);
  const int lr = lane & 15, kg = lane >> 4;
  const int wv = __builtin_amdgcn_readfirstlane(wave);

  int rowA[2], c8A[2];
#pragma unroll
  for (int rep = 0; rep < 2; ++rep) {
    int P = (rep * 256 + tid) << 4;
    int L = P ^ (((P >> 7) & 3) << 4);
    rowA[rep] = L >> 6; c8A[rep] = (L >> 4) & 3;
  }
  int rowB[NF / 2], c8B[NF / 2];
#pragma unroll
  for (int rep = 0; rep < NF / 2; ++rep) {
    int P = (rep * 256 + tid) << 4;
    int L = P ^ (((P >> 7) & 3) << 4);
    rowB[rep] = L >> 6; c8B[rep] = (L >> 4) & 3;
  }

  f32x4_t acc[4][NF];
#pragma unroll
  for (int i = 0; i < 4; ++i)
#pragma unroll
    for (int j = 0; j < NF; ++j) acc[i][j] = f32x4_t{0.f, 0.f, 0.f, 0.f};

  auto STAGE = [&](int buf, int k0) {
#pragma unroll
    for (int rep = 0; rep < 2; ++rep) {
      GLD16(Ah + (size_t)(m0 + rowA[rep]) * K + k0 + c8A[rep] * 8,
            &sAh[buf][(rep * 256 + wv * 64) * 8]);
      GLD16(Al + (size_t)(m0 + rowA[rep]) * K + k0 + c8A[rep] * 8,
            &sAl[buf][(rep * 256 + wv * 64) * 8]);
    }
#pragma unroll
    for (int rep = 0; rep < NF / 2; ++rep) {
      GLD16(Bh + (size_t)(n0 + rowB[rep]) * K + k0 + c8B[rep] * 8,
            &sBh[buf][(rep * 256 + wv * 64) * 8]);
      GLD16(Bl + (size_t)(n0 + rowB[rep]) * K + k0 + c8B[rep] * 8,
            &sBl[buf][(rep * 256 + wv * 64) * 8]);
    }
  };

  const int nk = K >> 5;
  STAGE(0, 0);
  __syncthreads();
  for (int t = 0; t < nk; ++t) {
    const int cur = t & 1;
    if (t + 1 < nk) STAGE(cur ^ 1, (t + 1) << 5);
    u16x8_t ah[4], al[4], bh[NF], bl[NF];
#pragma unroll
    for (int mi = 0; mi < 4; ++mi) {
      int La = (wr + mi * 16 + lr) * 64 + kg * 16;
      int off = La ^ (((La >> 7) & 3) << 4);
      ah[mi] = *(const u16x8_t*)((const char*)sAh[cur] + off);
      al[mi] = *(const u16x8_t*)((const char*)sAl[cur] + off);
    }
#pragma unroll
    for (int ni = 0; ni < NF; ++ni) {
      int Lb = (wc + ni * 16 + lr) * 64 + kg * 16;
      int off = Lb ^ (((Lb >> 7) & 3) << 4);
      bh[ni] = *(const u16x8_t*)((const char*)sBh[cur] + off);
      bl[ni] = *(const u16x8_t*)((const char*)sBl[cur] + off);
    }
#pragma unroll
    for (int mi = 0; mi < 4; ++mi)
#pragma unroll
      for (int ni = 0; ni < NF; ++ni) {
        acc[mi][ni] = mfma_bf16(ah[mi], bh[ni], acc[mi][ni]);
        acc[mi][ni] = mfma_bf16(ah[mi], bl[ni], acc[mi][ni]);
        acc[mi][ni] = mfma_bf16(al[mi], bh[ni], acc[mi][ni]);
      }
    __syncthreads();
  }
#pragma unroll
  for (int ni = 0; ni < NF; ++ni) {
    int col = n0 + wc + ni * 16 + lr;
    float bc = bias[col];
#pragma unroll
    for (int mi = 0; mi < 4; ++mi)
#pragma unroll
      for (int r = 0; r < 4; ++r) {
        int row = m0 + wr + mi * 16 + kg * 4 + r;
        Cf[(size_t)row * N + col] = acc[mi][ni][r] + bc;
      }
  }
}

// ---------------------------------------------------------------- ProbSparse
// One wave per (b,l), all 16 heads, XCD-pinned per batch. 4 key-range passes
// (512 keys = 2MB f32 per pass) so each pass's gather is L2-resident; q stays
// in registers across passes; max/sum accumulation is order-independent.
__global__ __launch_bounds__(256)
void probM_kernel(const float* __restrict__ qk, const int* __restrict__ idx,
                  float* __restrict__ Mv) {
  int blk = blockIdx.x;                        // 0..1023
  int xcd = blk & 7, j = blk >> 3;             // j: 0..127
  int b = xcd >> 2;
  int part = (xcd & 3) * 128 + j;              // 0..511
  int l = part * 4 + (threadIdx.x >> 6);
  int lane = threadIdx.x & 63;
  const float* qrow = qk + ((size_t)b * SEQ + l) * 2048 + lane * 16;
  f32x4_t qv0 = *(const f32x4_t*)(qrow);
  f32x4_t qv1 = *(const f32x4_t*)(qrow + 4);
  f32x4_t qv2 = *(const f32x4_t*)(qrow + 8);
  f32x4_t qv3 = *(const f32x4_t*)(qrow + 12);
  const int* ip = idx + l * NTOP;
  const float* kbase = qk + (size_t)b * SEQ * 2048 + 1024 + lane * 16;
  float mmax = -3.0e38f, msum = 0.f;
  for (int pass = 0; pass < 4; ++pass) {
    int lo = pass << 9;
#pragma unroll 4
    for (int u = 0; u < NTOP; ++u) {
      int ki = ip[u];
      if ((unsigned)(ki - lo) < 512u) {        // wave-uniform branch
        const float* kr = kbase + (size_t)ki * 2048;
        f32x4_t k0 = *(const f32x4_t*)(kr);
        f32x4_t k1 = *(const f32x4_t*)(kr + 4);
        f32x4_t k2 = *(const f32x4_t*)(kr + 8);
        f32x4_t k3 = *(const f32x4_t*)(kr + 12);
        float p = qv0[0] * k0[0] + qv0[1] * k0[1] + qv0[2] * k0[2] + qv0[3] * k0[3]
                + qv1[0] * k1[0] + qv1[1] * k1[1] + qv1[2] * k1[2] + qv1[3] * k1[3]
                + qv2[0] * k2[0] + qv2[1] * k2[1] + qv2[2] * k2[2] + qv2[3] * k2[3]
                + qv3[0] * k3[0] + qv3[1] * k3[1] + qv3[2] * k3[2] + qv3[3] * k3[3];
        p += __shfl_xor(p, 1);
        p += __shfl_xor(p, 2);
        mmax = fmaxf(mmax, p);
        msum += p;
      }
    }
  }
  if ((lane & 3) == 0) {
    int hh = lane >> 2;
    Mv[((size_t)b * NHEADS + hh) * SEQ + l] = mmax - msum * (1.f / 2048.f);
  }
}

// register-resident iterative top-40 (statically-indexed invalidation)
__global__ __launch_bounds__(256)
void topk_kernel(const float* __restrict__ Mv, int* __restrict__ Mtop) {
  int bh = blockIdx.x;
  int tid = threadIdx.x;
  int lane = tid & 63, wv = tid >> 6;
  float v8[8];
#pragma unroll
  for (int j = 0; j < 8; ++j) v8[j] = Mv[bh * 2048 + j * 256 + tid];
  __shared__ float wrv[4];
  __shared__ int wri[4];
  __shared__ int winner;
  for (int it = 0; it < NTOP; ++it) {
    float best = v8[0];
    int bj = 0;
#pragma unroll
    for (int j = 1; j < 8; ++j)
      if (v8[j] > best) { best = v8[j]; bj = j; }
    int bi = bj * 256 + tid;
#pragma unroll
    for (int m = 1; m < 64; m <<= 1) {
      float ov = __shfl_xor(best, m);
      int oi = __shfl_xor(bi, m);
      if (ov > best || (ov == best && oi < bi)) { best = ov; bi = oi; }
    }
    if (lane == 0) { wrv[wv] = best; wri[wv] = bi; }
    __syncthreads();
    if (tid == 0) {
      float bv = wrv[0]; int bbi = wri[0];
#pragma unroll
      for (int t = 1; t < 4; ++t)
        if (wrv[t] > bv || (wrv[t] == bv && wri[t] < bbi)) { bv = wrv[t]; bbi = wri[t]; }
      Mtop[bh * NTOP + it] = bbi;
      winner = bbi;
    }
    __syncthreads();
    int w = winner;
#pragma unroll
    for (int j = 0; j < 8; ++j)
      if ((w >> 8) == j && (w & 255) == tid) v8[j] = -3.4e38f;
  }
}

// ---------------------------------------------------------------- kv pack (self)
__global__ __launch_bounds__(256)
void kvpack_self(const float* __restrict__ qk, const u16* __restrict__ vbf,
                 u16* __restrict__ kpack, u16* __restrict__ vpack) {
  int bh = blockIdx.x, ch = blockIdx.y;
  int b = bh >> 4, hh = bh & 15;
  int tid = threadIdx.x;
  __shared__ u16 vt[64][80];
#pragma unroll
  for (int rep = 0; rep < 2; ++rep) {
    int u = rep * 256 + tid;
    int key = u >> 3, c = u & 7;
    const float* ksrc = qk + ((size_t)(b * SEQ + ch * 64 + key)) * 2048 + 1024 + hh * 64 + c * 8;
    f32x4_t k0 = *(const f32x4_t*)ksrc;
    f32x4_t k1 = *(const f32x4_t*)(ksrc + 4);
    u16x8_t d;
    d[0] = f2b(k0[0]); d[1] = f2b(k0[1]); d[2] = f2b(k0[2]); d[3] = f2b(k0[3]);
    d[4] = f2b(k1[0]); d[5] = f2b(k1[1]); d[6] = f2b(k1[2]); d[7] = f2b(k1[3]);
    int slot = (key & 3) | (((key >> 3) & 1) << 2);
    *(u16x8_t*)(kpack + ((size_t)bh * SEQ + ch * 64 + key) * 64 + ((c ^ slot) * 8)) = d;
    u16x8_t dv = *(const u16x8_t*)(vbf + ((size_t)(b * SEQ + ch * 64 + key)) * 1024 + hh * 64 + c * 8);
    *(u16x8_t*)(&vt[key][c * 8]) = dv;
  }
  __syncthreads();
#pragma unroll
  for (int rep = 0; rep < 2; ++rep) {
    int u = rep * 256 + tid;
    int e = u >> 3, c = u & 7;
    int kb = (c ^ (e & 7)) * 8;
    u16x8_t d;
#pragma unroll
    for (int j = 0; j < 8; ++j) d[j] = vt[kb + j][e];
    *(u16x8_t*)(vpack + (((size_t)bh * 32 + ch) * 64 + e) * 64 + c * 8) = d;
  }
}

// ---------------------------------------------------------------- probAttn (MFMA flash, key-split)
__global__ __launch_bounds__(256)
void probAttn_kernel(const float* __restrict__ qk, const u16* __restrict__ kpack,
                     const u16* __restrict__ vpack, const int* __restrict__ Mtop,
                     float* __restrict__ Opart, float* __restrict__ ml) {
  const int bh = blockIdx.x, b = bh >> 4, hh = bh & 15;
  const int split = blockIdx.y;                 // 0..7 (256 keys each)
  const int tid = threadIdx.x, wave = tid >> 6, lane = tid & 63;
  const int lr = lane & 15, kg = lane >> 4;
  const int wv = __builtin_amdgcn_readfirstlane(wave);
  __shared__ __align__(16) u16 Qs[48 * 64];
  __shared__ __align__(16) u16 Kt[2][64 * 64];
  __shared__ __align__(16) u16 Vt[2][64 * 64];

#pragma unroll
  for (int rep = 0; rep < 3; ++rep) {
    int j = tid + 256 * rep;        // 0..767
    int row = j >> 4, c4 = j & 15;
    int qi = Mtop[bh * NTOP + (row < NTOP ? row : NTOP - 1)];
    f32x4_t v4 = *(const f32x4_t*)(qk + ((size_t)b * SEQ + qi) * 2048 + hh * EHEAD + c4 * 4);
    u16x4_t b4;
    b4[0] = f2b(v4[0] * 0.125f); b4[1] = f2b(v4[1] * 0.125f);
    b4[2] = f2b(v4[2] * 0.125f); b4[3] = f2b(v4[3] * 0.125f);
    *(u16x4_t*)((char*)Qs + ((row * 128 + c4 * 8) ^ ((row & 7) << 4))) = b4;
  }

  const int qtile = (wave < 3) ? wave : 2;
  const int qrow_g = qtile * 16 + lr;
  const int iq = (qrow_g < NTOP) ? Mtop[bh * NTOP + qrow_g] : -1;

  const char* kgl = (const char*)kpack + (size_t)bh * SEQ * 128 + (size_t)split * 4 * 8192;
  const char* vgl = (const char*)vpack + (size_t)bh * 32 * 8192 + (size_t)split * 4 * 8192;
  auto STAGE = [&](int buf, int t) {
    GLD16(kgl + (size_t)t * 8192 + wv * 2048 + lane * 16, (char*)Kt[buf] + wv * 2048);
    GLD16(kgl + (size_t)t * 8192 + wv * 2048 + 1024 + lane * 16, (char*)Kt[buf] + wv * 2048 + 1024);
    GLD16(vgl + (size_t)t * 8192 + wv * 2048 + lane * 16, (char*)Vt[buf] + wv * 2048);
    GLD16(vgl + (size_t)t * 8192 + wv * 2048 + 1024 + lane * 16, (char*)Vt[buf] + wv * 2048 + 1024);
  };

  STAGE(0, 0);
  __syncthreads();

  u16x8_t bq[2];
  {
    int qrow = qtile * 16 + lr;
#pragma unroll
    for (int ks = 0; ks < 2; ++ks)
      bq[ks] = *(u16x8_t*)((char*)Qs + ((qrow * 128 + ks * 64 + kg * 16) ^ ((qrow & 7) << 4)));
  }

  f32x4_t oacc[4];
#pragma unroll
  for (int i = 0; i < 4; ++i) oacc[i] = f32x4_t{0.f, 0.f, 0.f, 0.f};
  float mrun = -3e38f, lrun = 0.f;

  for (int t = 0; t < 4; ++t) {
    const int cur = t & 1;
    if (t + 1 < 4) STAGE(cur ^ 1, t + 1);
    f32x4_t s[4];
#pragma unroll
    for (int i = 0; i < 4; ++i) s[i] = f32x4_t{0.f, 0.f, 0.f, 0.f};
#pragma unroll
    for (int ks = 0; ks < 2; ++ks)
#pragma unroll
      for (int t4 = 0; t4 < 4; ++t4) {
        int arow = ((t4 >> 1) << 5) + ((lr >> 2) << 3) + ((t4 & 1) << 2) + (lr & 3);
        int slot = (arow & 3) | (((arow >> 3) & 1) << 2);
        int off = (arow << 7) + (ks << 6) + (kg << 4);
        u16x8_t ak = *(const u16x8_t*)((const char*)Kt[cur] + (off ^ (slot << 4)));
        s[t4] = mfma_bf16(ak, bq[ks], s[t4]);
      }
    const int kb0 = split * 256 + t * 64;
#pragma unroll
    for (int t4 = 0; t4 < 4; ++t4)
#pragma unroll
      for (int r = 0; r < 4; ++r) {
        int gkey = kb0 + ((t4 >> 1) << 5) + (kg << 3) + ((t4 & 1) << 2) + r;
        if (gkey > iq) s[t4][r] = -1e9f;
      }
    float mx = s[0][0];
#pragma unroll
    for (int t4 = 0; t4 < 4; ++t4)
#pragma unroll
      for (int r = 0; r < 4; ++r) mx = fmaxf(mx, s[t4][r]);
    mx = fmaxf(mx, __shfl_xor(mx, 16));
    mx = fmaxf(mx, __shfl_xor(mx, 32));
    float mnew = fmaxf(mrun, mx);
    float a = __expf(mrun - mnew);
    float sum = 0.f;
#pragma unroll
    for (int t4 = 0; t4 < 4; ++t4)
#pragma unroll
      for (int r = 0; r < 4; ++r) {
        float p = __expf(s[t4][r] - mnew);
        s[t4][r] = p; sum += p;
      }
    sum += __shfl_xor(sum, 16);
    sum += __shfl_xor(sum, 32);
    lrun = lrun * a + sum;
    mrun = mnew;
    float ar[4];
#pragma unroll
    for (int r = 0; r < 4; ++r) ar[r] = __shfl(a, kg * 4 + r);
#pragma unroll
    for (int ne = 0; ne < 4; ++ne)
#pragma unroll
      for (int r = 0; r < 4; ++r) oacc[ne][r] *= ar[r];
#pragma unroll
    for (int ks2 = 0; ks2 < 2; ++ks2) {
      u16x8_t pa;
#pragma unroll
      for (int j = 0; j < 4; ++j) {
        pa[j] = f2b(s[2 * ks2][j]);
        pa[4 + j] = f2b(s[2 * ks2 + 1][j]);
      }
#pragma unroll
      for (int ne = 0; ne < 4; ++ne) {
        int e = ne * 16 + lr;
        int off = (e << 7) + (ks2 << 6) + (kg << 4);
        u16x8_t bv = *(const u16x8_t*)((const char*)Vt[cur] + (off ^ ((e & 7) << 4)));
        oacc[ne] = mfma_bf16(pa, bv, oacc[ne]);
      }
    }
    __syncthreads();
  }

  if (wave < 3) {
    float* ob = Opart + (((size_t)(bh * 8 + split)) * 48 + qtile * 16) * 64;
#pragma unroll
    for (int ne = 0; ne < 4; ++ne)
#pragma unroll
      for (int r = 0; r < 4; ++r)
        ob[(size_t)(kg * 4 + r) * 64 + ne * 16 + lr] = oacc[ne][r];
    if (kg == 0) {
      size_t mb = (((size_t)(bh * 8 + split)) * 48 + qtile * 16 + lr) * 2;
      ml[mb + 0] = mrun;
      ml[mb + 1] = lrun;
    }
  }
}

__global__ __launch_bounds__(64)
void probCombine_kernel(const float* __restrict__ Opart, const float* __restrict__ ml,
                        const int* __restrict__ Mtop, u16* __restrict__ ctxb) {
  int bh = blockIdx.x / NTOP, q = blockIdx.x % NTOP;
  int e = threadIdx.x;
  int b = bh >> 4, hh = bh & 15;
  float ms[8], ls[8];
  float mstar = -3.0e38f;
#pragma unroll
  for (int s = 0; s < 8; ++s) {
    size_t mb = (((size_t)(bh * 8 + s)) * 48 + q) * 2;
    ms[s] = ml[mb + 0];
    ls[s] = ml[mb + 1];
    mstar = fmaxf(mstar, ms[s]);
  }
  float lstar = 0.f, acc = 0.f;
#pragma unroll
  for (int s = 0; s < 8; ++s) {
    float w = __expf(ms[s] - mstar);
    lstar += w * ls[s];
    acc += w * Opart[(((size_t)(bh * 8 + s)) * 48 + q) * 64 + e];
  }
  int row = Mtop[bh * NTOP + q];
  ctxb[((size_t)b * SEQ + row) * DMODEL + hh * EHEAD + e] = f2b(acc / lstar);
}

// ---------------------------------------------------------------- fused scan
// per bh: 16 chunk-waves scan their 128 rows, LDS prefix, rewalk v, bf16 out.
__global__ __launch_bounds__(1024)
void scan_kernel(const u16* __restrict__ v, u16* __restrict__ ctxb) {
  int bh = blockIdx.x;
  int b = bh >> 4, hh = bh & 15;
  int e = threadIdx.x & 63, ch = threadIdx.x >> 6;   // ch: 0..15
  size_t base = ((size_t)b * SEQ + ch * 128) * DMODEL + hh * EHEAD + e;
  float run = 0.f;
  for (int i = 0; i < 128; ++i) run += b2f(v[base + (size_t)i * DMODEL]);
  __shared__ float cs[16][64];
  cs[ch][e] = run;
  __syncthreads();
  float off = 0.f;
  for (int cc = 0; cc < ch; ++cc) off += cs[cc][e];
  run = off;
  for (int i = 0; i < 128; ++i) {
    run += b2f(v[base + (size_t)i * DMODEL]);
    ctxb[base + (size_t)i * DMODEL] = f2b(run);
  }
}

// ---------------------------------------------------------------- kv pack (cross)
__global__ __launch_bounds__(256)
void kvpack_kernel(const u16* __restrict__ kv, u16* __restrict__ kpack,
                   u16* __restrict__ vpack) {
  int bh = blockIdx.x, ch = blockIdx.y;
  int b = bh >> 4, hh = bh & 15;
  int tid = threadIdx.x;
  __shared__ u16 vt[64][80];
#pragma unroll
  for (int rep = 0; rep < 2; ++rep) {
    int u = rep * 256 + tid;
    int key = u >> 3, c = u & 7;
    u16x8_t d = *(const u16x8_t*)(kv + ((size_t)(b * SEQ + ch * 64 + key)) * 2048 + hh * 64 + c * 8);
    int slot = (key & 3) | (((key >> 3) & 1) << 2);
    *(u16x8_t*)(kpack + ((size_t)bh * SEQ + ch * 64 + key) * 64 + ((c ^ slot) * 8)) = d;
    u16x8_t dv = *(const u16x8_t*)(kv + ((size_t)(b * SEQ + ch * 64 + key)) * 2048 + 1024 + hh * 64 + c * 8);
    *(u16x8_t*)(&vt[key][c * 8]) = dv;
  }
  __syncthreads();
#pragma unroll
  for (int rep = 0; rep < 2; ++rep) {
    int u = rep * 256 + tid;
    int e = u >> 3, c = u & 7;
    int kb = (c ^ (e & 7)) * 8;
    u16x8_t d;
#pragma unroll
    for (int j = 0; j < 8; ++j) d[j] = vt[kb + j][e];
    *(u16x8_t*)(vpack + (((size_t)bh * 32 + ch) * 64 + e) * 64 + c * 8) = d;
  }
}

// ---------------------------------------------------------------- cross attn
__global__ __launch_bounds__(512)
void cross_attn_kernel(const float* __restrict__ q2, const u16* __restrict__ kpack,
                       const u16* __restrict__ vpack, u16* __restrict__ cab) {
  const int bh = blockIdx.x, b = bh >> 4, hh = bh & 15;
  const int qt0 = blockIdx.y * 128;
  const int tid = threadIdx.x, wave = tid >> 6, lane = tid & 63;
  const int lr = lane & 15, kg = lane >> 4;
  const int wv = __builtin_amdgcn_readfirstlane(wave);
  __shared__ __align__(16) u16 Qs[128 * 64];
  __shared__ __align__(16) u16 Kt[2][64 * 64];
  __shared__ __align__(16) u16 Vt[2][64 * 64];

#pragma unroll
  for (int i = 0; i < 4; ++i) {
    int j = tid + 512 * i;
    int row = j >> 4, c4 = j & 15;
    f32x4_t v4 = *(const f32x4_t*)(q2 + ((size_t)b * SEQ + qt0 + row) * DMODEL + hh * EHEAD + c4 * 4);
    u16x4_t b4;
    b4[0] = f2b(v4[0] * 0.125f); b4[1] = f2b(v4[1] * 0.125f);
    b4[2] = f2b(v4[2] * 0.125f); b4[3] = f2b(v4[3] * 0.125f);
    *(u16x4_t*)((char*)Qs + ((row * 128 + c4 * 8) ^ ((row & 7) << 4))) = b4;
  }

  const char* kgl = (const char*)kpack + (size_t)bh * SEQ * 128;
  const char* vgl = (const char*)vpack + (size_t)bh * 32 * 8192;
  auto STAGE = [&](int buf, int t) {
    GLD16(kgl + (size_t)t * 8192 + wv * 1024 + lane * 16, (char*)Kt[buf] + wv * 1024);
    GLD16(vgl + (size_t)t * 8192 + wv * 1024 + lane * 16, (char*)Vt[buf] + wv * 1024);
  };

  STAGE(0, 0);
  __syncthreads();

  u16x8_t bq[2];
  {
    int qrow = wave * 16 + lr;
#pragma unroll
    for (int ks = 0; ks < 2; ++ks)
      bq[ks] = *(u16x8_t*)((char*)Qs + ((qrow * 128 + ks * 64 + kg * 16) ^ ((qrow & 7) << 4)));
  }

  f32x4_t oacc[4];
#pragma unroll
  for (int i = 0; i < 4; ++i) oacc[i] = f32x4_t{0.f, 0.f, 0.f, 0.f};
  float mrun = -3e38f, lrun = 0.f;

  for (int t = 0; t < 32; ++t) {
    const int cur = t & 1;
    if (t + 1 < 32) STAGE(cur ^ 1, t + 1);
    f32x4_t s[4];
#pragma unroll
    for (int i = 0; i < 4; ++i) s[i] = f32x4_t{0.f, 0.f, 0.f, 0.f};
#pragma unroll
    for (int ks = 0; ks < 2; ++ks)
#pragma unroll
      for (int t4 = 0; t4 < 4; ++t4) {
        int arow = ((t4 >> 1) << 5) + ((lr >> 2) << 3) + ((t4 & 1) << 2) + (lr & 3);
        int slot = (arow & 3) | (((arow >> 3) & 1) << 2);
        int off = (arow << 7) + (ks << 6) + (kg << 4);
        u16x8_t ak = *(const u16x8_t*)((const char*)Kt[cur] + (off ^ (slot << 4)));
        s[t4] = mfma_bf16(ak, bq[ks], s[t4]);
      }
    float mx = s[0][0];
#pragma unroll
    for (int t4 = 0; t4 < 4; ++t4)
#pragma unroll
      for (int r = 0; r < 4; ++r) mx = fmaxf(mx, s[t4][r]);
    mx = fmaxf(mx, __shfl_xor(mx, 16));
    mx = fmaxf(mx, __shfl_xor(mx, 32));
    float mnew = fmaxf(mrun, mx);
    float a = __expf(mrun - mnew);
    float sum = 0.f;
#pragma unroll
    for (int t4 = 0; t4 < 4; ++t4)
#pragma unroll
      for (int r = 0; r < 4; ++r) {
        float p = __expf(s[t4][r] - mnew);
        s[t4][r] = p; sum += p;
      }
    sum += __shfl_xor(sum, 16);
    sum += __shfl_xor(sum, 32);
    lrun = lrun * a + sum;
    mrun = mnew;
    float ar[4];
#pragma unroll
    for (int r = 0; r < 4; ++r) ar[r] = __shfl(a, kg * 4 + r);
#pragma unroll
    for (int ne = 0; ne < 4; ++ne)
#pragma unroll
      for (int r = 0; r < 4; ++r) oacc[ne][r] *= ar[r];
#pragma unroll
    for (int ks2 = 0; ks2 < 2; ++ks2) {
      u16x8_t pa;
#pragma unroll
      for (int j = 0; j < 4; ++j) {
        pa[j] = f2b(s[2 * ks2][j]);
        pa[4 + j] = f2b(s[2 * ks2 + 1][j]);
      }
#pragma unroll
      for (int ne = 0; ne < 4; ++ne) {
        int e = ne * 16 + lr;
        int off = (e << 7) + (ks2 << 6) + (kg << 4);
        u16x8_t bv = *(const u16x8_t*)((const char*)Vt[cur] + (off ^ ((e & 7) << 4)));
        oacc[ne] = mfma_bf16(pa, bv, oacc[ne]);
      }
    }
    __syncthreads();
  }

  float lr4[4];
#pragma unroll
  for (int r = 0; r < 4; ++r) lr4[r] = __shfl(lrun, kg * 4 + r);
#pragma unroll
  for (int ne = 0; ne < 4; ++ne)
#pragma unroll
    for (int r = 0; r < 4; ++r) {
      int row = qt0 + wave * 16 + kg * 4 + r;
      int col = hh * EHEAD + ne * 16 + lr;
      cab[((size_t)b * SEQ + row) * DMODEL + col] = f2b(oacc[ne][r] / lr4[r]);
    }
}

// ---------------------------------------------------------------- layernorm
__global__ __launch_bounds__(256)
void ln_kernel(const float* __restrict__ x, const float* __restrict__ r,
               const float* __restrict__ g, const float* __restrict__ be,
               float* __restrict__ outf, u16* __restrict__ outb) {
  int row = blockIdx.x, tid = threadIdx.x;
  size_t base = (size_t)row * DMODEL;
  float v[4];
  float s = 0.f, sq = 0.f;
#pragma unroll
  for (int i = 0; i < 4; ++i) {
    int c = tid + i * 256;
    float t = x[base + c] + r[base + c];
    v[i] = t; s += t; sq += t * t;
  }
  __shared__ float rs[256], rq[256];
  rs[tid] = s; rq[tid] = sq;
  __syncthreads();
  for (int st = 128; st > 0; st >>= 1) {
    if (tid < st) { rs[tid] += rs[tid + st]; rq[tid] += rq[tid + st]; }
    __syncthreads();
  }
  float mean = rs[0] * (1.f / DMODEL);
  float var = rq[0] * (1.f / DMODEL) - mean * mean;
  float rstd = rsqrtf(var + 1e-5f);
#pragma unroll
  for (int i = 0; i < 4; ++i) {
    int c = tid + i * 256;
    float o = (v[i] - mean) * rstd * g[c] + be[c];
    if (outf) outf[base + c] = o;
    if (outb) outb[base + c] = f2b(o);
  }
}

// ---------------------------------------------------------------- host side
static inline void gemm(const u16* A, const u16* Bt, const float* bias, float* Cf,
                        u16* Cb, int M, int N, int K, int relu, hipStream_t s,
                        int big = 0) {
  if (big)
    gemm_bf<4><<<dim3(M / 128, N / 128), 256, 0, s>>>(A, Bt, bias, Cf, Cb, M, N, K, relu);
  else
    gemm_bf<2><<<dim3(M / 128, N / 64), 256, 0, s>>>(A, Bt, bias, Cf, Cb, M, N, K, relu);
}
static inline void gemm4(const u16* Ah, const u16* Al, const u16* Bh, const u16* Bl,
                         const float* bias, float* Cf, int M, int N, int K, hipStream_t s) {
  gemm4_bf<4><<<dim3(M / 128, N / 128), 256, 0, s>>>(Ah, Al, Bh, Bl, bias, Cf, M, N, K);
}

extern "C" void kernel_launch(void* const* d_in, const int* in_sizes, int n_in,
                              void* d_out, int out_size, void* d_ws, size_t ws_size,
                              hipStream_t stream) {
  const float* x   = (const float*)d_in[0];
  const float* mem = (const float*)d_in[1];
  const float* sWq = (const float*)d_in[2];  const float* sbq = (const float*)d_in[3];
  const float* sWk = (const float*)d_in[4];  const float* sbk = (const float*)d_in[5];
  const float* sWv = (const float*)d_in[6];  const float* sbv = (const float*)d_in[7];
  const float* sWo = (const float*)d_in[8];  const float* sbo = (const float*)d_in[9];
  const float* cWq = (const float*)d_in[10]; const float* cbq = (const float*)d_in[11];
  const float* cWk = (const float*)d_in[12]; const float* cbk = (const float*)d_in[13];
  const float* cWv = (const float*)d_in[14]; const float* cbv = (const float*)d_in[15];
  const float* cWo = (const float*)d_in[16]; const float* cbo = (const float*)d_in[17];
  const float* W1  = (const float*)d_in[18]; const float* b1  = (const float*)d_in[19];
  const float* W2  = (const float*)d_in[20]; const float* b2  = (const float*)d_in[21];
  const float* g1  = (const float*)d_in[22]; const float* be1 = (const float*)d_in[23];
  const float* g2  = (const float*)d_in[24]; const float* be2 = (const float*)d_in[25];
  const float* g3  = (const float*)d_in[26]; const float* be3 = (const float*)d_in[27];
  float* outp = (float*)d_out;
  char* ws = (char*)d_ws;
  const size_t MB = 1ull << 20;

  int*   idx    = (int*)(ws);
  float* Mv     = (float*)(ws + 0x60000);
  int*   Mtop   = (int*)(ws + 0xA0000);
  float* biasqk = (float*)(ws + 0x120000);
  float* cbkv   = (float*)(ws + 0x122000);

  u16* WqkhT = (u16*)(ws + 2 * MB);    // [2048][1024]
  u16* WqklT = (u16*)(ws + 6 * MB);
  u16* sWvT  = (u16*)(ws + 10 * MB);
  u16* sWoT  = (u16*)(ws + 12 * MB);
  u16* cWqT  = (u16*)(ws + 14 * MB);
  u16* cWkvT = (u16*)(ws + 16 * MB);   // [2048][1024]
  u16* cWoT  = (u16*)(ws + 20 * MB);
  u16* W1T   = (u16*)(ws + 22 * MB);
  u16* W2T   = (u16*)(ws + 30 * MB);

  u16* xh   = (u16*)(ws + 38 * MB);
  u16* xl   = (u16*)(ws + 46 * MB);
  u16* memb = (u16*)(ws + 54 * MB);

  float* qk    = (float*)(ws + 62 * MB);   // [4096][2048] f32, 32MB [62,94)
  u16*   vbf   = (u16*)(ws + 94 * MB);     // 8MB [94,102)
  u16*   kpks  = (u16*)(ws + 102 * MB);    // 8MB [102,110) self K packed
  u16*   vpks  = (u16*)(ws + 46 * MB);     // 8MB (over xl, dead after gemm4)
  float* Opart = (float*)(ws + 110 * MB);  // 3MB [110,113)
  float* mlbuf = (float*)(ws + 113 * MB);  // 98KB
  u16*   ctxb  = (u16*)(ws + 78 * MB);
  float* sa    = (float*)(ws + 94 * MB);   // reuse vbf+kpks
  float* x1    = (float*)(ws + 62 * MB);
  u16*   x1b   = (u16*)(ws + 78 * MB);
  float* q2    = (float*)(ws + 94 * MB);
  u16*   kv2b  = (u16*)(ws + 38 * MB);     // [4096][2048] bf16, 16MB [38,54)
  u16*   kpk   = (u16*)(ws + 54 * MB);     // 8MB (over memb, dead)
  u16*   vpk   = (u16*)(ws + 110 * MB);    // 8MB (over Opart, dead)
  u16*   cab   = (u16*)(ws + 38 * MB);
  float* ca2   = (float*)(ws + 94 * MB);
  float* x2    = (float*)(ws + 38 * MB);
  u16*   x2b   = (u16*)(ws + 54 * MB);
  u16*   hbb   = (u16*)(ws + 62 * MB);     // 32MB [62,94)
  float* yb    = (float*)(ws + 94 * MB);

  const int MROWS = BATCH * SEQ;  // 4096

  // ---- prep ----
  idx_kernel<<<320, 256, 0, stream>>>(idx);
  {
    Ptr2 p2;
    p2.s[0] = sWq; p2.dh[0] = WqkhT;              p2.dl[0] = WqklT;
    p2.s[1] = sWk; p2.dh[1] = WqkhT + 1024*1024;  p2.dl[1] = WqklT + 1024*1024;
    wsplit2_kernel<<<dim3(16, 16, 2), 256, 0, stream>>>(p2);
    Ptr6 p6;
    p6.s[0] = sWv; p6.d[0] = sWvT;
    p6.s[1] = sWo; p6.d[1] = sWoT;
    p6.s[2] = cWq; p6.d[2] = cWqT;
    p6.s[3] = cWk; p6.d[3] = cWkvT;
    p6.s[4] = cWv; p6.d[4] = cWkvT + 1024*1024;
    p6.s[5] = cWo; p6.d[5] = cWoT;
    wt6_kernel<<<dim3(16, 16, 6), 256, 0, stream>>>(p6);
  }
  wt_kernel<<<dim3(64, 16), 256, 0, stream>>>(W1, W1T, 1024, 4096);
  wt_kernel<<<dim3(16, 64), 256, 0, stream>>>(W2, W2T, 4096, 1024);
  prep_inputs<<<8192, 256, 0, stream>>>(x, xh, xl, mem, memb);
  pack4_kernel<<<16, 256, 0, stream>>>(sbq, sbk, biasqk, cbk, cbv, cbkv);

  // ---- self attention (ProbSparse) ----
  gemm4(xh, xl, WqkhT, WqklT, biasqk, qk, MROWS, 2048, DMODEL, stream);
  gemm(xh, sWvT, sbv, nullptr, vbf, MROWS, DMODEL, DMODEL, 0, stream);
  probM_kernel<<<BATCH * SEQ / 4, 256, 0, stream>>>(qk, idx, Mv);
  topk_kernel<<<BATCH * NHEADS, 256, 0, stream>>>(Mv, Mtop);
  kvpack_self<<<dim3(BATCH * NHEADS, SEQ / 64), 256, 0, stream>>>(qk, vbf, kpks, vpks);
  probAttn_kernel<<<dim3(BATCH * NHEADS, 8), 256, 0, stream>>>(qk, kpks, vpks, Mtop, Opart, mlbuf);
  scan_kernel<<<BATCH * NHEADS, 1024, 0, stream>>>(vbf, ctxb);
  probCombine_kernel<<<BATCH * NHEADS * NTOP, 64, 0, stream>>>(Opart, mlbuf, Mtop, ctxb);
  gemm(ctxb, sWoT, sbo, sa, nullptr, MROWS, DMODEL, DMODEL, 0, stream);
  ln_kernel<<<MROWS, 256, 0, stream>>>(x, sa, g1, be1, x1, x1b);

  // ---- cross attention ----
  gemm(x1b, cWqT, cbq, q2, nullptr, MROWS, DMODEL, DMODEL, 0, stream);
  gemm(memb, cWkvT, cbkv, nullptr, kv2b, MROWS, 2048, DMODEL, 0, stream, 1);
  kvpack_kernel<<<dim3(BATCH * NHEADS, SEQ / 64), 256, 0, stream>>>(kv2b, kpk, vpk);
  cross_attn_kernel<<<dim3(BATCH * NHEADS, SEQ / 128), 512, 0, stream>>>(q2, kpk, vpk, cab);
  gemm(cab, cWoT, cbo, ca2, nullptr, MROWS, DMODEL, DMODEL, 0, stream);
  ln_kernel<<<MROWS, 256, 0, stream>>>(x1, ca2, g2, be2, x2, x2b);

  // ---- FFN ----
  gemm(x2b, W1T, b1, nullptr, hbb, MROWS, DFF, DMODEL, 1, stream, 1);
  gemm(hbb, W2T, b2, yb, nullptr, MROWS, DMODEL, DFF, 0, stream);
  ln_kernel<<<MROWS, 256, 0, stream>>>(x2, yb, g3, be3, outp, nullptr);
}